// Round 2
// baseline (1665.902 us; speedup 1.0000x reference)
//
#include <hip/hip_runtime.h>

#define NGR 10000
typedef unsigned int u32;

// ---------- float <-> ordered-uint for atomic max ----------
__device__ __forceinline__ u32 ford(float f) {
    u32 u = __float_as_uint(f);
    return (u & 0x80000000u) ? ~u : (u | 0x80000000u);
}
__device__ __forceinline__ float forddec(u32 u) {
    u32 b = (u & 0x80000000u) ? (u & 0x7FFFFFFFu) : ~u;
    return __uint_as_float(b);
}

// ---------- threefry2x32 (JAX-exact) ----------
__device__ __forceinline__ void threefry(u32 k0, u32 k1, u32 c0, u32 c1, u32& o0, u32& o1) {
    u32 ks2 = k0 ^ k1 ^ 0x1BD11BDAu;
    u32 x0 = c0 + k0, x1 = c1 + k1;
#define TF_R(r) { x0 += x1; x1 = (x1 << r) | (x1 >> (32 - r)); x1 ^= x0; }
    TF_R(13) TF_R(15) TF_R(26) TF_R(6)
    x0 += k1; x1 += ks2 + 1u;
    TF_R(17) TF_R(29) TF_R(16) TF_R(24)
    x0 += ks2; x1 += k0 + 2u;
    TF_R(13) TF_R(15) TF_R(26) TF_R(6)
    x0 += k0; x1 += k1 + 3u;
    TF_R(17) TF_R(29) TF_R(16) TF_R(24)
    x0 += k1; x1 += ks2 + 4u;
    TF_R(13) TF_R(15) TF_R(26) TF_R(6)
    x0 += ks2; x1 += k0 + 5u;
#undef TF_R
    o0 = x0; o1 = x1;
}

// ---------- f32 GEMM: C[M,N] = A[M,K] @ B[K,N] (+bias) ----------
// 128x128 tile, 8x8 microtile, TK=16
__global__ __launch_bounds__(256) void gemm_f32(
    const float* __restrict__ A, int lda,
    const float* __restrict__ B, int ldb,
    float* __restrict__ C, int ldc,
    const float* __restrict__ bias,
    int M, int N, int K)
{
    __shared__ float As[16][132];
    __shared__ float Bs[16][132];
    const int tid = threadIdx.x;
    const int bm = blockIdx.y * 128, bn = blockIdx.x * 128;
    const int tx = tid & 15, ty = tid >> 4;
    const int ar0 = tid >> 2, ac = (tid & 3) << 2;
    const int br = tid >> 5, bc = (tid & 31) << 2;
    float acc[8][8] = {};
    for (int k0 = 0; k0 < K; k0 += 16) {
#pragma unroll
        for (int h = 0; h < 2; ++h) {
            int m = bm + ar0 + h * 64;
            float4 v = make_float4(0.f, 0.f, 0.f, 0.f);
            if (m < M) v = *(const float4*)(A + (size_t)m * lda + k0 + ac);
            As[ac + 0][ar0 + h * 64] = v.x; As[ac + 1][ar0 + h * 64] = v.y;
            As[ac + 2][ar0 + h * 64] = v.z; As[ac + 3][ar0 + h * 64] = v.w;
        }
#pragma unroll
        for (int h = 0; h < 2; ++h) {
            int n = bn + bc;
            int kr = k0 + br + h * 8;
            float4 v = make_float4(0.f, 0.f, 0.f, 0.f);
            if (n < N) v = *(const float4*)(B + (size_t)kr * ldb + n);
            *(float4*)&Bs[br + h * 8][bc] = v;
        }
        __syncthreads();
#pragma unroll
        for (int kk = 0; kk < 16; ++kk) {
            float a[8], b[8];
#pragma unroll
            for (int i = 0; i < 8; ++i) a[i] = As[kk][ty * 8 + i];
#pragma unroll
            for (int j = 0; j < 8; ++j) b[j] = Bs[kk][tx * 8 + j];
#pragma unroll
            for (int i = 0; i < 8; ++i)
#pragma unroll
                for (int j = 0; j < 8; ++j)
                    acc[i][j] = fmaf(a[i], b[j], acc[i][j]);
        }
        __syncthreads();
    }
#pragma unroll
    for (int i = 0; i < 8; ++i) {
        int m = bm + ty * 8 + i;
        if (m >= M) continue;
#pragma unroll
        for (int j = 0; j < 8; ++j) {
            int n = bn + tx * 8 + j;
            if (n < N) C[(size_t)m * ldc + n] = acc[i][j] + (bias ? bias[n] : 0.f);
        }
    }
}

// ---------- tf = leaky_relu(feat[t] @ Wt + bt, 0.01) ----------
__global__ void k_tf(const float* __restrict__ feat, const int* __restrict__ tptr,
                     const float* __restrict__ Wt, const float* __restrict__ bt, float* __restrict__ tf)
{
    int j = threadIdx.x;
    if (j >= 512) return;
    int t = *tptr;
    float acc = 0.f;
    for (int k = 0; k < 256; ++k) acc = fmaf(feat[t * 256 + k], Wt[k * 512 + j], acc);
    acc += bt[j];
    tf[j] = acc >= 0.f ? acc : 0.01f * acc;
}

// ---------- el/er: per (n,h) dot over D ----------
__global__ void k_el_er(const float* __restrict__ h, int ldh, int hoff,
                        const float* __restrict__ al, const float* __restrict__ ar,
                        float* __restrict__ el, float* __restrict__ er,
                        int ldE, int eoff, int H, int D, int N)
{
    int idx = blockIdx.x * blockDim.x + threadIdx.x;
    if (idx >= N * H) return;
    int n = idx / H, hh = idx - n * H;
    const float* hp = h + (size_t)n * ldh + hoff + hh * D;
    const float* alp = al + hh * D;
    const float* arp = ar + hh * D;
    float sl = 0.f, sr = 0.f;
    for (int d = 0; d < D; ++d) { float v = hp[d]; sl = fmaf(v, alp[d], sl); sr = fmaf(v, arp[d], sr); }
    el[n * ldE + eoff + hh] = sl;
    er[n * ldE + eoff + hh] = sr;
}

// ---------- edge pass 1: e = lrelu(el[src]+er[dst], 0.2); segment max ----------
__global__ void k_edge1(const float* __restrict__ el, const float* __restrict__ er,
                        const int* __restrict__ src, const int* __restrict__ dst,
                        float* __restrict__ ee, u32* __restrict__ m, int H, int E)
{
    int idx = blockIdx.x * blockDim.x + threadIdx.x;
    if (idx >= E * H) return;
    int k = idx / H, hh = idx - k * H;
    float v = el[src[k] * H + hh] + er[dst[k] * H + hh];
    v = v >= 0.f ? v : 0.2f * v;
    ee[idx] = v;
    atomicMax(&m[dst[k] * H + hh], ford(v));
}

// ---------- edge pass 2: ex = exp(e - m[dst]); segment sum ----------
__global__ void k_edge2(float* __restrict__ ee, const u32* __restrict__ m,
                        const int* __restrict__ dst, float* __restrict__ s, int H, int E)
{
    int idx = blockIdx.x * blockDim.x + threadIdx.x;
    if (idx >= E * H) return;
    int k = idx / H, hh = idx - k * H;
    float ex = expf(ee[idx] - forddec(m[dst[k] * H + hh]));
    ee[idx] = ex;
    atomicAdd(&s[dst[k] * H + hh], ex);
}

// ---------- edge pass 3: out[dst] += (ex/s[dst]) * h[src] ----------
__global__ void k_agg(const float* __restrict__ ee, const float* __restrict__ s,
                      const int* __restrict__ src, const int* __restrict__ dst,
                      const float* __restrict__ h, int ldh, int hoff,
                      float* __restrict__ out, int ldo, int ooff,
                      int H, int D, int E)
{
    long long idx = blockIdx.x * (long long)blockDim.x + threadIdx.x;
    int HD = H * D;
    if (idx >= (long long)E * HD) return;
    int k = (int)(idx / HD), c = (int)(idx - (long long)k * HD);
    int hh = c / D;
    int sn = src[k], dn = dst[k];
    float alpha = ee[(size_t)k * H + hh] / s[dn * H + hh];
    atomicAdd(&out[(size_t)dn * ldo + ooff + c], alpha * h[(size_t)sn * ldh + hoff + c]);
}

// ---------- a2/e2 = lrelu(concat +- swap + tf, 0.01) ----------
__global__ void k_a2e2(const float* __restrict__ o1, const float* __restrict__ tf, float* __restrict__ B)
{
    int idx = blockIdx.x * blockDim.x + threadIdx.x;
    if (idx >= NGR * 1024) return;
    int n = idx >> 10, c = idx & 1023;
    float x;
    if (c < 512) x = o1[n * 512 + c];
    else { int cc = c - 512; x = o1[n * 512 + ((cc < 256) ? cc + 256 : cc - 256)]; }
    x += tf[c & 511];
    B[idx] = x >= 0.f ? x : 0.01f * x;
}

// ---------- attr[c] = mean_n a3[n,c] ----------
__global__ void k_attr(const float* __restrict__ a3, float* __restrict__ attr)
{
    int c = blockIdx.x;
    float sum = 0.f;
    for (int n = threadIdx.x; n < NGR; n += 256) sum += a3[(size_t)n * 1024 + c];
    __shared__ float red[256];
    red[threadIdx.x] = sum; __syncthreads();
    for (int s = 128; s > 0; s >>= 1) {
        if (threadIdx.x < s) red[threadIdx.x] += red[threadIdx.x + s];
        __syncthreads();
    }
    if (threadIdx.x == 0) attr[c] = red[0] / (float)NGR;
}

// ---------- node_attr = lrelu(attr,0.01) @ Wo + bo (written twice) ----------
__global__ void k_nattr(const float* __restrict__ attr, const float* __restrict__ Wo,
                        const float* __restrict__ bo, float* __restrict__ out)
{
    int idx = blockIdx.x * blockDim.x + threadIdx.x;
    if (idx >= 16 * 256) return;
    int i = idx >> 8, j = idx & 255;
    float acc = 0.f;
    for (int d = 0; d < 64; ++d) {
        float v = attr[i * 64 + d];
        v = v >= 0.f ? v : 0.01f * v;
        acc = fmaf(v, Wo[d * 256 + j], acc);
    }
    acc += bo[j];
    out[idx] = acc;
    out[4096 + idx] = acc;
}

// ---------- probs[r,:] = softmax over n of e3[n,r] ----------
__global__ void k_probs(const float* __restrict__ e3, float* __restrict__ probs)
{
    int r = blockIdx.x;
    int tid = threadIdx.x;
    __shared__ float red[256];
    __shared__ float smx, ssum;
    float mx = -INFINITY;
    for (int n = tid; n < NGR; n += 256) mx = fmaxf(mx, e3[n * 16 + r]);
    red[tid] = mx; __syncthreads();
    for (int s = 128; s > 0; s >>= 1) { if (tid < s) red[tid] = fmaxf(red[tid], red[tid + s]); __syncthreads(); }
    if (tid == 0) smx = red[0];
    __syncthreads();
    float sum = 0.f;
    for (int n = tid; n < NGR; n += 256) sum += expf(e3[n * 16 + r] - smx);
    red[tid] = sum; __syncthreads();
    for (int s = 128; s > 0; s >>= 1) { if (tid < s) red[tid] += red[tid + s]; __syncthreads(); }
    if (tid == 0) ssum = red[0];
    __syncthreads();
    for (int n = tid; n < NGR; n += 256) probs[r * NGR + n] = expf(e3[n * 16 + r] - smx) / ssum;
}

// ---------- sampler: JAX-exact masked softmax + gumbel-argmax categorical ----------
// PRNG: threefry2x32 with jax_threefry_partitionable=True semantics (JAX >= 0.4.30):
//   counts = iota(uint64, prod(shape)); block = (hi(count)=0, lo(count)=f);
//   32-bit draw = o0 ^ o1.
// fold_in stays legacy: new_key = threefry(key, (0, i)).
#define TINYF 1.17549435e-38f
__global__ __launch_bounds__(256) void k_sample(const float* __restrict__ probs,
                                                const int* __restrict__ tptr,
                                                float* __restrict__ out_edges)
{
    int r = blockIdx.x;   // 0..15
    int tid = threadIdx.x;
    __shared__ int sel[5];
    __shared__ float s_red[256];
    __shared__ int s_redi[256];
    __shared__ float sh_vmax, sh_den;
    __shared__ u32 fk0, fk1;
    int target = *tptr;
    if (tid == 0) { sel[0] = target; out_edges[r * 5 + 0] = (float)target; }
    __syncthreads();
    const float* p = probs + r * NGR;

    for (int it = 0; it < 4; ++it) {
        int nsel = it + 1;
        if (tid == 0) {
            u32 o0, o1;
            threefry(0u, 42u, 0u, (u32)it, o0, o1);  // fold_in(key(42), it)
            fk0 = o0; fk1 = o1;
        }
        // pass 1: vmax of (p*m - 10000*(1-m))
        float vmax = -INFINITY;
        for (int j = tid; j < NGR; j += 256) {
            bool masked = false;
            for (int q = 0; q < nsel; ++q) masked |= (sel[q] == j);
            float m = masked ? 0.f : 1.f;
            float v = p[j] * m - 10000.0f * (1.0f - m);
            vmax = fmaxf(vmax, v);
        }
        s_red[tid] = vmax; __syncthreads();
        for (int s = 128; s > 0; s >>= 1) { if (tid < s) s_red[tid] = fmaxf(s_red[tid], s_red[tid + s]); __syncthreads(); }
        if (tid == 0) sh_vmax = s_red[0];
        __syncthreads();
        // pass 2: sum of exps
        float sum = 0.f;
        for (int j = tid; j < NGR; j += 256) {
            bool masked = false;
            for (int q = 0; q < nsel; ++q) masked |= (sel[q] == j);
            float m = masked ? 0.f : 1.f;
            sum += expf((p[j] - sh_vmax) * m) * m;
        }
        s_red[tid] = sum; __syncthreads();
        for (int s = 128; s > 0; s >>= 1) { if (tid < s) s_red[tid] += s_red[tid + s]; __syncthreads(); }
        if (tid == 0) sh_den = s_red[0] + 1e-8f;
        __syncthreads();
        // pass 3: argmax of gumbel + log(max(p,1e-30))
        float best = -INFINITY;
        int bidx = 0x7FFFFFFF;
        float den = sh_den, vm = sh_vmax;
        for (int j = tid; j < NGR; j += 256) {
            bool masked = false;
            for (int q = 0; q < nsel; ++q) masked |= (sel[q] == j);
            float m = masked ? 0.f : 1.f;
            float ex = expf((p[j] - vm) * m) * m;
            float pj = ex / den;
            float lg = logf(fmaxf(pj, 1e-30f));
            // partitionable threefry: 64-bit counter f (hi=0, lo=f), bits = o0^o1
            u32 o0, o1;
            threefry(fk0, fk1, 0u, (u32)(r * NGR + j), o0, o1);
            u32 b = o0 ^ o1;
            float fl = __uint_as_float((b >> 9) | 0x3F800000u) - 1.0f;
            float u = fmaxf(TINYF, fl + TINYF);
            float g = -logf(-logf(u));
            float sc = g + lg;
            if (sc > best || (sc == best && j < bidx)) { best = sc; bidx = j; }
        }
        s_red[tid] = best; s_redi[tid] = bidx; __syncthreads();
        for (int s = 128; s > 0; s >>= 1) {
            if (tid < s) {
                float ov = s_red[tid + s]; int oi = s_redi[tid + s];
                if (ov > s_red[tid] || (ov == s_red[tid] && oi < s_redi[tid])) { s_red[tid] = ov; s_redi[tid] = oi; }
            }
            __syncthreads();
        }
        if (tid == 0) { sel[it + 1] = s_redi[0]; out_edges[r * 5 + it + 1] = (float)s_redi[0]; }
        __syncthreads();
    }
}

extern "C" void kernel_launch(void* const* d_in, const int* in_sizes, int n_in,
                              void* d_out, int out_size, void* d_ws, size_t ws_size,
                              hipStream_t stream)
{
    const float* feat = (const float*)d_in[0];
    const int* src = (const int*)d_in[1];
    const int* dst = (const int*)d_in[2];
    const int* tptr = (const int*)d_in[3];
    const float* W1a = (const float*)d_in[4];  const float* al1a = (const float*)d_in[5];
    const float* ar1a = (const float*)d_in[6]; const float* R1a = (const float*)d_in[7];
    const float* b1a = (const float*)d_in[8];
    const float* W1e = (const float*)d_in[9];  const float* al1e = (const float*)d_in[10];
    const float* ar1e = (const float*)d_in[11]; const float* R1e = (const float*)d_in[12];
    const float* b1e = (const float*)d_in[13];
    const float* W2a = (const float*)d_in[14]; const float* al2a = (const float*)d_in[15];
    const float* ar2a = (const float*)d_in[16]; const float* R2a = (const float*)d_in[17];
    const float* b2a = (const float*)d_in[18];
    const float* W2e = (const float*)d_in[19]; const float* al2e = (const float*)d_in[20];
    const float* ar2e = (const float*)d_in[21]; const float* R2e = (const float*)d_in[22];
    const float* b2e = (const float*)d_in[23];
    const float* Wt = (const float*)d_in[24];  const float* bt = (const float*)d_in[25];
    const float* Wo = (const float*)d_in[26];  const float* bo = (const float*)d_in[27];
    const int E = in_sizes[1];
    const int N = NGR;

    float* ws = (float*)d_ws;
    // region A: phase1 h1 [N][512] + o1 [N][512]; phase2 h2a [N][1024]
    float* h1 = ws;
    float* o1 = ws + (size_t)N * 512;
    float* h2a = ws;
    float* a2e2 = ws + (size_t)N * 1024;       // [N][1024]
    float* o2a = a2e2 + (size_t)N * 1024;      // [N][1024] (a3)
    float* sm = o2a + (size_t)N * 1024;
    float* tf = sm;                 // 512
    float* attr = sm + 512;         // 1024
    float* el1 = sm + 2048;         // N*8
    float* er1 = el1 + (size_t)N * 8;
    float* el2a = er1 + (size_t)N * 8;   // N*4
    float* er2a = el2a + (size_t)N * 4;
    float* el2e = er2a + (size_t)N * 4;  // N
    float* er2e = el2e + N;
    float* mz = er2e + N;           // ---- zeroed region start ----
    u32* m1 = (u32*)mz;             // N*8
    float* s1 = mz + (size_t)N * 8;
    u32* m2a = (u32*)(s1 + (size_t)N * 8);  // N*4
    float* s2a = (float*)m2a + (size_t)N * 4;
    u32* m2e = (u32*)(s2a + (size_t)N * 4); // N
    float* s2e = (float*)m2e + N;
    float* mzend = s2e + N;         // ---- zeroed region end ----
    float* h2e = mzend;             // N*16
    float* e3 = h2e + (size_t)N * 16;
    float* ee1 = e3 + (size_t)N * 16;        // E*8
    float* ee2a = ee1 + (size_t)E * 8;       // E*4
    float* ee2e = ee2a + (size_t)E * 4;      // E

    float* out = (float*)d_out;
    float* out_edges = out + 8192;
    float* out_probs = out + 8272;

    hipMemsetAsync(mz, 0, (size_t)(mzend - mz) * sizeof(float), stream);

    k_tf<<<1, 512, 0, stream>>>(feat, tptr, Wt, bt, tf);

    dim3 blk(256);
    auto g2 = [](int n, int m) { return dim3((unsigned)((n + 127) / 128), (unsigned)((m + 127) / 128)); };

    // layer 1
    gemm_f32<<<g2(256, N), blk, 0, stream>>>(feat, 256, W1a, 256, h1 + 0, 512, nullptr, N, 256, 256);
    gemm_f32<<<g2(256, N), blk, 0, stream>>>(feat, 256, W1e, 256, h1 + 256, 512, nullptr, N, 256, 256);
    gemm_f32<<<g2(256, N), blk, 0, stream>>>(feat, 256, R1a, 256, o1 + 0, 512, b1a, N, 256, 256);
    gemm_f32<<<g2(256, N), blk, 0, stream>>>(feat, 256, R1e, 256, o1 + 256, 512, b1e, N, 256, 256);

    k_el_er<<<(N * 4 + 255) / 256, blk, 0, stream>>>(h1, 512, 0, al1a, ar1a, el1, er1, 8, 0, 4, 64, N);
    k_el_er<<<(N * 4 + 255) / 256, blk, 0, stream>>>(h1, 512, 256, al1e, ar1e, el1, er1, 8, 4, 4, 64, N);

    k_edge1<<<(E * 8 + 255) / 256, blk, 0, stream>>>(el1, er1, src, dst, ee1, m1, 8, E);
    k_edge2<<<(E * 8 + 255) / 256, blk, 0, stream>>>(ee1, m1, dst, s1, 8, E);
    k_agg<<<(unsigned)(((long long)E * 512 + 255) / 256), blk, 0, stream>>>(
        ee1, s1, src, dst, h1, 512, 0, o1, 512, 0, 8, 64, E);

    k_a2e2<<<(N * 1024 + 255) / 256, blk, 0, stream>>>(o1, tf, a2e2);

    // layer 2
    gemm_f32<<<g2(1024, N), blk, 0, stream>>>(a2e2, 1024, W2a, 1024, h2a, 1024, nullptr, N, 1024, 512);
    gemm_f32<<<g2(1024, N), blk, 0, stream>>>(a2e2, 1024, R2a, 1024, o2a, 1024, b2a, N, 1024, 512);
    gemm_f32<<<g2(16, N), blk, 0, stream>>>(a2e2 + 512, 1024, W2e, 16, h2e, 16, nullptr, N, 16, 512);
    gemm_f32<<<g2(16, N), blk, 0, stream>>>(a2e2 + 512, 1024, R2e, 16, e3, 16, b2e, N, 16, 512);

    k_el_er<<<(N * 4 + 255) / 256, blk, 0, stream>>>(h2a, 1024, 0, al2a, ar2a, el2a, er2a, 4, 0, 4, 256, N);
    k_el_er<<<(N + 255) / 256, blk, 0, stream>>>(h2e, 16, 0, al2e, ar2e, el2e, er2e, 1, 0, 1, 16, N);

    k_edge1<<<(E * 4 + 255) / 256, blk, 0, stream>>>(el2a, er2a, src, dst, ee2a, m2a, 4, E);
    k_edge2<<<(E * 4 + 255) / 256, blk, 0, stream>>>(ee2a, m2a, dst, s2a, 4, E);
    k_agg<<<(unsigned)(((long long)E * 1024 + 255) / 256), blk, 0, stream>>>(
        ee2a, s2a, src, dst, h2a, 1024, 0, o2a, 1024, 0, 4, 256, E);

    k_edge1<<<(E + 255) / 256, blk, 0, stream>>>(el2e, er2e, src, dst, ee2e, m2e, 1, E);
    k_edge2<<<(E + 255) / 256, blk, 0, stream>>>(ee2e, m2e, dst, s2e, 1, E);
    k_agg<<<(unsigned)(((long long)E * 16 + 255) / 256), blk, 0, stream>>>(
        ee2e, s2e, src, dst, h2e, 16, 0, e3, 16, 0, 1, 16, E);

    k_attr<<<1024, blk, 0, stream>>>(o2a, attr);
    k_nattr<<<16, blk, 0, stream>>>(attr, Wo, bo, out);
    k_probs<<<16, blk, 0, stream>>>(e3, out_probs);
    k_sample<<<16, blk, 0, stream>>>(out_probs, tptr, out_edges);
}

// Round 3
// 965.891 us; speedup vs baseline: 1.7247x; 1.7247x over previous
//
#include <hip/hip_runtime.h>
#include <hip/hip_bf16.h>

#define NGR 10000
typedef unsigned int u32;
typedef __attribute__((ext_vector_type(8))) short short8;
typedef __attribute__((ext_vector_type(4))) float f32x4;

// ---------- threefry2x32 (JAX-exact) ----------
__device__ __forceinline__ void threefry(u32 k0, u32 k1, u32 c0, u32 c1, u32& o0, u32& o1) {
    u32 ks2 = k0 ^ k1 ^ 0x1BD11BDAu;
    u32 x0 = c0 + k0, x1 = c1 + k1;
#define TF_R(r) { x0 += x1; x1 = (x1 << r) | (x1 >> (32 - r)); x1 ^= x0; }
    TF_R(13) TF_R(15) TF_R(26) TF_R(6)
    x0 += k1; x1 += ks2 + 1u;
    TF_R(17) TF_R(29) TF_R(16) TF_R(24)
    x0 += ks2; x1 += k0 + 2u;
    TF_R(13) TF_R(15) TF_R(26) TF_R(6)
    x0 += k0; x1 += k1 + 3u;
    TF_R(17) TF_R(29) TF_R(16) TF_R(24)
    x0 += k1; x1 += ks2 + 4u;
    TF_R(13) TF_R(15) TF_R(26) TF_R(6)
    x0 += ks2; x1 += k0 + 5u;
#undef TF_R
    o0 = x0; o1 = x1;
}

// ---------- CSR build ----------
__global__ void k_deg(const int* __restrict__ dst, int* __restrict__ deg, int E) {
    int i = blockIdx.x * blockDim.x + threadIdx.x;
    if (i < E) atomicAdd(&deg[dst[i]], 1);
}
__global__ void k_scan(const int* __restrict__ deg, int* __restrict__ rowptr, int n) {
    __shared__ int sums[256];
    __shared__ int excl[257];
    const int T = 256;
    int t = threadIdx.x;
    int per = (n + T - 1) / T;
    int lo = t * per, hi = min(lo + per, n);
    int s = 0;
    for (int i = lo; i < hi; ++i) s += deg[i];
    sums[t] = s;
    __syncthreads();
    if (t == 0) { int run = 0; for (int i = 0; i < T; ++i) { excl[i] = run; run += sums[i]; } excl[T] = run; }
    __syncthreads();
    int run = excl[t];
    for (int i = lo; i < hi; ++i) { rowptr[i] = run; run += deg[i]; }
    if (t == 0) rowptr[n] = excl[T];
}
__global__ void k_scatter(const int* __restrict__ dst, const int* __restrict__ rowptr,
                          int* __restrict__ cursor, int* __restrict__ colidx, int E) {
    int i = blockIdx.x * blockDim.x + threadIdx.x;
    if (i >= E) return;
    int d = dst[i];
    int pos = atomicAdd(&cursor[d], 1);
    colidx[rowptr[d] + pos] = i;
}

// ---------- f32 GEMM: C[M,N] = A[M,K] @ B[K,N] (+bias), 128x128 tile ----------
__global__ __launch_bounds__(256) void gemm_f32(
    const float* __restrict__ A, int lda,
    const float* __restrict__ B, int ldb,
    float* __restrict__ C, int ldc,
    const float* __restrict__ bias,
    int M, int N, int K)
{
    __shared__ float As[16][132];
    __shared__ float Bs[16][132];
    const int tid = threadIdx.x;
    const int bm = blockIdx.y * 128, bn = blockIdx.x * 128;
    const int tx = tid & 15, ty = tid >> 4;
    const int ar0 = tid >> 2, ac = (tid & 3) << 2;
    const int br = tid >> 5, bc = (tid & 31) << 2;
    float acc[8][8] = {};
    for (int k0 = 0; k0 < K; k0 += 16) {
#pragma unroll
        for (int h = 0; h < 2; ++h) {
            int m = bm + ar0 + h * 64;
            float4 v = make_float4(0.f, 0.f, 0.f, 0.f);
            if (m < M) v = *(const float4*)(A + (size_t)m * lda + k0 + ac);
            As[ac + 0][ar0 + h * 64] = v.x; As[ac + 1][ar0 + h * 64] = v.y;
            As[ac + 2][ar0 + h * 64] = v.z; As[ac + 3][ar0 + h * 64] = v.w;
        }
#pragma unroll
        for (int h = 0; h < 2; ++h) {
            int n = bn + bc;
            int kr = k0 + br + h * 8;
            float4 v = make_float4(0.f, 0.f, 0.f, 0.f);
            if (n < N) v = *(const float4*)(B + (size_t)kr * ldb + n);
            *(float4*)&Bs[br + h * 8][bc] = v;
        }
        __syncthreads();
#pragma unroll
        for (int kk = 0; kk < 16; ++kk) {
            float a[8], b[8];
#pragma unroll
            for (int i = 0; i < 8; ++i) a[i] = As[kk][ty * 8 + i];
#pragma unroll
            for (int j = 0; j < 8; ++j) b[j] = Bs[kk][tx * 8 + j];
#pragma unroll
            for (int i = 0; i < 8; ++i)
#pragma unroll
                for (int j = 0; j < 8; ++j)
                    acc[i][j] = fmaf(a[i], b[j], acc[i][j]);
        }
        __syncthreads();
    }
#pragma unroll
    for (int i = 0; i < 8; ++i) {
        int m = bm + ty * 8 + i;
        if (m >= M) continue;
#pragma unroll
        for (int j = 0; j < 8; ++j) {
            int n = bn + tx * 8 + j;
            if (n < N) C[(size_t)m * ldc + n] = acc[i][j] + (bias ? bias[n] : 0.f);
        }
    }
}

// ---------- bf16 MFMA GEMM: C[M,1024] = A[M,512] @ BT[1024,512]^T (+bias) ----------
// 128x128 tile, BK=32, 4 waves (2x2), 64x64 per wave, global_load_lds 16B staging.
__global__ __launch_bounds__(256) void gemm_bf16(
    const unsigned short* __restrict__ A,    // [Mpad][512] bf16 bits
    const unsigned short* __restrict__ BT,   // [1024][512] bf16 bits (B transposed)
    float* __restrict__ C,                   // [M][1024]
    const float* __restrict__ bias,
    int M)
{
    constexpr int K = 512;
    __shared__ unsigned short As[128 * 32];
    __shared__ unsigned short Bs[128 * 32];
    const int tid = threadIdx.x;
    const int lane = tid & 63;
    const int w = tid >> 6, wr = w >> 1, wc = w & 1;
    const int bm = blockIdx.y * 128, bn = blockIdx.x * 128;
    const int fr = lane & 15, fq = lane >> 4;
    const int srow = tid >> 2;
    const int sbyte = (tid & 3) * 16;
    f32x4 acc[4][4] = {};
    const char* Ab = (const char*)A;
    const char* Bb = (const char*)BT;
    char* AsB = (char*)As;
    char* BsB = (char*)Bs;

    for (int k0 = 0; k0 < K; k0 += 32) {
        const char* ga0 = Ab + ((size_t)(bm + srow) * K + k0) * 2 + sbyte;
        const char* ga1 = Ab + ((size_t)(bm + 64 + srow) * K + k0) * 2 + sbyte;
        const char* gb0 = Bb + ((size_t)(bn + srow) * K + k0) * 2 + sbyte;
        const char* gb1 = Bb + ((size_t)(bn + 64 + srow) * K + k0) * 2 + sbyte;
        __builtin_amdgcn_global_load_lds((const __attribute__((address_space(1))) void*)ga0,
            (__attribute__((address_space(3))) void*)(AsB + tid * 16), 16, 0, 0);
        __builtin_amdgcn_global_load_lds((const __attribute__((address_space(1))) void*)ga1,
            (__attribute__((address_space(3))) void*)(AsB + 4096 + tid * 16), 16, 0, 0);
        __builtin_amdgcn_global_load_lds((const __attribute__((address_space(1))) void*)gb0,
            (__attribute__((address_space(3))) void*)(BsB + tid * 16), 16, 0, 0);
        __builtin_amdgcn_global_load_lds((const __attribute__((address_space(1))) void*)gb1,
            (__attribute__((address_space(3))) void*)(BsB + 4096 + tid * 16), 16, 0, 0);
        __syncthreads();
        short8 af[4], bfv[4];
#pragma unroll
        for (int m = 0; m < 4; ++m)
            af[m] = *(const short8*)(AsB + ((wr * 64 + m * 16 + fr) * 64 + fq * 16));
#pragma unroll
        for (int n = 0; n < 4; ++n)
            bfv[n] = *(const short8*)(BsB + ((wc * 64 + n * 16 + fr) * 64 + fq * 16));
#pragma unroll
        for (int m = 0; m < 4; ++m)
#pragma unroll
            for (int n = 0; n < 4; ++n)
                acc[m][n] = __builtin_amdgcn_mfma_f32_16x16x32_bf16(af[m], bfv[n], acc[m][n], 0, 0, 0);
        __syncthreads();
    }
#pragma unroll
    for (int m = 0; m < 4; ++m) {
#pragma unroll
        for (int i = 0; i < 4; ++i) {
            int row = bm + wr * 64 + m * 16 + fq * 4 + i;
            if (row >= M) continue;
#pragma unroll
            for (int n = 0; n < 4; ++n) {
                int col = bn + wc * 64 + n * 16 + fr;
                C[(size_t)row * 1024 + col] = acc[m][n][i] + (bias ? bias[col] : 0.f);
            }
        }
    }
}

// ---------- weight transpose + bf16 convert: WT[n][k] = bf16(W[k][n]) ----------
__global__ void k_wt(const float* __restrict__ W, unsigned short* __restrict__ WT) {
    int idx = blockIdx.x * blockDim.x + threadIdx.x;
    if (idx >= 1024 * 512) return;
    int nn = idx >> 9, kk = idx & 511;
    __hip_bfloat16 b = __float2bfloat16(W[kk * 1024 + nn]);
    WT[idx] = *(unsigned short*)&b;
}

// ---------- pack layer-1 weights: [256][512] = [W1a | W1e] ----------
__global__ void k_pack(const float* __restrict__ Wa, const float* __restrict__ We,
                       const float* __restrict__ Ra, const float* __restrict__ Re,
                       const float* __restrict__ ba, const float* __restrict__ be,
                       float* __restrict__ PW, float* __restrict__ PR, float* __restrict__ Pb) {
    int idx = blockIdx.x * blockDim.x + threadIdx.x;
    if (idx < 256 * 512) {
        int k = idx >> 9, c = idx & 511;
        PW[idx] = (c < 256) ? Wa[k * 256 + c] : We[k * 256 + (c - 256)];
        PR[idx] = (c < 256) ? Ra[k * 256 + c] : Re[k * 256 + (c - 256)];
    } else if (idx < 256 * 512 + 512) {
        int c = idx - 256 * 512;
        Pb[c] = (c < 256) ? ba[c] : be[c - 256];
    }
}

// ---------- tf = leaky_relu(feat[t] @ Wt + bt, 0.01) ----------
__global__ void k_tf(const float* __restrict__ feat, const int* __restrict__ tptr,
                     const float* __restrict__ Wt, const float* __restrict__ bt, float* __restrict__ tf)
{
    int j = threadIdx.x;
    if (j >= 512) return;
    int t = *tptr;
    float acc = 0.f;
    for (int k = 0; k < 256; ++k) acc = fmaf(feat[t * 256 + k], Wt[k * 512 + j], acc);
    acc += bt[j];
    tf[j] = acc >= 0.f ? acc : 0.01f * acc;
}

// ---------- el/er: per (n,h) dot over D (float4) ----------
__global__ void k_el_er(const float* __restrict__ h, int ldh, int hoff,
                        const float* __restrict__ al, const float* __restrict__ ar,
                        float* __restrict__ el, float* __restrict__ er,
                        int ldE, int eoff, int H, int D, int N)
{
    int idx = blockIdx.x * blockDim.x + threadIdx.x;
    if (idx >= N * H) return;
    int n = idx / H, hh = idx - n * H;
    const float* hp = h + (size_t)n * ldh + hoff + hh * D;
    const float* alp = al + hh * D;
    const float* arp = ar + hh * D;
    float sl = 0.f, sr = 0.f;
    for (int d = 0; d < D; d += 4) {
        float4 v = *(const float4*)(hp + d);
        float4 a4 = *(const float4*)(alp + d);
        float4 r4 = *(const float4*)(arp + d);
        sl = fmaf(v.x, a4.x, sl); sl = fmaf(v.y, a4.y, sl); sl = fmaf(v.z, a4.z, sl); sl = fmaf(v.w, a4.w, sl);
        sr = fmaf(v.x, r4.x, sr); sr = fmaf(v.y, r4.y, sr); sr = fmaf(v.z, r4.z, sr); sr = fmaf(v.w, r4.w, sr);
    }
    el[n * ldE + eoff + hh] = sl;
    er[n * ldE + eoff + hh] = sr;
}

// ---------- CSR edge softmax: write normalized alpha into ee[E][H] ----------
__global__ void k_softmax_csr(const float* __restrict__ el, const float* __restrict__ er,
                              const int* __restrict__ rowptr, const int* __restrict__ colidx,
                              const int* __restrict__ src,
                              float* __restrict__ ee, int H, int hshift, int total)
{
    int idx = blockIdx.x * blockDim.x + threadIdx.x;
    if (idx >= total) return;
    int n = idx >> hshift, hh = idx & (H - 1);
    float ern = er[n * H + hh];
    int i0 = rowptr[n], i1 = rowptr[n + 1];
    float mx = -INFINITY;
    for (int i = i0; i < i1; ++i) {
        float v = el[src[colidx[i]] * H + hh] + ern;
        v = v >= 0.f ? v : 0.2f * v;
        mx = fmaxf(mx, v);
    }
    float s = 0.f;
    for (int i = i0; i < i1; ++i) {
        int e = colidx[i];
        float v = el[src[e] * H + hh] + ern;
        v = v >= 0.f ? v : 0.2f * v;
        float ex = expf(v - mx);
        ee[(size_t)e * H + hh] = ex;
        s += ex;
    }
    for (int i = i0; i < i1; ++i) {
        int e = colidx[i];
        ee[(size_t)e * H + hh] /= s;
    }
}

// ---------- CSR aggregation: out[n,c] += sum_e alpha[e,hh] * h[src[e],c] ----------
__global__ void k_agg_csr(const float* __restrict__ alpha,
                          const int* __restrict__ rowptr, const int* __restrict__ colidx,
                          const int* __restrict__ src,
                          const float* __restrict__ h, int ldh, int hoff,
                          float* __restrict__ out, int ldo, int ooff,
                          int H, int dshift, int hdshift, int total)
{
    int idx = blockIdx.x * blockDim.x + threadIdx.x;
    if (idx >= total) return;
    int n = idx >> hdshift, c = idx & ((1 << hdshift) - 1);
    int hh = c >> dshift;
    float accv = out[(size_t)n * ldo + ooff + c];
    int i1 = rowptr[n + 1];
    for (int i = rowptr[n]; i < i1; ++i) {
        int e = colidx[i];
        accv = fmaf(alpha[(size_t)e * H + hh], h[(size_t)src[e] * ldh + hoff + c], accv);
    }
    out[(size_t)n * ldo + ooff + c] = accv;
}

// ---------- a2/e2 = lrelu(concat/swap + tf, 0.01); also bf16 copy of a2 ----------
__global__ void k_a2e2(const float* __restrict__ o1, const float* __restrict__ tf,
                       float* __restrict__ B, unsigned short* __restrict__ a2bf)
{
    int idx = blockIdx.x * blockDim.x + threadIdx.x;
    if (idx >= NGR * 1024) return;
    int n = idx >> 10, c = idx & 1023;
    float x;
    if (c < 512) x = o1[n * 512 + c];
    else { int cc = c - 512; x = o1[n * 512 + ((cc < 256) ? cc + 256 : cc - 256)]; }
    x += tf[c & 511];
    x = x >= 0.f ? x : 0.01f * x;
    B[idx] = x;
    if (c < 512) {
        __hip_bfloat16 hb = __float2bfloat16(x);
        a2bf[(size_t)n * 512 + c] = *(unsigned short*)&hb;
    }
}

// ---------- skinny GEMM: h2e = e2 @ W2e ; e3 = e2 @ R2e + b2e  (N=16 each) ----------
__global__ __launch_bounds__(256) void gemm_e(
    const float* __restrict__ A,    // e2 = a2e2+512, lda=1024
    const float* __restrict__ We, const float* __restrict__ Re, const float* __restrict__ be,
    float* __restrict__ h2e, float* __restrict__ e3, int M)
{
    __shared__ float As[8 * 512];
    int tid = threadIdx.x;
    int m0 = blockIdx.x * 8;
    for (int i = tid; i < 8 * 128; i += 256) {
        int row = i >> 7, c4 = (i & 127) << 2;
        int m = m0 + row;
        float4 v = make_float4(0.f, 0.f, 0.f, 0.f);
        if (m < M) v = *(const float4*)(A + (size_t)m * 1024 + c4);
        *(float4*)(As + row * 512 + c4) = v;
    }
    __syncthreads();
    int r = tid >> 5, j = tid & 31;
    const float* B = (j < 16) ? We : Re;
    int jj = j & 15;
    const float* ar = As + r * 512;
    float acc = 0.f;
#pragma unroll 8
    for (int k = 0; k < 512; ++k) acc = fmaf(ar[k], B[k * 16 + jj], acc);
    int m = m0 + r;
    if (m < M) {
        if (j < 16) h2e[(size_t)m * 16 + jj] = acc;
        else        e3[(size_t)m * 16 + jj] = acc + be[jj];
    }
}

// ---------- attr mean: two-stage coalesced reduction ----------
__global__ __launch_bounds__(256) void k_attr_part(const float* __restrict__ a3, float* __restrict__ part)
{
    int b = blockIdx.x;
    int t = threadIdx.x;
    float r0 = 0, r1 = 0, r2 = 0, r3 = 0;
    int n0 = b * 157, n1 = min(n0 + 157, NGR);
    for (int n = n0; n < n1; ++n) {
        const float* row = a3 + (size_t)n * 1024;
        r0 += row[t]; r1 += row[t + 256]; r2 += row[t + 512]; r3 += row[t + 768];
    }
    part[(size_t)b * 1024 + t] = r0;
    part[(size_t)b * 1024 + t + 256] = r1;
    part[(size_t)b * 1024 + t + 512] = r2;
    part[(size_t)b * 1024 + t + 768] = r3;
}
__global__ void k_attr_fin(const float* __restrict__ part, float* __restrict__ attr)
{
    int c = blockIdx.x * blockDim.x + threadIdx.x;
    if (c >= 1024) return;
    float s = 0.f;
    for (int b = 0; b < 64; ++b) s += part[(size_t)b * 1024 + c];
    attr[c] = s / (float)NGR;
}

// ---------- node_attr = lrelu(attr,0.01) @ Wo + bo (written twice) ----------
__global__ void k_nattr(const float* __restrict__ attr, const float* __restrict__ Wo,
                        const float* __restrict__ bo, float* __restrict__ out)
{
    int idx = blockIdx.x * blockDim.x + threadIdx.x;
    if (idx >= 16 * 256) return;
    int i = idx >> 8, j = idx & 255;
    float acc = 0.f;
    for (int d = 0; d < 64; ++d) {
        float v = attr[i * 64 + d];
        v = v >= 0.f ? v : 0.01f * v;
        acc = fmaf(v, Wo[d * 256 + j], acc);
    }
    acc += bo[j];
    out[idx] = acc;
    out[4096 + idx] = acc;
}

// ---------- probs[r,:] = softmax over n of e3[n,r] ----------
__global__ void k_probs(const float* __restrict__ e3, float* __restrict__ probs)
{
    int r = blockIdx.x;
    int tid = threadIdx.x;
    __shared__ float red[256];
    __shared__ float smx, ssum;
    float mx = -INFINITY;
    for (int n = tid; n < NGR; n += 256) mx = fmaxf(mx, e3[n * 16 + r]);
    red[tid] = mx; __syncthreads();
    for (int s = 128; s > 0; s >>= 1) { if (tid < s) red[tid] = fmaxf(red[tid], red[tid + s]); __syncthreads(); }
    if (tid == 0) smx = red[0];
    __syncthreads();
    float sum = 0.f;
    for (int n = tid; n < NGR; n += 256) sum += expf(e3[n * 16 + r] - smx);
    red[tid] = sum; __syncthreads();
    for (int s = 128; s > 0; s >>= 1) { if (tid < s) red[tid] += red[tid + s]; __syncthreads(); }
    if (tid == 0) ssum = red[0];
    __syncthreads();
    for (int n = tid; n < NGR; n += 256) probs[r * NGR + n] = expf(e3[n * 16 + r] - smx) / ssum;
}

// ---------- sampler: JAX-exact (threefry partitionable: bits = o0^o1, count=(0,f)) ----------
#define TINYF 1.17549435e-38f
__global__ __launch_bounds__(256) void k_sample(const float* __restrict__ probs,
                                                const int* __restrict__ tptr,
                                                float* __restrict__ out_edges)
{
    int r = blockIdx.x;
    int tid = threadIdx.x;
    __shared__ int sel[5];
    __shared__ float s_red[256];
    __shared__ int s_redi[256];
    __shared__ float sh_vmax, sh_den;
    __shared__ u32 fk0, fk1;
    int target = *tptr;
    if (tid == 0) { sel[0] = target; out_edges[r * 5 + 0] = (float)target; }
    __syncthreads();
    const float* p = probs + r * NGR;

    for (int it = 0; it < 4; ++it) {
        int nsel = it + 1;
        if (tid == 0) {
            u32 o0, o1;
            threefry(0u, 42u, 0u, (u32)it, o0, o1);
            fk0 = o0; fk1 = o1;
        }
        float vmax = -INFINITY;
        for (int j = tid; j < NGR; j += 256) {
            bool masked = false;
            for (int q = 0; q < nsel; ++q) masked |= (sel[q] == j);
            float m = masked ? 0.f : 1.f;
            float v = p[j] * m - 10000.0f * (1.0f - m);
            vmax = fmaxf(vmax, v);
        }
        s_red[tid] = vmax; __syncthreads();
        for (int s = 128; s > 0; s >>= 1) { if (tid < s) s_red[tid] = fmaxf(s_red[tid], s_red[tid + s]); __syncthreads(); }
        if (tid == 0) sh_vmax = s_red[0];
        __syncthreads();
        float sum = 0.f;
        for (int j = tid; j < NGR; j += 256) {
            bool masked = false;
            for (int q = 0; q < nsel; ++q) masked |= (sel[q] == j);
            float m = masked ? 0.f : 1.f;
            sum += expf((p[j] - sh_vmax) * m) * m;
        }
        s_red[tid] = sum; __syncthreads();
        for (int s = 128; s > 0; s >>= 1) { if (tid < s) s_red[tid] += s_red[tid + s]; __syncthreads(); }
        if (tid == 0) sh_den = s_red[0] + 1e-8f;
        __syncthreads();
        float best = -INFINITY;
        int bidx = 0x7FFFFFFF;
        float den = sh_den, vm = sh_vmax;
        for (int j = tid; j < NGR; j += 256) {
            bool masked = false;
            for (int q = 0; q < nsel; ++q) masked |= (sel[q] == j);
            float m = masked ? 0.f : 1.f;
            float ex = expf((p[j] - vm) * m) * m;
            float pj = ex / den;
            float lg = logf(fmaxf(pj, 1e-30f));
            u32 o0, o1;
            threefry(fk0, fk1, 0u, (u32)(r * NGR + j), o0, o1);
            u32 b = o0 ^ o1;
            float fl = __uint_as_float((b >> 9) | 0x3F800000u) - 1.0f;
            float u = fmaxf(TINYF, fl + TINYF);
            float g = -logf(-logf(u));
            float sc = g + lg;
            if (sc > best || (sc == best && j < bidx)) { best = sc; bidx = j; }
        }
        s_red[tid] = best; s_redi[tid] = bidx; __syncthreads();
        for (int s = 128; s > 0; s >>= 1) {
            if (tid < s) {
                float ov = s_red[tid + s]; int oi = s_redi[tid + s];
                if (ov > s_red[tid] || (ov == s_red[tid] && oi < s_redi[tid])) { s_red[tid] = ov; s_redi[tid] = oi; }
            }
            __syncthreads();
        }
        if (tid == 0) { sel[it + 1] = s_redi[0]; out_edges[r * 5 + it + 1] = (float)s_redi[0]; }
        __syncthreads();
    }
}

extern "C" void kernel_launch(void* const* d_in, const int* in_sizes, int n_in,
                              void* d_out, int out_size, void* d_ws, size_t ws_size,
                              hipStream_t stream)
{
    const float* feat = (const float*)d_in[0];
    const int* src = (const int*)d_in[1];
    const int* dst = (const int*)d_in[2];
    const int* tptr = (const int*)d_in[3];
    const float* W1a = (const float*)d_in[4];  const float* al1a = (const float*)d_in[5];
    const float* ar1a = (const float*)d_in[6]; const float* R1a = (const float*)d_in[7];
    const float* b1a = (const float*)d_in[8];
    const float* W1e = (const float*)d_in[9];  const float* al1e = (const float*)d_in[10];
    const float* ar1e = (const float*)d_in[11]; const float* R1e = (const float*)d_in[12];
    const float* b1e = (const float*)d_in[13];
    const float* W2a = (const float*)d_in[14]; const float* al2a = (const float*)d_in[15];
    const float* ar2a = (const float*)d_in[16]; const float* R2a = (const float*)d_in[17];
    const float* b2a = (const float*)d_in[18];
    const float* W2e = (const float*)d_in[19];
    const float* R2e = (const float*)d_in[22];
    const float* b2e = (const float*)d_in[23];
    const float* Wt = (const float*)d_in[24];  const float* bt = (const float*)d_in[25];
    const float* Wo = (const float*)d_in[26];  const float* bo = (const float*)d_in[27];
    const int E = in_sizes[1];
    const int N = NGR;

    float* ws = (float*)d_ws;
    size_t off = (size_t)N * 1024;   // region A: h1|o1 (phase 1) then h2a (phase 2)
    float* h1 = ws;
    float* o1 = ws + (size_t)N * 512;
    float* h2a = ws;
    auto alloc = [&](size_t n) { float* p = ws + off; off += (n + 3) & ~(size_t)3; return p; };
    float* a2e2 = alloc((size_t)N * 1024);
    float* o2a  = alloc((size_t)N * 1024);
    float* tf   = alloc(512);
    float* attr = alloc(1024);
    float* part = alloc(64 * 1024);
    float* el1  = alloc((size_t)N * 8);
    float* er1  = alloc((size_t)N * 8);
    float* el2a = alloc((size_t)N * 4);
    float* er2a = alloc((size_t)N * 4);
    float* el2e = alloc(N);
    float* er2e = alloc(N);
    float* h2e  = alloc((size_t)N * 16);
    float* e3   = alloc((size_t)N * 16);
    float* ee1  = alloc((size_t)E * 8);
    float* ee2a = alloc((size_t)E * 4);
    float* ee2e = alloc(E);
    float* packW = alloc(256 * 512);
    float* packR = alloc(256 * 512);
    float* packb = alloc(512);
    unsigned short* a2bf = (unsigned short*)alloc((size_t)10112 * 512 / 2);
    unsigned short* WTa  = (unsigned short*)alloc(1024 * 512 / 2);
    unsigned short* WTr  = (unsigned short*)alloc(1024 * 512 / 2);
    int* deg    = (int*)alloc(N);
    int* rowptr = (int*)alloc(N + 1);
    int* cursor = (int*)alloc(N);
    int* colidx = (int*)alloc(E);

    float* out = (float*)d_out;
    float* out_edges = out + 8192;
    float* out_probs = out + 8272;

    dim3 blk(256);

    // CSR build
    hipMemsetAsync(deg, 0, N * sizeof(int), stream);
    hipMemsetAsync(cursor, 0, N * sizeof(int), stream);
    k_deg<<<(E + 255) / 256, blk, 0, stream>>>(dst, deg, E);
    k_scan<<<1, blk, 0, stream>>>(deg, rowptr, N);
    k_scatter<<<(E + 255) / 256, blk, 0, stream>>>(dst, rowptr, cursor, colidx, E);

    // weight prep
    k_tf<<<1, 512, 0, stream>>>(feat, tptr, Wt, bt, tf);
    k_pack<<<(256 * 512 + 512 + 255) / 256, blk, 0, stream>>>(W1a, W1e, R1a, R1e, b1a, b1e, packW, packR, packb);
    k_wt<<<(1024 * 512 + 255) / 256, blk, 0, stream>>>(W2a, WTa);
    k_wt<<<(1024 * 512 + 255) / 256, blk, 0, stream>>>(R2a, WTr);

    // layer 1 (f32, precision-critical path)
    gemm_f32<<<dim3(4, 79), blk, 0, stream>>>(feat, 256, packW, 512, h1, 512, nullptr, N, 512, 256);
    gemm_f32<<<dim3(4, 79), blk, 0, stream>>>(feat, 256, packR, 512, o1, 512, packb, N, 512, 256);
    k_el_er<<<(N * 4 + 255) / 256, blk, 0, stream>>>(h1, 512, 0, al1a, ar1a, el1, er1, 8, 0, 4, 64, N);
    k_el_er<<<(N * 4 + 255) / 256, blk, 0, stream>>>(h1, 512, 256, al1e, ar1e, el1, er1, 8, 4, 4, 64, N);
    k_softmax_csr<<<(N * 8 + 255) / 256, blk, 0, stream>>>(el1, er1, rowptr, colidx, src, ee1, 8, 3, N * 8);
    k_agg_csr<<<(N * 512 + 255) / 256, blk, 0, stream>>>(ee1, rowptr, colidx, src,
                                                         h1, 512, 0, o1, 512, 0, 8, 6, 9, N * 512);
    k_a2e2<<<(N * 1024 + 255) / 256, blk, 0, stream>>>(o1, tf, a2e2, a2bf);

    // layer 2a (bf16 MFMA, lenient path)
    gemm_bf16<<<dim3(8, 79), blk, 0, stream>>>(a2bf, WTa, h2a, nullptr, N);
    gemm_bf16<<<dim3(8, 79), blk, 0, stream>>>(a2bf, WTr, o2a, b2a, N);

    // layer 2e (f32, precision-critical)
    gemm_e<<<(N + 7) / 8, blk, 0, stream>>>(a2e2 + 512, W2e, R2e, b2e, h2e, e3, N);

    k_el_er<<<(N * 4 + 255) / 256, blk, 0, stream>>>(h2a, 1024, 0, al2a, ar2a, el2a, er2a, 4, 0, 4, 256, N);
    k_el_er<<<(N + 255) / 256, blk, 0, stream>>>(h2e, 16, 0, d_in[20] ? (const float*)d_in[20] : nullptr,
                                                 (const float*)d_in[21], el2e, er2e, 1, 0, 1, 16, N);
    k_softmax_csr<<<(N * 4 + 255) / 256, blk, 0, stream>>>(el2a, er2a, rowptr, colidx, src, ee2a, 4, 2, N * 4);
    k_softmax_csr<<<(N + 255) / 256, blk, 0, stream>>>(el2e, er2e, rowptr, colidx, src, ee2e, 1, 0, N);
    k_agg_csr<<<(N * 1024 + 255) / 256, blk, 0, stream>>>(ee2a, rowptr, colidx, src,
                                                          h2a, 1024, 0, o2a, 1024, 0, 4, 8, 10, N * 1024);
    k_agg_csr<<<(N * 16 + 255) / 256, blk, 0, stream>>>(ee2e, rowptr, colidx, src,
                                                        h2e, 16, 0, e3, 16, 0, 1, 4, 4, N * 16);

    // outputs
    k_attr_part<<<64, blk, 0, stream>>>(o2a, part);
    k_attr_fin<<<4, blk, 0, stream>>>(part, attr);
    k_nattr<<<16, blk, 0, stream>>>(attr, Wo, bo, out);
    k_probs<<<16, blk, 0, stream>>>(e3, out_probs);
    k_sample<<<16, blk, 0, stream>>>(out_probs, tptr, out_edges);
}

// Round 4
// 628.106 us; speedup vs baseline: 2.6523x; 1.5378x over previous
//
#include <hip/hip_runtime.h>
#include <hip/hip_bf16.h>

#define NGR 10000
typedef unsigned int u32;
typedef __attribute__((ext_vector_type(8))) short short8;
typedef __attribute__((ext_vector_type(4))) float f32x4;

// ---------- threefry2x32 (JAX-exact) ----------
__device__ __forceinline__ void threefry(u32 k0, u32 k1, u32 c0, u32 c1, u32& o0, u32& o1) {
    u32 ks2 = k0 ^ k1 ^ 0x1BD11BDAu;
    u32 x0 = c0 + k0, x1 = c1 + k1;
#define TF_R(r) { x0 += x1; x1 = (x1 << r) | (x1 >> (32 - r)); x1 ^= x0; }
    TF_R(13) TF_R(15) TF_R(26) TF_R(6)
    x0 += k1; x1 += ks2 + 1u;
    TF_R(17) TF_R(29) TF_R(16) TF_R(24)
    x0 += ks2; x1 += k0 + 2u;
    TF_R(13) TF_R(15) TF_R(26) TF_R(6)
    x0 += k0; x1 += k1 + 3u;
    TF_R(17) TF_R(29) TF_R(16) TF_R(24)
    x0 += k1; x1 += ks2 + 4u;
    TF_R(13) TF_R(15) TF_R(26) TF_R(6)
    x0 += ks2; x1 += k0 + 5u;
#undef TF_R
    o0 = x0; o1 = x1;
}

// ---------- CSR build ----------
__global__ void k_deg(const int* __restrict__ dst, int* __restrict__ deg, int E) {
    int i = blockIdx.x * blockDim.x + threadIdx.x;
    if (i < E) atomicAdd(&deg[dst[i]], 1);
}
__global__ void k_scan(const int* __restrict__ deg, int* __restrict__ rowptr, int n) {
    __shared__ int sums[256];
    __shared__ int excl[257];
    const int T = 256;
    int t = threadIdx.x;
    int per = (n + T - 1) / T;
    int lo = t * per, hi = min(lo + per, n);
    int s = 0;
    for (int i = lo; i < hi; ++i) s += deg[i];
    sums[t] = s;
    __syncthreads();
    if (t == 0) { int run = 0; for (int i = 0; i < T; ++i) { excl[i] = run; run += sums[i]; } excl[T] = run; }
    __syncthreads();
    int run = excl[t];
    for (int i = lo; i < hi; ++i) { rowptr[i] = run; run += deg[i]; }
    if (t == 0) rowptr[n] = excl[T];
}
__global__ void k_scatter(const int* __restrict__ dst, const int* __restrict__ rowptr,
                          int* __restrict__ cursor, int* __restrict__ colidx, int E) {
    int i = blockIdx.x * blockDim.x + threadIdx.x;
    if (i >= E) return;
    int d = dst[i];
    int pos = atomicAdd(&cursor[d], 1);
    colidx[rowptr[d] + pos] = i;
}

// ---------- f32 GEMM: C[M,N] = A[M,K] @ B[K,N] (+bias), 128x128 tile ----------
__global__ __launch_bounds__(256) void gemm_f32(
    const float* __restrict__ A, int lda,
    const float* __restrict__ B, int ldb,
    float* __restrict__ C, int ldc,
    const float* __restrict__ bias,
    int M, int N, int K)
{
    __shared__ float As[16][132];
    __shared__ float Bs[16][132];
    const int tid = threadIdx.x;
    const int bm = blockIdx.y * 128, bn = blockIdx.x * 128;
    const int tx = tid & 15, ty = tid >> 4;
    const int ar0 = tid >> 2, ac = (tid & 3) << 2;
    const int br = tid >> 5, bc = (tid & 31) << 2;
    float acc[8][8] = {};
    for (int k0 = 0; k0 < K; k0 += 16) {
#pragma unroll
        for (int h = 0; h < 2; ++h) {
            int m = bm + ar0 + h * 64;
            float4 v = make_float4(0.f, 0.f, 0.f, 0.f);
            if (m < M) v = *(const float4*)(A + (size_t)m * lda + k0 + ac);
            As[ac + 0][ar0 + h * 64] = v.x; As[ac + 1][ar0 + h * 64] = v.y;
            As[ac + 2][ar0 + h * 64] = v.z; As[ac + 3][ar0 + h * 64] = v.w;
        }
#pragma unroll
        for (int h = 0; h < 2; ++h) {
            int n = bn + bc;
            int kr = k0 + br + h * 8;
            float4 v = make_float4(0.f, 0.f, 0.f, 0.f);
            if (n < N) v = *(const float4*)(B + (size_t)kr * ldb + n);
            *(float4*)&Bs[br + h * 8][bc] = v;
        }
        __syncthreads();
#pragma unroll
        for (int kk = 0; kk < 16; ++kk) {
            float a[8], b[8];
#pragma unroll
            for (int i = 0; i < 8; ++i) a[i] = As[kk][ty * 8 + i];
#pragma unroll
            for (int j = 0; j < 8; ++j) b[j] = Bs[kk][tx * 8 + j];
#pragma unroll
            for (int i = 0; i < 8; ++i)
#pragma unroll
                for (int j = 0; j < 8; ++j)
                    acc[i][j] = fmaf(a[i], b[j], acc[i][j]);
        }
        __syncthreads();
    }
#pragma unroll
    for (int i = 0; i < 8; ++i) {
        int m = bm + ty * 8 + i;
        if (m >= M) continue;
#pragma unroll
        for (int j = 0; j < 8; ++j) {
            int n = bn + tx * 8 + j;
            if (n < N) C[(size_t)m * ldc + n] = acc[i][j] + (bias ? bias[n] : 0.f);
        }
    }
}

// ---------- bf16 MFMA GEMM: C[M,Ncols] = A[M,512] @ BT[Ncols,512]^T + bias ----------
__global__ __launch_bounds__(256) void gemm_bf16(
    const unsigned short* __restrict__ A,    // [Mpad][512] bf16 bits
    const unsigned short* __restrict__ BT,   // [Ncols][512] bf16 bits
    float* __restrict__ C,                   // [M][Ncols]
    const float* __restrict__ bias,          // [Ncols]
    int M, int Ncols)
{
    constexpr int K = 512;
    __shared__ unsigned short As[128 * 32];
    __shared__ unsigned short Bs[128 * 32];
    const int tid = threadIdx.x;
    const int lane = tid & 63;
    const int w = tid >> 6, wr = w >> 1, wc = w & 1;
    const int bm = blockIdx.y * 128, bn = blockIdx.x * 128;
    const int fr = lane & 15, fq = lane >> 4;
    const int srow = tid >> 2;
    const int sbyte = (tid & 3) * 16;
    f32x4 acc[4][4] = {};
    const char* Ab = (const char*)A;
    const char* Bb = (const char*)BT;
    char* AsB = (char*)As;
    char* BsB = (char*)Bs;

    for (int k0 = 0; k0 < K; k0 += 32) {
        const char* ga0 = Ab + ((size_t)(bm + srow) * K + k0) * 2 + sbyte;
        const char* ga1 = Ab + ((size_t)(bm + 64 + srow) * K + k0) * 2 + sbyte;
        const char* gb0 = Bb + ((size_t)(bn + srow) * K + k0) * 2 + sbyte;
        const char* gb1 = Bb + ((size_t)(bn + 64 + srow) * K + k0) * 2 + sbyte;
        __builtin_amdgcn_global_load_lds((const __attribute__((address_space(1))) void*)ga0,
            (__attribute__((address_space(3))) void*)(AsB + tid * 16), 16, 0, 0);
        __builtin_amdgcn_global_load_lds((const __attribute__((address_space(1))) void*)ga1,
            (__attribute__((address_space(3))) void*)(AsB + 4096 + tid * 16), 16, 0, 0);
        __builtin_amdgcn_global_load_lds((const __attribute__((address_space(1))) void*)gb0,
            (__attribute__((address_space(3))) void*)(BsB + tid * 16), 16, 0, 0);
        __builtin_amdgcn_global_load_lds((const __attribute__((address_space(1))) void*)gb1,
            (__attribute__((address_space(3))) void*)(BsB + 4096 + tid * 16), 16, 0, 0);
        __syncthreads();
        short8 af[4], bfv[4];
#pragma unroll
        for (int m = 0; m < 4; ++m)
            af[m] = *(const short8*)(AsB + ((wr * 64 + m * 16 + fr) * 64 + fq * 16));
#pragma unroll
        for (int n = 0; n < 4; ++n)
            bfv[n] = *(const short8*)(BsB + ((wc * 64 + n * 16 + fr) * 64 + fq * 16));
#pragma unroll
        for (int m = 0; m < 4; ++m)
#pragma unroll
            for (int n = 0; n < 4; ++n)
                acc[m][n] = __builtin_amdgcn_mfma_f32_16x16x32_bf16(af[m], bfv[n], acc[m][n], 0, 0, 0);
        __syncthreads();
    }
#pragma unroll
    for (int m = 0; m < 4; ++m) {
#pragma unroll
        for (int i = 0; i < 4; ++i) {
            int row = bm + wr * 64 + m * 16 + fq * 4 + i;
            if (row >= M) continue;
#pragma unroll
            for (int n = 0; n < 4; ++n) {
                int col = bn + wc * 64 + n * 16 + fr;
                C[(size_t)row * Ncols + col] = acc[m][n][i] + bias[col];
            }
        }
    }
}

// ---------- weight transpose + bf16 convert: WT[n][k] = bf16(W[k][n]) ----------
__global__ void k_wt(const float* __restrict__ W, unsigned short* __restrict__ WT) {
    int idx = blockIdx.x * blockDim.x + threadIdx.x;
    if (idx >= 1024 * 512) return;
    int nn = idx >> 9, kk = idx & 511;
    __hip_bfloat16 b = __float2bfloat16(W[kk * 1024 + nn]);
    WT[idx] = *(unsigned short*)&b;
}
__global__ void k_bias2(const float* __restrict__ b2a, float* __restrict__ bias2) {
    int c = blockIdx.x * blockDim.x + threadIdx.x;
    if (c < 2048) bias2[c] = (c < 1024) ? 0.f : b2a[c - 1024];
}

// ---------- pack layer-1 weights: PW[256][1024] = [W1a|W1e|R1a|R1e] ----------
__global__ void k_pack(const float* __restrict__ Wa, const float* __restrict__ We,
                       const float* __restrict__ Ra, const float* __restrict__ Re,
                       const float* __restrict__ ba, const float* __restrict__ be,
                       float* __restrict__ PW, float* __restrict__ Pb) {
    int idx = blockIdx.x * blockDim.x + threadIdx.x;
    if (idx < 256 * 1024) {
        int k = idx >> 10, c = idx & 1023;
        float v;
        if (c < 256) v = Wa[k * 256 + c];
        else if (c < 512) v = We[k * 256 + (c - 256)];
        else if (c < 768) v = Ra[k * 256 + (c - 512)];
        else v = Re[k * 256 + (c - 768)];
        PW[idx] = v;
    } else if (idx < 256 * 1024 + 1024) {
        int c = idx - 256 * 1024;
        Pb[c] = (c < 512) ? 0.f : ((c < 768) ? ba[c - 512] : be[c - 768]);
    }
}

// ---------- tf = leaky_relu(feat[t] @ Wt + bt, 0.01) ----------
__global__ void k_tf(const float* __restrict__ feat, const int* __restrict__ tptr,
                     const float* __restrict__ Wt, const float* __restrict__ bt, float* __restrict__ tf)
{
    int j = threadIdx.x;
    if (j >= 512) return;
    int t = *tptr;
    float acc = 0.f;
    for (int k = 0; k < 256; ++k) acc = fmaf(feat[t * 256 + k], Wt[k * 512 + j], acc);
    acc += bt[j];
    tf[j] = acc >= 0.f ? acc : 0.01f * acc;
}

// ---------- el/er: per (n,h) dot over D (float4) ----------
__global__ void k_el_er(const float* __restrict__ h, int ldh, int hoff,
                        const float* __restrict__ al, const float* __restrict__ ar,
                        float* __restrict__ el, float* __restrict__ er,
                        int ldE, int eoff, int H, int D, int N)
{
    int idx = blockIdx.x * blockDim.x + threadIdx.x;
    if (idx >= N * H) return;
    int n = idx / H, hh = idx - n * H;
    const float* hp = h + (size_t)n * ldh + hoff + hh * D;
    const float* alp = al + hh * D;
    const float* arp = ar + hh * D;
    float sl = 0.f, sr = 0.f;
    for (int d = 0; d < D; d += 4) {
        float4 v = *(const float4*)(hp + d);
        float4 a4 = *(const float4*)(alp + d);
        float4 r4 = *(const float4*)(arp + d);
        sl = fmaf(v.x, a4.x, sl); sl = fmaf(v.y, a4.y, sl); sl = fmaf(v.z, a4.z, sl); sl = fmaf(v.w, a4.w, sl);
        sr = fmaf(v.x, r4.x, sr); sr = fmaf(v.y, r4.y, sr); sr = fmaf(v.z, r4.z, sr); sr = fmaf(v.w, r4.w, sr);
    }
    el[n * ldE + eoff + hh] = sl;
    er[n * ldE + eoff + hh] = sr;
}

// ---------- CSR edge softmax: write normalized alpha into ee[E][H] ----------
__global__ void k_softmax_csr(const float* __restrict__ el, const float* __restrict__ er,
                              const int* __restrict__ rowptr, const int* __restrict__ colidx,
                              const int* __restrict__ src,
                              float* __restrict__ ee, int H, int hshift, int total)
{
    int idx = blockIdx.x * blockDim.x + threadIdx.x;
    if (idx >= total) return;
    int n = idx >> hshift, hh = idx & (H - 1);
    float ern = er[n * H + hh];
    int i0 = rowptr[n], i1 = rowptr[n + 1];
    float mx = -INFINITY;
    for (int i = i0; i < i1; ++i) {
        float v = el[src[colidx[i]] * H + hh] + ern;
        v = v >= 0.f ? v : 0.2f * v;
        mx = fmaxf(mx, v);
    }
    float s = 0.f;
    for (int i = i0; i < i1; ++i) {
        int e = colidx[i];
        float v = el[src[e] * H + hh] + ern;
        v = v >= 0.f ? v : 0.2f * v;
        float ex = expf(v - mx);
        ee[(size_t)e * H + hh] = ex;
        s += ex;
    }
    for (int i = i0; i < i1; ++i) {
        int e = colidx[i];
        ee[(size_t)e * H + hh] /= s;
    }
}

// ---------- CSR aggregation (float4): out4[n,c4] += sum_e alpha[e,hh]*h4[src[e],c4] ----------
__global__ void k_agg_csr4(const float* __restrict__ alpha,
                           const int* __restrict__ rowptr, const int* __restrict__ colidx,
                           const int* __restrict__ src,
                           const float* __restrict__ h, int ldh4, int hoff4,
                           float* __restrict__ out, int ldo4, int ooff4,
                           int H, int dshift4, int hdshift4, int total)
{
    int idx = blockIdx.x * blockDim.x + threadIdx.x;
    if (idx >= total) return;
    int n = idx >> hdshift4, c4 = idx & ((1 << hdshift4) - 1);
    int hh = c4 >> dshift4;
    const float4* h4 = (const float4*)h;
    float4* out4 = (float4*)out;
    float4 acc = out4[(size_t)n * ldo4 + ooff4 + c4];
    int i1 = rowptr[n + 1];
    for (int i = rowptr[n]; i < i1; ++i) {
        int e = colidx[i];
        float a = alpha[(size_t)e * H + hh];
        float4 hv = h4[(size_t)src[e] * ldh4 + hoff4 + c4];
        acc.x = fmaf(a, hv.x, acc.x); acc.y = fmaf(a, hv.y, acc.y);
        acc.z = fmaf(a, hv.z, acc.z); acc.w = fmaf(a, hv.w, acc.w);
    }
    out4[(size_t)n * ldo4 + ooff4 + c4] = acc;
}

// ---------- a2/e2 = lrelu(concat/swap + tf, 0.01); bf16 copy of a2 (float4) ----------
__global__ void k_a2e2(const float* __restrict__ h1o1, const float* __restrict__ tf,
                       float* __restrict__ B, unsigned short* __restrict__ a2bf)
{
    int idx = blockIdx.x * blockDim.x + threadIdx.x;
    if (idx >= NGR * 256) return;
    int n = idx >> 8, c4 = idx & 255;
    int c = c4 << 2;
    const float* o = h1o1 + (size_t)n * 1024 + 512;
    float4 x;
    if (c < 512) x = *(const float4*)(o + c);
    else { int cc = c - 512; x = *(const float4*)(o + ((cc < 256) ? cc + 256 : cc - 256)); }
    float4 t4 = *(const float4*)(tf + (c & 511));
    x.x += t4.x; x.y += t4.y; x.z += t4.z; x.w += t4.w;
    x.x = x.x >= 0.f ? x.x : 0.01f * x.x;
    x.y = x.y >= 0.f ? x.y : 0.01f * x.y;
    x.z = x.z >= 0.f ? x.z : 0.01f * x.z;
    x.w = x.w >= 0.f ? x.w : 0.01f * x.w;
    *(float4*)(B + (size_t)n * 1024 + c) = x;
    if (c < 512) {
        __hip_bfloat16 b0 = __float2bfloat16(x.x), b1 = __float2bfloat16(x.y);
        __hip_bfloat16 b2 = __float2bfloat16(x.z), b3 = __float2bfloat16(x.w);
        ushort4 u4;
        u4.x = *(unsigned short*)&b0; u4.y = *(unsigned short*)&b1;
        u4.z = *(unsigned short*)&b2; u4.w = *(unsigned short*)&b3;
        *(ushort4*)(a2bf + (size_t)n * 512 + c) = u4;
    }
}

// ---------- skinny GEMM: h2e = e2 @ W2e ; e3 = e2 @ R2e + b2e  (N=16 each) ----------
__global__ __launch_bounds__(256) void gemm_e(
    const float* __restrict__ A,    // e2 = a2e2+512, lda=1024
    const float* __restrict__ We, const float* __restrict__ Re, const float* __restrict__ be,
    float* __restrict__ h2e, float* __restrict__ e3, int M)
{
    __shared__ float As[8 * 512];
    int tid = threadIdx.x;
    int m0 = blockIdx.x * 8;
    for (int i = tid; i < 8 * 128; i += 256) {
        int row = i >> 7, c4 = (i & 127) << 2;
        int m = m0 + row;
        float4 v = make_float4(0.f, 0.f, 0.f, 0.f);
        if (m < M) v = *(const float4*)(A + (size_t)m * 1024 + c4);
        *(float4*)(As + row * 512 + c4) = v;
    }
    __syncthreads();
    int r = tid >> 5, j = tid & 31;
    const float* B = (j < 16) ? We : Re;
    int jj = j & 15;
    const float* ar = As + r * 512;
    float acc = 0.f;
#pragma unroll 8
    for (int k = 0; k < 512; ++k) acc = fmaf(ar[k], B[k * 16 + jj], acc);
    int m = m0 + r;
    if (m < M) {
        if (j < 16) h2e[(size_t)m * 16 + jj] = acc;
        else        e3[(size_t)m * 16 + jj] = acc + be[jj];
    }
}

// ---------- attr mean: two-stage coalesced reduction ----------
__global__ __launch_bounds__(256) void k_attr_part(const float* __restrict__ a3, int ld, float* __restrict__ part)
{
    int b = blockIdx.x;
    int t = threadIdx.x;
    float r0 = 0, r1 = 0, r2 = 0, r3 = 0;
    int n0 = b * 157, n1 = min(n0 + 157, NGR);
    for (int n = n0; n < n1; ++n) {
        const float* row = a3 + (size_t)n * ld;
        r0 += row[t]; r1 += row[t + 256]; r2 += row[t + 512]; r3 += row[t + 768];
    }
    part[(size_t)b * 1024 + t] = r0;
    part[(size_t)b * 1024 + t + 256] = r1;
    part[(size_t)b * 1024 + t + 512] = r2;
    part[(size_t)b * 1024 + t + 768] = r3;
}
__global__ void k_attr_fin(const float* __restrict__ part, float* __restrict__ attr)
{
    int c = blockIdx.x * blockDim.x + threadIdx.x;
    if (c >= 1024) return;
    float s = 0.f;
    for (int b = 0; b < 64; ++b) s += part[(size_t)b * 1024 + c];
    attr[c] = s / (float)NGR;
}

// ---------- node_attr = lrelu(attr,0.01) @ Wo + bo (written twice) ----------
__global__ void k_nattr(const float* __restrict__ attr, const float* __restrict__ Wo,
                        const float* __restrict__ bo, float* __restrict__ out)
{
    int idx = blockIdx.x * blockDim.x + threadIdx.x;
    if (idx >= 16 * 256) return;
    int i = idx >> 8, j = idx & 255;
    float acc = 0.f;
    for (int d = 0; d < 64; ++d) {
        float v = attr[i * 64 + d];
        v = v >= 0.f ? v : 0.01f * v;
        acc = fmaf(v, Wo[d * 256 + j], acc);
    }
    acc += bo[j];
    out[idx] = acc;
    out[4096 + idx] = acc;
}

// ---------- block reductions (1024 threads = 16 waves) ----------
__device__ __forceinline__ float blk_max(float v, float* sh) {
#pragma unroll
    for (int o = 32; o > 0; o >>= 1) v = fmaxf(v, __shfl_xor(v, o, 64));
    if ((threadIdx.x & 63) == 0) sh[threadIdx.x >> 6] = v;
    __syncthreads();
    if (threadIdx.x < 16) {
        float t = sh[threadIdx.x];
#pragma unroll
        for (int o = 8; o > 0; o >>= 1) t = fmaxf(t, __shfl_xor(t, o, 16));
        if (threadIdx.x == 0) sh[0] = t;
    }
    __syncthreads();
    float r = sh[0];
    __syncthreads();
    return r;
}
__device__ __forceinline__ float blk_sum(float v, float* sh) {
#pragma unroll
    for (int o = 32; o > 0; o >>= 1) v += __shfl_xor(v, o, 64);
    if ((threadIdx.x & 63) == 0) sh[threadIdx.x >> 6] = v;
    __syncthreads();
    if (threadIdx.x < 16) {
        float t = sh[threadIdx.x];
#pragma unroll
        for (int o = 8; o > 0; o >>= 1) t += __shfl_xor(t, o, 16);
        if (threadIdx.x == 0) sh[0] = t;
    }
    __syncthreads();
    float r = sh[0];
    __syncthreads();
    return r;
}
__device__ __forceinline__ void blk_argmax(float& v, int& i, float* shf, int* shi) {
#pragma unroll
    for (int o = 32; o > 0; o >>= 1) {
        float ov = __shfl_xor(v, o, 64); int oi = __shfl_xor(i, o, 64);
        if (ov > v || (ov == v && oi < i)) { v = ov; i = oi; }
    }
    if ((threadIdx.x & 63) == 0) { shf[threadIdx.x >> 6] = v; shi[threadIdx.x >> 6] = i; }
    __syncthreads();
    if (threadIdx.x < 16) {
        float tv = shf[threadIdx.x]; int ti = shi[threadIdx.x];
#pragma unroll
        for (int o = 8; o > 0; o >>= 1) {
            float ov = __shfl_xor(tv, o, 16); int oi = __shfl_xor(ti, o, 16);
            if (ov > tv || (ov == tv && oi < ti)) { tv = ov; ti = oi; }
        }
        if (threadIdx.x == 0) { shf[0] = tv; shi[0] = ti; }
    }
    __syncthreads();
    v = shf[0]; i = shi[0];
    __syncthreads();
}

// ---------- probs[r,:] = softmax over n of e3[n,r] (LDS-staged column) ----------
__global__ __launch_bounds__(1024) void k_probs(const float* __restrict__ e3, float* __restrict__ probs)
{
    __shared__ float col[NGR];
    __shared__ float sh[16];
    int r = blockIdx.x, tid = threadIdx.x;
    float mx = -INFINITY;
    for (int n = tid; n < NGR; n += 1024) { float v = e3[n * 16 + r]; col[n] = v; mx = fmaxf(mx, v); }
    __syncthreads();
    float smx = blk_max(mx, sh);
    float sum = 0.f;
    for (int n = tid; n < NGR; n += 1024) sum += expf(col[n] - smx);
    float ssum = blk_sum(sum, sh);
    for (int n = tid; n < NGR; n += 1024) probs[(size_t)r * NGR + n] = expf(col[n] - smx) / ssum;
}

// ---------- gumbel precompute: g[it][r][j], JAX-exact (partitionable threefry) ----------
#define TINYF 1.17549435e-38f
__global__ void k_gumbel(float* __restrict__ gum)
{
    int idx = blockIdx.x * blockDim.x + threadIdx.x;
    if (idx >= 4 * 16 * NGR) return;
    int it = idx / (16 * NGR);
    int f = idx - it * (16 * NGR);     // = r*NGR + j
    u32 fk0, fk1, o0, o1;
    threefry(0u, 42u, 0u, (u32)it, fk0, fk1);   // fold_in(key(42), it)
    threefry(fk0, fk1, 0u, (u32)f, o0, o1);     // partitionable: count=(0,f)
    u32 b = o0 ^ o1;
    float fl = __uint_as_float((b >> 9) | 0x3F800000u) - 1.0f;
    float u = fmaxf(TINYF, fl + TINYF);
    gum[idx] = -logf(-logf(u));
}

// ---------- sampler: masked softmax + gumbel-argmax, probs row in registers ----------
__global__ __launch_bounds__(1024) void k_sample(const float* __restrict__ probs,
                                                 const int* __restrict__ tptr,
                                                 const float* __restrict__ gum,
                                                 float* __restrict__ out_edges)
{
    int r = blockIdx.x, tid = threadIdx.x;
    __shared__ int sel[5];
    __shared__ float shf[16];
    __shared__ int shi[16];
    const float* p = probs + (size_t)r * NGR;
    float pv[10];
#pragma unroll
    for (int w = 0; w < 10; ++w) { int j = w * 1024 + tid; pv[w] = (j < NGR) ? p[j] : 0.f; }
    if (tid == 0) { sel[0] = *tptr; out_edges[r * 5] = (float)sel[0]; }
    __syncthreads();

    for (int it = 0; it < 4; ++it) {
        int nsel = it + 1;
        bool msk[10];
        float vmax = -INFINITY;
#pragma unroll
        for (int w = 0; w < 10; ++w) {
            int j = w * 1024 + tid;
            bool mk = false;
            for (int q = 0; q < nsel; ++q) mk |= (sel[q] == j);
            msk[w] = mk;
            if (j < NGR) {
                float mm = mk ? 0.f : 1.f;
                vmax = fmaxf(vmax, pv[w] * mm - 10000.0f * (1.0f - mm));
            }
        }
        float vm = blk_max(vmax, shf);
        float ex[10];
        float sum = 0.f;
#pragma unroll
        for (int w = 0; w < 10; ++w) {
            int j = w * 1024 + tid;
            float mm = msk[w] ? 0.f : 1.f;
            float e = (j < NGR) ? expf((pv[w] - vm) * mm) * mm : 0.f;
            ex[w] = e; sum += e;
        }
        float den = blk_sum(sum, shf) + 1e-8f;
        float best = -INFINITY;
        int bidx = 0x7FFFFFFF;
        const float* g = gum + (size_t)(it * 16 + r) * NGR;
#pragma unroll
        for (int w = 0; w < 10; ++w) {
            int j = w * 1024 + tid;
            if (j < NGR) {
                float lg = logf(fmaxf(ex[w] / den, 1e-30f));
                float sc = g[j] + lg;
                if (sc > best || (sc == best && j < bidx)) { best = sc; bidx = j; }
            }
        }
        blk_argmax(best, bidx, shf, shi);
        if (tid == 0) { sel[it + 1] = bidx; out_edges[r * 5 + it + 1] = (float)bidx; }
        __syncthreads();
    }
}

extern "C" void kernel_launch(void* const* d_in, const int* in_sizes, int n_in,
                              void* d_out, int out_size, void* d_ws, size_t ws_size,
                              hipStream_t stream)
{
    const float* feat = (const float*)d_in[0];
    const int* src = (const int*)d_in[1];
    const int* dst = (const int*)d_in[2];
    const int* tptr = (const int*)d_in[3];
    const float* W1a = (const float*)d_in[4];  const float* al1a = (const float*)d_in[5];
    const float* ar1a = (const float*)d_in[6]; const float* R1a = (const float*)d_in[7];
    const float* b1a = (const float*)d_in[8];
    const float* W1e = (const float*)d_in[9];  const float* al1e = (const float*)d_in[10];
    const float* ar1e = (const float*)d_in[11]; const float* R1e = (const float*)d_in[12];
    const float* b1e = (const float*)d_in[13];
    const float* W2a = (const float*)d_in[14]; const float* al2a = (const float*)d_in[15];
    const float* ar2a = (const float*)d_in[16]; const float* R2a = (const float*)d_in[17];
    const float* b2a = (const float*)d_in[18];
    const float* W2e = (const float*)d_in[19]; const float* al2e = (const float*)d_in[20];
    const float* ar2e = (const float*)d_in[21]; const float* R2e = (const float*)d_in[22];
    const float* b2e = (const float*)d_in[23];
    const float* Wt = (const float*)d_in[24];  const float* bt = (const float*)d_in[25];
    const float* Wo = (const float*)d_in[26];  const float* bo = (const float*)d_in[27];
    const int E = in_sizes[1];
    const int N = NGR;

    float* ws = (float*)d_ws;
    // regionA [N][2048]: phase 1 uses first N*1024 as h1o1 [h1a|h1e|o1a|o1e];
    // phase 2 holds h2o2 [N][2048] = [h2a(1024) | o2a(1024)]
    float* regionA = ws;
    size_t off = (size_t)N * 2048;
    auto alloc = [&](size_t n) { float* p = ws + off; off += (n + 3) & ~(size_t)3; return p; };
    float* a2e2 = alloc((size_t)N * 1024);     // [a2(512) | e2(512)]
    float* tf   = alloc(512);
    float* attr = alloc(1024);
    float* part = alloc(64 * 1024);
    float* el1  = alloc((size_t)N * 8);
    float* er1  = alloc((size_t)N * 8);
    float* el2a = alloc((size_t)N * 4);
    float* er2a = alloc((size_t)N * 4);
    float* el2e = alloc(N);
    float* er2e = alloc(N);
    float* h2e  = alloc((size_t)N * 16);
    float* e3   = alloc((size_t)N * 16);
    float* ee1  = alloc((size_t)E * 8);
    float* ee2a = alloc((size_t)E * 4);
    float* ee2e = alloc(E);
    float* packW = alloc(256 * 1024);
    float* packb = alloc(1024);
    float* bias2 = alloc(2048);
    float* gum   = alloc((size_t)4 * 16 * NGR);
    unsigned short* a2bf = (unsigned short*)alloc((size_t)10112 * 512 / 2);
    unsigned short* WT   = (unsigned short*)alloc((size_t)2048 * 512 / 2);
    int* deg    = (int*)alloc(N);
    int* rowptr = (int*)alloc(N + 1);
    int* cursor = (int*)alloc(N);
    int* colidx = (int*)alloc(E);

    float* out = (float*)d_out;
    float* out_edges = out + 8192;
    float* out_probs = out + 8272;

    dim3 blk(256);

    // CSR build
    hipMemsetAsync(deg, 0, N * sizeof(int), stream);
    hipMemsetAsync(cursor, 0, N * sizeof(int), stream);
    k_deg<<<(E + 255) / 256, blk, 0, stream>>>(dst, deg, E);
    k_scan<<<1, blk, 0, stream>>>(deg, rowptr, N);
    k_scatter<<<(E + 255) / 256, blk, 0, stream>>>(dst, rowptr, cursor, colidx, E);

    // prep (weights, tf, gumbel)
    k_tf<<<1, 512, 0, stream>>>(feat, tptr, Wt, bt, tf);
    k_pack<<<(256 * 1024 + 1024 + 255) / 256, blk, 0, stream>>>(W1a, W1e, R1a, R1e, b1a, b1e, packW, packb);
    k_wt<<<(1024 * 512 + 255) / 256, blk, 0, stream>>>(W2a, WT);
    k_wt<<<(1024 * 512 + 255) / 256, blk, 0, stream>>>(R2a, WT + 1024 * 512);
    k_bias2<<<8, blk, 0, stream>>>(b2a, bias2);
    k_gumbel<<<(4 * 16 * NGR + 255) / 256, blk, 0, stream>>>(gum);

    // layer 1 (f32, precision-critical): one fused GEMM, C = [h1a|h1e|o1a|o1e]
    gemm_f32<<<dim3(8, 79), blk, 0, stream>>>(feat, 256, packW, 1024, regionA, 1024, packb, N, 1024, 256);
    k_el_er<<<(N * 4 + 255) / 256, blk, 0, stream>>>(regionA, 1024, 0,   al1a, ar1a, el1, er1, 8, 0, 4, 64, N);
    k_el_er<<<(N * 4 + 255) / 256, blk, 0, stream>>>(regionA, 1024, 256, al1e, ar1e, el1, er1, 8, 4, 4, 64, N);
    k_softmax_csr<<<(N * 8 + 255) / 256, blk, 0, stream>>>(el1, er1, rowptr, colidx, src, ee1, 8, 3, N * 8);
    // out (o-part, cols 512..1023) += alpha * h (cols 0..511)
    k_agg_csr4<<<(N * 128 + 255) / 256, blk, 0, stream>>>(ee1, rowptr, colidx, src,
                                                          regionA, 256, 0, regionA, 256, 128,
                                                          8, 4, 7, N * 128);
    k_a2e2<<<(N * 256 + 255) / 256, blk, 0, stream>>>(regionA, tf, a2e2, a2bf);

    // layer 2a (bf16 MFMA, lenient path): one fused GEMM → [h2a | o2a] in regionA [N][2048]
    gemm_bf16<<<dim3(16, 79), blk, 0, stream>>>(a2bf, WT, regionA, bias2, N, 2048);

    // layer 2e (f32, precision-critical)
    gemm_e<<<(N + 7) / 8, blk, 0, stream>>>(a2e2 + 512, W2e, R2e, b2e, h2e, e3, N);

    k_el_er<<<(N * 4 + 255) / 256, blk, 0, stream>>>(regionA, 2048, 0, al2a, ar2a, el2a, er2a, 4, 0, 4, 256, N);
    k_el_er<<<(N + 255) / 256, blk, 0, stream>>>(h2e, 16, 0, al2e, ar2e, el2e, er2e, 1, 0, 1, 16, N);
    k_softmax_csr<<<(N * 4 + 255) / 256, blk, 0, stream>>>(el2a, er2a, rowptr, colidx, src, ee2a, 4, 2, N * 4);
    k_softmax_csr<<<(N + 255) / 256, blk, 0, stream>>>(el2e, er2e, rowptr, colidx, src, ee2e, 1, 0, N);
    // o2a (cols 1024..2047) += alpha * h2a (cols 0..1023)
    k_agg_csr4<<<(N * 256 + 255) / 256, blk, 0, stream>>>(ee2a, rowptr, colidx, src,
                                                          regionA, 512, 0, regionA, 512, 256,
                                                          4, 6, 8, N * 256);
    k_agg_csr4<<<(N * 4 + 255) / 256, blk, 0, stream>>>(ee2e, rowptr, colidx, src,
                                                        h2e, 4, 0, e3, 4, 0,
                                                        1, 2, 2, N * 4);

    // outputs
    k_attr_part<<<64, blk, 0, stream>>>(regionA + 1024, 2048, part);
    k_attr_fin<<<4, blk, 0, stream>>>(part, attr);
    k_nattr<<<16, blk, 0, stream>>>(attr, Wo, bo, out);
    k_probs<<<16, 1024, 0, stream>>>(e3, out_probs);
    k_sample<<<16, 1024, 0, stream>>>(out_probs, tptr, gum, out_edges);
}

// Round 5
// 593.244 us; speedup vs baseline: 2.8081x; 1.0588x over previous
//
#include <hip/hip_runtime.h>
#include <hip/hip_bf16.h>

#define NGR 10000
typedef unsigned int u32;
typedef __attribute__((ext_vector_type(8))) short short8;
typedef __attribute__((ext_vector_type(4))) float f32x4;

// ---------- threefry2x32 (JAX-exact) ----------
__device__ __forceinline__ void threefry(u32 k0, u32 k1, u32 c0, u32 c1, u32& o0, u32& o1) {
    u32 ks2 = k0 ^ k1 ^ 0x1BD11BDAu;
    u32 x0 = c0 + k0, x1 = c1 + k1;
#define TF_R(r) { x0 += x1; x1 = (x1 << r) | (x1 >> (32 - r)); x1 ^= x0; }
    TF_R(13) TF_R(15) TF_R(26) TF_R(6)
    x0 += k1; x1 += ks2 + 1u;
    TF_R(17) TF_R(29) TF_R(16) TF_R(24)
    x0 += ks2; x1 += k0 + 2u;
    TF_R(13) TF_R(15) TF_R(26) TF_R(6)
    x0 += k0; x1 += k1 + 3u;
    TF_R(17) TF_R(29) TF_R(16) TF_R(24)
    x0 += k1; x1 += ks2 + 4u;
    TF_R(13) TF_R(15) TF_R(26) TF_R(6)
    x0 += ks2; x1 += k0 + 5u;
#undef TF_R
    o0 = x0; o1 = x1;
}

// ---------- CSR build ----------
__global__ void k_deg(const int* __restrict__ dst, int* __restrict__ deg, int E) {
    int i = blockIdx.x * blockDim.x + threadIdx.x;
    if (i < E) atomicAdd(&deg[dst[i]], 1);
}
__global__ void k_scan(const int* __restrict__ deg, int* __restrict__ rowptr, int n) {
    __shared__ int sums[256];
    __shared__ int excl[257];
    const int T = 256;
    int t = threadIdx.x;
    int per = (n + T - 1) / T;
    int lo = t * per, hi = min(lo + per, n);
    int s = 0;
    for (int i = lo; i < hi; ++i) s += deg[i];
    sums[t] = s;
    __syncthreads();
    if (t == 0) { int run = 0; for (int i = 0; i < T; ++i) { excl[i] = run; run += sums[i]; } excl[T] = run; }
    __syncthreads();
    int run = excl[t];
    for (int i = lo; i < hi; ++i) { rowptr[i] = run; run += deg[i]; }
    if (t == 0) rowptr[n] = excl[T];
}
__global__ void k_scatter(const int* __restrict__ dst, const int* __restrict__ rowptr,
                          int* __restrict__ cursor, int* __restrict__ colidx, int E) {
    int i = blockIdx.x * blockDim.x + threadIdx.x;
    if (i >= E) return;
    int d = dst[i];
    int pos = atomicAdd(&cursor[d], 1);
    colidx[rowptr[d] + pos] = i;
}

// ---------- f32 GEMM, reg-staged double-buffered, conflict-free microtile ----------
__global__ __launch_bounds__(256) void gemm_f32_db(
    const float* __restrict__ A, int lda,
    const float* __restrict__ B, int ldb,
    float* __restrict__ C, int ldc,
    const float* __restrict__ bias,
    int M, int N, int K)
{
    __shared__ float As[2][16][132];
    __shared__ float Bs[2][16][128];
    const int tid = threadIdx.x;
    const int bm = blockIdx.y * 128, bn = blockIdx.x * 128;
    const int tx4 = (tid & 15) << 2, ty4 = ((tid >> 4) & 15) << 2;
    const int am = tid >> 2, ak = (tid & 3) << 2;
    const int bkr = tid >> 4, bcc = (tid & 15) << 3;
    const int NT = K >> 4;
    float acc[8][8] = {};
    float4 ra0, ra1, rb0, rb1;

    auto gload = [&](int k0) {
        int m0 = bm + am, m1 = bm + am + 64;
        ra0 = (m0 < M) ? *(const float4*)(A + (size_t)m0 * lda + k0 + ak) : make_float4(0.f, 0.f, 0.f, 0.f);
        ra1 = (m1 < M) ? *(const float4*)(A + (size_t)m1 * lda + k0 + ak) : make_float4(0.f, 0.f, 0.f, 0.f);
        const float* bp = B + (size_t)(k0 + bkr) * ldb + bn + bcc;
        rb0 = *(const float4*)(bp);
        rb1 = *(const float4*)(bp + 4);
    };
    auto sstore = [&](int b) {
        As[b][ak + 0][am] = ra0.x; As[b][ak + 1][am] = ra0.y;
        As[b][ak + 2][am] = ra0.z; As[b][ak + 3][am] = ra0.w;
        As[b][ak + 0][am + 64] = ra1.x; As[b][ak + 1][am + 64] = ra1.y;
        As[b][ak + 2][am + 64] = ra1.z; As[b][ak + 3][am + 64] = ra1.w;
        *(float4*)&Bs[b][bkr][bcc] = rb0;
        *(float4*)&Bs[b][bkr][bcc + 4] = rb1;
    };

    gload(0);
    sstore(0);
    __syncthreads();
    int buf = 0;
    for (int t = 0; t < NT; ++t) {
        bool more = (t + 1 < NT);
        if (more) gload((t + 1) << 4);
#pragma unroll
        for (int kk = 0; kk < 16; ++kk) {
            float4 a0 = *(const float4*)&As[buf][kk][ty4];
            float4 a1 = *(const float4*)&As[buf][kk][ty4 + 64];
            float4 b0 = *(const float4*)&Bs[buf][kk][tx4];
            float4 b1 = *(const float4*)&Bs[buf][kk][tx4 + 64];
            float av[8] = {a0.x, a0.y, a0.z, a0.w, a1.x, a1.y, a1.z, a1.w};
            float bv[8] = {b0.x, b0.y, b0.z, b0.w, b1.x, b1.y, b1.z, b1.w};
#pragma unroll
            for (int i = 0; i < 8; ++i)
#pragma unroll
                for (int j = 0; j < 8; ++j)
                    acc[i][j] = fmaf(av[i], bv[j], acc[i][j]);
        }
        if (more) {
            sstore(buf ^ 1);
            __syncthreads();
            buf ^= 1;
        }
    }
#pragma unroll
    for (int i = 0; i < 8; ++i) {
        int ri = bm + ((i < 4) ? ty4 + i : 64 + ty4 + i - 4);
        if (ri >= M) continue;
        float* cp = C + (size_t)ri * ldc + bn;
        float4 v0, v1;
        v0.x = acc[i][0] + (bias ? bias[bn + tx4 + 0] : 0.f);
        v0.y = acc[i][1] + (bias ? bias[bn + tx4 + 1] : 0.f);
        v0.z = acc[i][2] + (bias ? bias[bn + tx4 + 2] : 0.f);
        v0.w = acc[i][3] + (bias ? bias[bn + tx4 + 3] : 0.f);
        v1.x = acc[i][4] + (bias ? bias[bn + 64 + tx4 + 0] : 0.f);
        v1.y = acc[i][5] + (bias ? bias[bn + 64 + tx4 + 1] : 0.f);
        v1.z = acc[i][6] + (bias ? bias[bn + 64 + tx4 + 2] : 0.f);
        v1.w = acc[i][7] + (bias ? bias[bn + 64 + tx4 + 3] : 0.f);
        *(float4*)(cp + tx4) = v0;
        *(float4*)(cp + 64 + tx4) = v1;
    }
}

// ---------- bf16 MFMA GEMM, 2-phase LDS double-buffer ----------
__global__ __launch_bounds__(256) void gemm_bf16(
    const unsigned short* __restrict__ A,    // [Mpad][512] bf16 bits
    const unsigned short* __restrict__ BT,   // [Ncols][512] bf16 bits
    float* __restrict__ C,                   // [M][Ncols]
    const float* __restrict__ bias,          // [Ncols] or null
    int M, int Ncols)
{
    constexpr int K = 512;
    __shared__ unsigned short As[2][128 * 32];
    __shared__ unsigned short Bs[2][128 * 32];
    const int tid = threadIdx.x;
    const int lane = tid & 63;
    const int w = tid >> 6, wr = w >> 1, wc = w & 1;
    const int bm = blockIdx.y * 128, bn = blockIdx.x * 128;
    const int fr = lane & 15, fq = lane >> 4;
    const int srow = tid >> 2;
    const int sbyte = (tid & 3) * 16;
    f32x4 acc[4][4] = {};
    const char* Ab = (const char*)A;
    const char* Bb = (const char*)BT;

    auto stage = [&](int b, int k0) {
        char* AsB = (char*)As[b];
        char* BsB = (char*)Bs[b];
        const char* ga0 = Ab + ((size_t)(bm + srow) * K + k0) * 2 + sbyte;
        const char* ga1 = Ab + ((size_t)(bm + 64 + srow) * K + k0) * 2 + sbyte;
        const char* gb0 = Bb + ((size_t)(bn + srow) * K + k0) * 2 + sbyte;
        const char* gb1 = Bb + ((size_t)(bn + 64 + srow) * K + k0) * 2 + sbyte;
        __builtin_amdgcn_global_load_lds((const __attribute__((address_space(1))) void*)ga0,
            (__attribute__((address_space(3))) void*)(AsB + tid * 16), 16, 0, 0);
        __builtin_amdgcn_global_load_lds((const __attribute__((address_space(1))) void*)ga1,
            (__attribute__((address_space(3))) void*)(AsB + 4096 + tid * 16), 16, 0, 0);
        __builtin_amdgcn_global_load_lds((const __attribute__((address_space(1))) void*)gb0,
            (__attribute__((address_space(3))) void*)(BsB + tid * 16), 16, 0, 0);
        __builtin_amdgcn_global_load_lds((const __attribute__((address_space(1))) void*)gb1,
            (__attribute__((address_space(3))) void*)(BsB + 4096 + tid * 16), 16, 0, 0);
    };

    stage(0, 0);
    __syncthreads();
    int buf = 0;
    for (int t = 0; t < 16; ++t) {
        if (t < 15) stage(buf ^ 1, (t + 1) * 32);
        const char* AsB = (const char*)As[buf];
        const char* BsB = (const char*)Bs[buf];
        short8 af[4], bfv[4];
#pragma unroll
        for (int m = 0; m < 4; ++m)
            af[m] = *(const short8*)(AsB + ((wr * 64 + m * 16 + fr) * 64 + fq * 16));
#pragma unroll
        for (int n = 0; n < 4; ++n)
            bfv[n] = *(const short8*)(BsB + ((wc * 64 + n * 16 + fr) * 64 + fq * 16));
#pragma unroll
        for (int m = 0; m < 4; ++m)
#pragma unroll
            for (int n = 0; n < 4; ++n)
                acc[m][n] = __builtin_amdgcn_mfma_f32_16x16x32_bf16(af[m], bfv[n], acc[m][n], 0, 0, 0);
        __syncthreads();
        buf ^= 1;
    }
#pragma unroll
    for (int m = 0; m < 4; ++m) {
#pragma unroll
        for (int i = 0; i < 4; ++i) {
            int row = bm + wr * 64 + m * 16 + fq * 4 + i;
            if (row >= M) continue;
#pragma unroll
            for (int n = 0; n < 4; ++n) {
                int col = bn + wc * 64 + n * 16 + fr;
                C[(size_t)row * Ncols + col] = acc[m][n][i] + (bias ? bias[col] : 0.f);
            }
        }
    }
}

// ---------- coalesced LDS-tiled transpose + bf16: WT[n][k] = bf16(W[k][n]) ----------
__global__ __launch_bounds__(256) void k_wt2(const float* __restrict__ W, unsigned short* __restrict__ WT) {
    __shared__ float tile[32][33];
    int bx = blockIdx.x, by = blockIdx.y;     // bx: n-tile (0..31), by: k-tile (0..15)
    int tx = threadIdx.x & 31, ty = threadIdx.x >> 5;
#pragma unroll
    for (int i = ty; i < 32; i += 8)
        tile[i][tx] = W[(size_t)(by * 32 + i) * 1024 + bx * 32 + tx];
    __syncthreads();
#pragma unroll
    for (int i = ty; i < 32; i += 8) {
        __hip_bfloat16 b = __float2bfloat16(tile[tx][i]);
        WT[(size_t)(bx * 32 + i) * 512 + by * 32 + tx] = *(unsigned short*)&b;
    }
}

// ---------- pack layer-1 weights: PW[256][1024] = [W1a|W1e|R1a|R1e] ----------
__global__ void k_pack(const float* __restrict__ Wa, const float* __restrict__ We,
                       const float* __restrict__ Ra, const float* __restrict__ Re,
                       const float* __restrict__ ba, const float* __restrict__ be,
                       float* __restrict__ PW, float* __restrict__ Pb) {
    int idx = blockIdx.x * blockDim.x + threadIdx.x;
    if (idx < 256 * 1024) {
        int k = idx >> 10, c = idx & 1023;
        float v;
        if (c < 256) v = Wa[k * 256 + c];
        else if (c < 512) v = We[k * 256 + (c - 256)];
        else if (c < 768) v = Ra[k * 256 + (c - 512)];
        else v = Re[k * 256 + (c - 768)];
        PW[idx] = v;
    } else if (idx < 256 * 1024 + 1024) {
        int c = idx - 256 * 1024;
        Pb[c] = (c < 512) ? 0.f : ((c < 768) ? ba[c - 512] : be[c - 768]);
    }
}

// ---------- tf = leaky_relu(feat[t] @ Wt + bt, 0.01) ----------
__global__ void k_tf(const float* __restrict__ feat, const int* __restrict__ tptr,
                     const float* __restrict__ Wt, const float* __restrict__ bt, float* __restrict__ tf)
{
    int j = threadIdx.x;
    if (j >= 512) return;
    int t = *tptr;
    float acc = 0.f;
    for (int k = 0; k < 256; ++k) acc = fmaf(feat[t * 256 + k], Wt[k * 512 + j], acc);
    acc += bt[j];
    tf[j] = acc >= 0.f ? acc : 0.01f * acc;
}

// ---------- el/er: per (n,h) dot over D (float4) ----------
__global__ void k_el_er(const float* __restrict__ h, int ldh, int hoff,
                        const float* __restrict__ al, const float* __restrict__ ar,
                        float* __restrict__ el, float* __restrict__ er,
                        int ldE, int eoff, int H, int D, int N)
{
    int idx = blockIdx.x * blockDim.x + threadIdx.x;
    if (idx >= N * H) return;
    int n = idx / H, hh = idx - n * H;
    const float* hp = h + (size_t)n * ldh + hoff + hh * D;
    const float* alp = al + hh * D;
    const float* arp = ar + hh * D;
    float sl = 0.f, sr = 0.f;
    for (int d = 0; d < D; d += 4) {
        float4 v = *(const float4*)(hp + d);
        float4 a4 = *(const float4*)(alp + d);
        float4 r4 = *(const float4*)(arp + d);
        sl = fmaf(v.x, a4.x, sl); sl = fmaf(v.y, a4.y, sl); sl = fmaf(v.z, a4.z, sl); sl = fmaf(v.w, a4.w, sl);
        sr = fmaf(v.x, r4.x, sr); sr = fmaf(v.y, r4.y, sr); sr = fmaf(v.z, r4.z, sr); sr = fmaf(v.w, r4.w, sr);
    }
    el[n * ldE + eoff + hh] = sl;
    er[n * ldE + eoff + hh] = sr;
}

// ---------- CSR edge softmax: write normalized alpha into ee[E][H] ----------
__global__ void k_softmax_csr(const float* __restrict__ el, const float* __restrict__ er,
                              const int* __restrict__ rowptr, const int* __restrict__ colidx,
                              const int* __restrict__ src,
                              float* __restrict__ ee, int H, int hshift, int total)
{
    int idx = blockIdx.x * blockDim.x + threadIdx.x;
    if (idx >= total) return;
    int n = idx >> hshift, hh = idx & (H - 1);
    float ern = er[n * H + hh];
    int i0 = rowptr[n], i1 = rowptr[n + 1];
    float mx = -INFINITY;
    for (int i = i0; i < i1; ++i) {
        float v = el[src[colidx[i]] * H + hh] + ern;
        v = v >= 0.f ? v : 0.2f * v;
        mx = fmaxf(mx, v);
    }
    float s = 0.f;
    for (int i = i0; i < i1; ++i) {
        int e = colidx[i];
        float v = el[src[e] * H + hh] + ern;
        v = v >= 0.f ? v : 0.2f * v;
        float ex = expf(v - mx);
        ee[(size_t)e * H + hh] = ex;
        s += ex;
    }
    for (int i = i0; i < i1; ++i) {
        int e = colidx[i];
        ee[(size_t)e * H + hh] /= s;
    }
}

// ---------- CSR aggregation (float4): out4[n,c4] += sum_e alpha[e,hh]*h4[src[e],c4] ----------
__global__ void k_agg_csr4(const float* __restrict__ alpha,
                           const int* __restrict__ rowptr, const int* __restrict__ colidx,
                           const int* __restrict__ src,
                           const float* __restrict__ h, int ldh4, int hoff4,
                           float* __restrict__ out, int ldo4, int ooff4,
                           int H, int dshift4, int hdshift4, int total)
{
    int idx = blockIdx.x * blockDim.x + threadIdx.x;
    if (idx >= total) return;
    int n = idx >> hdshift4, c4 = idx & ((1 << hdshift4) - 1);
    int hh = c4 >> dshift4;
    const float4* h4 = (const float4*)h;
    float4* out4 = (float4*)out;
    float4 acc = out4[(size_t)n * ldo4 + ooff4 + c4];
    int i1 = rowptr[n + 1];
    for (int i = rowptr[n]; i < i1; ++i) {
        int e = colidx[i];
        float a = alpha[(size_t)e * H + hh];
        float4 hv = h4[(size_t)src[e] * ldh4 + hoff4 + c4];
        acc.x = fmaf(a, hv.x, acc.x); acc.y = fmaf(a, hv.y, acc.y);
        acc.z = fmaf(a, hv.z, acc.z); acc.w = fmaf(a, hv.w, acc.w);
    }
    out4[(size_t)n * ldo4 + ooff4 + c4] = acc;
}

// ---------- a2/e2 = lrelu(concat/swap + tf, 0.01); bf16 copy of a2 (float4) ----------
__global__ void k_a2e2(const float* __restrict__ h1o1, const float* __restrict__ tf,
                       float* __restrict__ B, unsigned short* __restrict__ a2bf)
{
    int idx = blockIdx.x * blockDim.x + threadIdx.x;
    if (idx >= NGR * 256) return;
    int n = idx >> 8, c4 = idx & 255;
    int c = c4 << 2;
    const float* o = h1o1 + (size_t)n * 1024 + 512;
    float4 x;
    if (c < 512) x = *(const float4*)(o + c);
    else { int cc = c - 512; x = *(const float4*)(o + ((cc < 256) ? cc + 256 : cc - 256)); }
    float4 t4 = *(const float4*)(tf + (c & 511));
    x.x += t4.x; x.y += t4.y; x.z += t4.z; x.w += t4.w;
    x.x = x.x >= 0.f ? x.x : 0.01f * x.x;
    x.y = x.y >= 0.f ? x.y : 0.01f * x.y;
    x.z = x.z >= 0.f ? x.z : 0.01f * x.z;
    x.w = x.w >= 0.f ? x.w : 0.01f * x.w;
    *(float4*)(B + (size_t)n * 1024 + c) = x;
    if (c < 512) {
        __hip_bfloat16 b0 = __float2bfloat16(x.x), b1 = __float2bfloat16(x.y);
        __hip_bfloat16 b2 = __float2bfloat16(x.z), b3 = __float2bfloat16(x.w);
        ushort4 u4;
        u4.x = *(unsigned short*)&b0; u4.y = *(unsigned short*)&b1;
        u4.z = *(unsigned short*)&b2; u4.w = *(unsigned short*)&b3;
        *(ushort4*)(a2bf + (size_t)n * 512 + c) = u4;
    }
}

// ---------- skinny GEMM: h2e = e2 @ W2e ; e3 = e2 @ R2e + b2e  (N=16 each) ----------
__global__ __launch_bounds__(256) void gemm_e(
    const float* __restrict__ A,    // e2 = a2e2+512, lda=1024
    const float* __restrict__ We, const float* __restrict__ Re, const float* __restrict__ be,
    float* __restrict__ h2e, float* __restrict__ e3, int M)
{
    __shared__ float As[8 * 512];
    int tid = threadIdx.x;
    int m0 = blockIdx.x * 8;
    for (int i = tid; i < 8 * 128; i += 256) {
        int row = i >> 7, c4 = (i & 127) << 2;
        int m = m0 + row;
        float4 v = make_float4(0.f, 0.f, 0.f, 0.f);
        if (m < M) v = *(const float4*)(A + (size_t)m * 1024 + c4);
        *(float4*)(As + row * 512 + c4) = v;
    }
    __syncthreads();
    int r = tid >> 5, j = tid & 31;
    const float* B = (j < 16) ? We : Re;
    int jj = j & 15;
    const float* ar = As + r * 512;
    float acc = 0.f;
#pragma unroll 8
    for (int k = 0; k < 512; ++k) acc = fmaf(ar[k], B[k * 16 + jj], acc);
    int m = m0 + r;
    if (m < M) {
        if (j < 16) h2e[(size_t)m * 16 + jj] = acc;
        else        e3[(size_t)m * 16 + jj] = acc + be[jj];
    }
}

// ---------- attr path (o2a collapsed to mean) ----------
// walpha[s,hh] = sum over edges with src==s of alpha[e,hh]
__global__ void k_walpha(const float* __restrict__ ee2a, const int* __restrict__ src,
                         float* __restrict__ walpha, int E)
{
    int i = blockIdx.x * blockDim.x + threadIdx.x;
    if (i >= E * 4) return;
    int e = i >> 2, hh = i & 3;
    atomicAdd(&walpha[src[e] * 4 + hh], ee2a[(size_t)e * 4 + hh]);
}
// partW[b][c] = sum over chunk rows of h2a[n,c] * walpha[n, c>>8]
__global__ __launch_bounds__(256) void k_wmean(const float* __restrict__ h2a,
                                               const float* __restrict__ walpha,
                                               float* __restrict__ partW)
{
    int b = blockIdx.x;
    int t = threadIdx.x;
    float r0 = 0, r1 = 0, r2 = 0, r3 = 0;
    int n0 = b * 40, n1 = min(n0 + 40, NGR);
    for (int n = n0; n < n1; ++n) {
        const float* row = h2a + (size_t)n * 1024;
        const float* wa = walpha + n * 4;
        r0 = fmaf(row[t], wa[0], r0);
        r1 = fmaf(row[t + 256], wa[1], r1);
        r2 = fmaf(row[t + 512], wa[2], r2);
        r3 = fmaf(row[t + 768], wa[3], r3);
    }
    partW[(size_t)b * 1024 + t] = r0;
    partW[(size_t)b * 1024 + t + 256] = r1;
    partW[(size_t)b * 1024 + t + 512] = r2;
    partW[(size_t)b * 1024 + t + 768] = r3;
}
// partA[b][k] = sum over chunk rows of a2[n,k]
__global__ __launch_bounds__(256) void k_mean_a2(const float* __restrict__ a2e2, float* __restrict__ partA)
{
    int b = blockIdx.x;
    int t = threadIdx.x;
    float s0 = 0, s1 = 0;
    int n0 = b * 80, n1 = min(n0 + 80, NGR);
    for (int n = n0; n < n1; ++n) {
        const float* row = a2e2 + (size_t)n * 1024;
        s0 += row[t]; s1 += row[t + 256];
    }
    partA[(size_t)b * 512 + t] = s0;
    partA[(size_t)b * 512 + t + 256] = s1;
}
// attrR[c] = (mean a2) @ R2a[:,c] + b2a[c]
__global__ __launch_bounds__(256) void k_gemv_R(const float* __restrict__ partA,
                                                const float* __restrict__ R2a,
                                                const float* __restrict__ b2a,
                                                float* __restrict__ attrR)
{
    __shared__ float am[512];
    __shared__ float red[256];
    int tid = threadIdx.x;
    for (int k = tid; k < 512; k += 256) {
        float s = 0.f;
        for (int b = 0; b < 125; ++b) s += partA[(size_t)b * 512 + k];
        am[k] = s / (float)NGR;
    }
    __syncthreads();
    int c = blockIdx.x * 64 + (tid & 63);
    int ks = (tid >> 6) * 128;
    float s = 0.f;
    for (int k = ks; k < ks + 128; ++k) s = fmaf(am[k], R2a[(size_t)k * 1024 + c], s);
    red[tid] = s;
    __syncthreads();
    if (tid < 64) {
        float v = red[tid] + red[tid + 64] + red[tid + 128] + red[tid + 192];
        attrR[blockIdx.x * 64 + tid] = v + b2a[blockIdx.x * 64 + tid];
    }
}
// attr[c] = sum_b partW[b][c] / N + attrR[c]
__global__ void k_attr_fin2(const float* __restrict__ partW, const float* __restrict__ attrR,
                            float* __restrict__ attr)
{
    int c = blockIdx.x * blockDim.x + threadIdx.x;
    if (c >= 1024) return;
    float s = 0.f;
    for (int b = 0; b < 250; ++b) s += partW[(size_t)b * 1024 + c];
    attr[c] = s / (float)NGR + attrR[c];
}

// ---------- node_attr = lrelu(attr,0.01) @ Wo + bo (written twice) ----------
__global__ void k_nattr(const float* __restrict__ attr, const float* __restrict__ Wo,
                        const float* __restrict__ bo, float* __restrict__ out)
{
    int idx = blockIdx.x * blockDim.x + threadIdx.x;
    if (idx >= 16 * 256) return;
    int i = idx >> 8, j = idx & 255;
    float acc = 0.f;
    for (int d = 0; d < 64; ++d) {
        float v = attr[i * 64 + d];
        v = v >= 0.f ? v : 0.01f * v;
        acc = fmaf(v, Wo[d * 256 + j], acc);
    }
    acc += bo[j];
    out[idx] = acc;
    out[4096 + idx] = acc;
}

// ---------- block reductions (1024 threads = 16 waves) ----------
__device__ __forceinline__ float blk_max(float v, float* sh) {
#pragma unroll
    for (int o = 32; o > 0; o >>= 1) v = fmaxf(v, __shfl_xor(v, o, 64));
    if ((threadIdx.x & 63) == 0) sh[threadIdx.x >> 6] = v;
    __syncthreads();
    if (threadIdx.x < 16) {
        float t = sh[threadIdx.x];
#pragma unroll
        for (int o = 8; o > 0; o >>= 1) t = fmaxf(t, __shfl_xor(t, o, 16));
        if (threadIdx.x == 0) sh[0] = t;
    }
    __syncthreads();
    float r = sh[0];
    __syncthreads();
    return r;
}
__device__ __forceinline__ float blk_sum(float v, float* sh) {
#pragma unroll
    for (int o = 32; o > 0; o >>= 1) v += __shfl_xor(v, o, 64);
    if ((threadIdx.x & 63) == 0) sh[threadIdx.x >> 6] = v;
    __syncthreads();
    if (threadIdx.x < 16) {
        float t = sh[threadIdx.x];
#pragma unroll
        for (int o = 8; o > 0; o >>= 1) t += __shfl_xor(t, o, 16);
        if (threadIdx.x == 0) sh[0] = t;
    }
    __syncthreads();
    float r = sh[0];
    __syncthreads();
    return r;
}
__device__ __forceinline__ void blk_argmax(float& v, int& i, float* shf, int* shi) {
#pragma unroll
    for (int o = 32; o > 0; o >>= 1) {
        float ov = __shfl_xor(v, o, 64); int oi = __shfl_xor(i, o, 64);
        if (ov > v || (ov == v && oi < i)) { v = ov; i = oi; }
    }
    if ((threadIdx.x & 63) == 0) { shf[threadIdx.x >> 6] = v; shi[threadIdx.x >> 6] = i; }
    __syncthreads();
    if (threadIdx.x < 16) {
        float tv = shf[threadIdx.x]; int ti = shi[threadIdx.x];
#pragma unroll
        for (int o = 8; o > 0; o >>= 1) {
            float ov = __shfl_xor(tv, o, 16); int oi = __shfl_xor(ti, o, 16);
            if (ov > tv || (ov == tv && oi < ti)) { tv = ov; ti = oi; }
        }
        if (threadIdx.x == 0) { shf[0] = tv; shi[0] = ti; }
    }
    __syncthreads();
    v = shf[0]; i = shi[0];
    __syncthreads();
}

// ---------- gumbel precompute: g[it][r][j], JAX-exact (partitionable threefry) ----------
#define TINYF 1.17549435e-38f
__global__ void k_gumbel(float* __restrict__ gum)
{
    int idx = blockIdx.x * blockDim.x + threadIdx.x;
    if (idx >= 4 * 16 * NGR) return;
    int it = idx / (16 * NGR);
    int f = idx - it * (16 * NGR);     // = r*NGR + j
    u32 fk0, fk1, o0, o1;
    threefry(0u, 42u, 0u, (u32)it, fk0, fk1);   // fold_in(key(42), it)
    threefry(fk0, fk1, 0u, (u32)f, o0, o1);     // partitionable: count=(0,f)
    u32 b = o0 ^ o1;
    float fl = __uint_as_float((b >> 9) | 0x3F800000u) - 1.0f;
    float u = fmaxf(TINYF, fl + TINYF);
    gum[idx] = -logf(-logf(u));
}

// ---------- fused probs softmax + masked-softmax gumbel-argmax sampler ----------
__global__ __launch_bounds__(1024) void k_probs_sample(const float* __restrict__ e3,
                                                       const int* __restrict__ tptr,
                                                       const float* __restrict__ gum,
                                                       float* __restrict__ probs,
                                                       float* __restrict__ out_edges)
{
    __shared__ float col[NGR];
    __shared__ float shf[16];
    __shared__ int shi[16];
    __shared__ int sel[5];
    int r = blockIdx.x, tid = threadIdx.x;
    float mx = -INFINITY;
    for (int n = tid; n < NGR; n += 1024) { float v = e3[n * 16 + r]; col[n] = v; mx = fmaxf(mx, v); }
    __syncthreads();
    float smx = blk_max(mx, shf);
    float sum = 0.f;
    for (int n = tid; n < NGR; n += 1024) sum += expf(col[n] - smx);
    float ssum = blk_sum(sum, shf);
    float pv[10];
#pragma unroll
    for (int w = 0; w < 10; ++w) {
        int j = w * 1024 + tid;
        float p = 0.f;
        if (j < NGR) {
            p = expf(col[j] - smx) / ssum;
            probs[(size_t)r * NGR + j] = p;
        }
        pv[w] = p;
    }
    if (tid == 0) { sel[0] = *tptr; out_edges[r * 5] = (float)sel[0]; }
    __syncthreads();

    for (int it = 0; it < 4; ++it) {
        int nsel = it + 1;
        bool msk[10];
        float vmax = -INFINITY;
#pragma unroll
        for (int w = 0; w < 10; ++w) {
            int j = w * 1024 + tid;
            bool mk = false;
            for (int q = 0; q < nsel; ++q) mk |= (sel[q] == j);
            msk[w] = mk;
            if (j < NGR) {
                float mm = mk ? 0.f : 1.f;
                vmax = fmaxf(vmax, pv[w] * mm - 10000.0f * (1.0f - mm));
            }
        }
        float vm = blk_max(vmax, shf);
        float ex[10];
        float sum2 = 0.f;
#pragma unroll
        for (int w = 0; w < 10; ++w) {
            int j = w * 1024 + tid;
            float mm = msk[w] ? 0.f : 1.f;
            float e = (j < NGR) ? expf((pv[w] - vm) * mm) * mm : 0.f;
            ex[w] = e; sum2 += e;
        }
        float den = blk_sum(sum2, shf) + 1e-8f;
        float best = -INFINITY;
        int bidx = 0x7FFFFFFF;
        const float* g = gum + (size_t)(it * 16 + r) * NGR;
#pragma unroll
        for (int w = 0; w < 10; ++w) {
            int j = w * 1024 + tid;
            if (j < NGR) {
                float lg = logf(fmaxf(ex[w] / den, 1e-30f));
                float sc = g[j] + lg;
                if (sc > best || (sc == best && j < bidx)) { best = sc; bidx = j; }
            }
        }
        blk_argmax(best, bidx, shf, shi);
        if (tid == 0) { sel[it + 1] = bidx; out_edges[r * 5 + it + 1] = (float)bidx; }
        __syncthreads();
    }
}

extern "C" void kernel_launch(void* const* d_in, const int* in_sizes, int n_in,
                              void* d_out, int out_size, void* d_ws, size_t ws_size,
                              hipStream_t stream)
{
    const float* feat = (const float*)d_in[0];
    const int* src = (const int*)d_in[1];
    const int* dst = (const int*)d_in[2];
    const int* tptr = (const int*)d_in[3];
    const float* W1a = (const float*)d_in[4];  const float* al1a = (const float*)d_in[5];
    const float* ar1a = (const float*)d_in[6]; const float* R1a = (const float*)d_in[7];
    const float* b1a = (const float*)d_in[8];
    const float* W1e = (const float*)d_in[9];  const float* al1e = (const float*)d_in[10];
    const float* ar1e = (const float*)d_in[11]; const float* R1e = (const float*)d_in[12];
    const float* b1e = (const float*)d_in[13];
    const float* W2a = (const float*)d_in[14]; const float* al2a = (const float*)d_in[15];
    const float* ar2a = (const float*)d_in[16]; const float* R2a = (const float*)d_in[17];
    const float* b2a = (const float*)d_in[18];
    const float* W2e = (const float*)d_in[19]; const float* al2e = (const float*)d_in[20];
    const float* ar2e = (const float*)d_in[21]; const float* R2e = (const float*)d_in[22];
    const float* b2e = (const float*)d_in[23];
    const float* Wt = (const float*)d_in[24];  const float* bt = (const float*)d_in[25];
    const float* Wo = (const float*)d_in[26];  const float* bo = (const float*)d_in[27];
    const int E = in_sizes[1];
    const int N = NGR;

    float* ws = (float*)d_ws;
    // regionA [N][1024]: phase 1 = h1o1 [h1a|h1e|o1a|o1e]; phase 2 = h2a
    float* regionA = ws;
    size_t off = (size_t)N * 1024;
    auto alloc = [&](size_t n) { float* p = ws + off; off += (n + 3) & ~(size_t)3; return p; };
    float* a2e2 = alloc((size_t)N * 1024);     // [a2(512) | e2(512)]
    float* tf   = alloc(512);
    float* attr = alloc(1024);
    float* attrR = alloc(1024);
    float* partA = alloc(125 * 512);
    float* partW = alloc(250 * 1024);
    float* el1  = alloc((size_t)N * 8);
    float* er1  = alloc((size_t)N * 8);
    float* el2a = alloc((size_t)N * 4);
    float* er2a = alloc((size_t)N * 4);
    float* el2e = alloc(N);
    float* er2e = alloc(N);
    float* h2e  = alloc((size_t)N * 16);
    float* e3   = alloc((size_t)N * 16);
    float* ee1  = alloc((size_t)E * 8);
    float* ee2a = alloc((size_t)E * 4);
    float* ee2e = alloc(E);
    float* packW = alloc(256 * 1024);
    float* packb = alloc(1024);
    float* gum   = alloc((size_t)4 * 16 * NGR);
    unsigned short* a2bf = (unsigned short*)alloc((size_t)10112 * 256);
    unsigned short* WT   = (unsigned short*)alloc((size_t)1024 * 256);
    // ---- zeroed region: walpha (4N floats) + deg (N) + cursor (N) ----
    float* zstart = alloc((size_t)N * 6);
    float* walpha = zstart;
    int* deg    = (int*)(zstart + (size_t)N * 4);
    int* cursor = deg + N;
    int* rowptr = (int*)alloc(N + 1);
    int* colidx = (int*)alloc(E);

    float* out = (float*)d_out;
    float* out_edges = out + 8192;
    float* out_probs = out + 8272;

    dim3 blk(256);

    // zero accumulators + CSR build
    hipMemsetAsync(zstart, 0, (size_t)N * 6 * sizeof(float), stream);
    k_deg<<<(E + 255) / 256, blk, 0, stream>>>(dst, deg, E);
    k_scan<<<1, blk, 0, stream>>>(deg, rowptr, N);
    k_scatter<<<(E + 255) / 256, blk, 0, stream>>>(dst, rowptr, cursor, colidx, E);

    // prep (weights, tf, gumbel)
    k_tf<<<1, 512, 0, stream>>>(feat, tptr, Wt, bt, tf);
    k_pack<<<(256 * 1024 + 1024 + 255) / 256, blk, 0, stream>>>(W1a, W1e, R1a, R1e, b1a, b1e, packW, packb);
    k_wt2<<<dim3(32, 16), blk, 0, stream>>>(W2a, WT);
    k_gumbel<<<(4 * 16 * NGR + 255) / 256, blk, 0, stream>>>(gum);

    // layer 1 (f32, precision-critical): fused GEMM → [h1a|h1e|o1a|o1e]
    gemm_f32_db<<<dim3(8, 79), blk, 0, stream>>>(feat, 256, packW, 1024, regionA, 1024, packb, N, 1024, 256);
    k_el_er<<<(N * 4 + 255) / 256, blk, 0, stream>>>(regionA, 1024, 0,   al1a, ar1a, el1, er1, 8, 0, 4, 64, N);
    k_el_er<<<(N * 4 + 255) / 256, blk, 0, stream>>>(regionA, 1024, 256, al1e, ar1e, el1, er1, 8, 4, 4, 64, N);
    k_softmax_csr<<<(N * 8 + 255) / 256, blk, 0, stream>>>(el1, er1, rowptr, colidx, src, ee1, 8, 3, N * 8);
    k_agg_csr4<<<(N * 128 + 255) / 256, blk, 0, stream>>>(ee1, rowptr, colidx, src,
                                                          regionA, 256, 0, regionA, 256, 128,
                                                          8, 4, 7, N * 128);
    k_a2e2<<<(N * 256 + 255) / 256, blk, 0, stream>>>(regionA, tf, a2e2, a2bf);

    // mean(a2) path (for collapsed R2a GEMV)
    k_mean_a2<<<125, blk, 0, stream>>>(a2e2, partA);
    k_gemv_R<<<16, blk, 0, stream>>>(partA, R2a, b2a, attrR);

    // layer 2a: only h2a = a2 @ W2a needed per-node (bf16 MFMA, lenient path)
    gemm_bf16<<<dim3(8, 79), blk, 0, stream>>>(a2bf, WT, regionA, nullptr, N, 1024);

    // layer 2e (f32, precision-critical)
    gemm_e<<<(N + 7) / 8, blk, 0, stream>>>(a2e2 + 512, W2e, R2e, b2e, h2e, e3, N);

    k_el_er<<<(N * 4 + 255) / 256, blk, 0, stream>>>(regionA, 1024, 0, al2a, ar2a, el2a, er2a, 4, 0, 4, 256, N);
    k_el_er<<<(N + 255) / 256, blk, 0, stream>>>(h2e, 16, 0, al2e, ar2e, el2e, er2e, 1, 0, 1, 16, N);
    k_softmax_csr<<<(N * 4 + 255) / 256, blk, 0, stream>>>(el2a, er2a, rowptr, colidx, src, ee2a, 4, 2, N * 4);
    k_softmax_csr<<<(N + 255) / 256, blk, 0, stream>>>(el2e, er2e, rowptr, colidx, src, ee2e, 1, 0, N);
    k_agg_csr4<<<(N * 4 + 255) / 256, blk, 0, stream>>>(ee2e, rowptr, colidx, src,
                                                        h2e, 4, 0, e3, 4, 0,
                                                        1, 2, 2, N * 4);

    // attr = mean_n o2a collapsed: agg term via walpha + weighted col-mean of h2a
    k_walpha<<<(E * 4 + 255) / 256, blk, 0, stream>>>(ee2a, src, walpha, E);
    k_wmean<<<250, blk, 0, stream>>>(regionA, walpha, partW);
    k_attr_fin2<<<4, blk, 0, stream>>>(partW, attrR, attr);
    k_nattr<<<16, blk, 0, stream>>>(attr, Wo, bo, out);

    // probs + sampling (bit-exact path)
    k_probs_sample<<<16, 1024, 0, stream>>>(e3, tptr, gum, out_probs, out_edges);
}

// Round 6
// 507.230 us; speedup vs baseline: 3.2843x; 1.1696x over previous
//
#include <hip/hip_runtime.h>
#include <hip/hip_bf16.h>

#define NGR 10000
typedef unsigned int u32;
typedef __attribute__((ext_vector_type(8))) short short8;
typedef __attribute__((ext_vector_type(4))) float f32x4;

// ---------- threefry2x32 (JAX-exact) ----------
__device__ __forceinline__ void threefry(u32 k0, u32 k1, u32 c0, u32 c1, u32& o0, u32& o1) {
    u32 ks2 = k0 ^ k1 ^ 0x1BD11BDAu;
    u32 x0 = c0 + k0, x1 = c1 + k1;
#define TF_R(r) { x0 += x1; x1 = (x1 << r) | (x1 >> (32 - r)); x1 ^= x0; }
    TF_R(13) TF_R(15) TF_R(26) TF_R(6)
    x0 += k1; x1 += ks2 + 1u;
    TF_R(17) TF_R(29) TF_R(16) TF_R(24)
    x0 += ks2; x1 += k0 + 2u;
    TF_R(13) TF_R(15) TF_R(26) TF_R(6)
    x0 += k0; x1 += k1 + 3u;
    TF_R(17) TF_R(29) TF_R(16) TF_R(24)
    x0 += k1; x1 += ks2 + 4u;
    TF_R(13) TF_R(15) TF_R(26) TF_R(6)
    x0 += ks2; x1 += k0 + 5u;
#undef TF_R
    o0 = x0; o1 = x1;
}

// ---------- CSR build ----------
__global__ void k_deg(const int* __restrict__ dst, int* __restrict__ deg, int E) {
    int i = blockIdx.x * blockDim.x + threadIdx.x;
    if (i < E) atomicAdd(&deg[dst[i]], 1);
}
__global__ void k_scan(const int* __restrict__ deg, int* __restrict__ rowptr, int n) {
    __shared__ int sums[256];
    __shared__ int excl[257];
    const int T = 256;
    int t = threadIdx.x;
    int per = (n + T - 1) / T;
    int lo = t * per, hi = min(lo + per, n);
    int s = 0;
    for (int i = lo; i < hi; ++i) s += deg[i];
    sums[t] = s;
    __syncthreads();
    if (t == 0) { int run = 0; for (int i = 0; i < T; ++i) { excl[i] = run; run += sums[i]; } excl[T] = run; }
    __syncthreads();
    int run = excl[t];
    for (int i = lo; i < hi; ++i) { rowptr[i] = run; run += deg[i]; }
    if (t == 0) rowptr[n] = excl[T];
}
__global__ void k_scatter(const int* __restrict__ dst, const int* __restrict__ rowptr,
                          int* __restrict__ cursor, int* __restrict__ colidx, int E) {
    int i = blockIdx.x * blockDim.x + threadIdx.x;
    if (i >= E) return;
    int d = dst[i];
    int pos = atomicAdd(&cursor[d], 1);
    colidx[rowptr[d] + pos] = i;
}

// ---------- split f32 -> (hi, lo) bf16 planes ----------
__global__ void k_split(const float* __restrict__ X, unsigned short* __restrict__ hi,
                        unsigned short* __restrict__ lo, int total4)
{
    int idx = blockIdx.x * blockDim.x + threadIdx.x;
    if (idx >= total4) return;
    float4 v = ((const float4*)X)[idx];
    ushort4 h, l;
    __hip_bfloat16 b; float r;
    b = __float2bfloat16(v.x); h.x = *(unsigned short*)&b; r = v.x - __bfloat162float(b);
    b = __float2bfloat16(r);   l.x = *(unsigned short*)&b;
    b = __float2bfloat16(v.y); h.y = *(unsigned short*)&b; r = v.y - __bfloat162float(b);
    b = __float2bfloat16(r);   l.y = *(unsigned short*)&b;
    b = __float2bfloat16(v.z); h.z = *(unsigned short*)&b; r = v.z - __bfloat162float(b);
    b = __float2bfloat16(r);   l.z = *(unsigned short*)&b;
    b = __float2bfloat16(v.w); h.w = *(unsigned short*)&b; r = v.w - __bfloat162float(b);
    b = __float2bfloat16(r);   l.w = *(unsigned short*)&b;
    ((ushort4*)hi)[idx] = h;
    ((ushort4*)lo)[idx] = l;
}

// ---------- transpose + hi/lo split: BT[n][k] = split(W[k][n]), W=[256][1024] ----------
__global__ __launch_bounds__(256) void k_wtsplit(const float* __restrict__ W,
                                                 unsigned short* __restrict__ BThi,
                                                 unsigned short* __restrict__ BTlo)
{
    __shared__ float tile[32][33];
    int bx = blockIdx.x, by = blockIdx.y;     // bx: n-tile (0..31), by: k-tile (0..7)
    int tx = threadIdx.x & 31, ty = threadIdx.x >> 5;
#pragma unroll
    for (int i = ty; i < 32; i += 8)
        tile[i][tx] = W[(size_t)(by * 32 + i) * 1024 + bx * 32 + tx];
    __syncthreads();
#pragma unroll
    for (int i = ty; i < 32; i += 8) {
        float x = tile[tx][i];
        __hip_bfloat16 b = __float2bfloat16(x);
        float r = x - __bfloat162float(b);
        __hip_bfloat16 bl = __float2bfloat16(r);
        BThi[(size_t)(bx * 32 + i) * 256 + by * 32 + tx] = *(unsigned short*)&b;
        BTlo[(size_t)(bx * 32 + i) * 256 + by * 32 + tx] = *(unsigned short*)&bl;
    }
}

// ---------- bf16x3 MFMA GEMM (f32-emulation): C = A @ BT^T + bias, K=256 ----------
// acc += Alo*Bhi + Ahi*Blo + Ahi*Bhi  (relative error ~2^-17 vs true f32)
__global__ __launch_bounds__(256) void gemm_bf16x3(
    const unsigned short* __restrict__ Ahi, const unsigned short* __restrict__ Alo,  // [Mpad][256]
    const unsigned short* __restrict__ Bhi, const unsigned short* __restrict__ Blo,  // [1024][256]
    float* __restrict__ C, const float* __restrict__ bias, int M)
{
    constexpr int K = 256;
    __shared__ unsigned short AsH[2][128 * 32];
    __shared__ unsigned short AsL[2][128 * 32];
    __shared__ unsigned short BsH[2][128 * 32];
    __shared__ unsigned short BsL[2][128 * 32];
    const int tid = threadIdx.x;
    const int lane = tid & 63;
    const int w = tid >> 6, wr = w >> 1, wc = w & 1;
    const int bm = blockIdx.y * 128, bn = blockIdx.x * 128;
    const int fr = lane & 15, fq = lane >> 4;
    const int srow = tid >> 2;
    const int sbyte = (tid & 3) * 16;
    f32x4 acc[4][4] = {};

    auto stage = [&](int b, int k0) {
        const char* pA[2] = {(const char*)Ahi, (const char*)Alo};
        const char* pB[2] = {(const char*)Bhi, (const char*)Blo};
        char* dA[2] = {(char*)AsH[b], (char*)AsL[b]};
        char* dB[2] = {(char*)BsH[b], (char*)BsL[b]};
#pragma unroll
        for (int q = 0; q < 2; ++q) {
            const char* ga0 = pA[q] + ((size_t)(bm + srow) * K + k0) * 2 + sbyte;
            const char* ga1 = pA[q] + ((size_t)(bm + 64 + srow) * K + k0) * 2 + sbyte;
            const char* gb0 = pB[q] + ((size_t)(bn + srow) * K + k0) * 2 + sbyte;
            const char* gb1 = pB[q] + ((size_t)(bn + 64 + srow) * K + k0) * 2 + sbyte;
            __builtin_amdgcn_global_load_lds((const __attribute__((address_space(1))) void*)ga0,
                (__attribute__((address_space(3))) void*)(dA[q] + tid * 16), 16, 0, 0);
            __builtin_amdgcn_global_load_lds((const __attribute__((address_space(1))) void*)ga1,
                (__attribute__((address_space(3))) void*)(dA[q] + 4096 + tid * 16), 16, 0, 0);
            __builtin_amdgcn_global_load_lds((const __attribute__((address_space(1))) void*)gb0,
                (__attribute__((address_space(3))) void*)(dB[q] + tid * 16), 16, 0, 0);
            __builtin_amdgcn_global_load_lds((const __attribute__((address_space(1))) void*)gb1,
                (__attribute__((address_space(3))) void*)(dB[q] + 4096 + tid * 16), 16, 0, 0);
        }
    };

    stage(0, 0);
    __syncthreads();
    int buf = 0;
    for (int t = 0; t < 8; ++t) {
        if (t < 7) stage(buf ^ 1, (t + 1) * 32);
        const char* ah = (const char*)AsH[buf];
        const char* al = (const char*)AsL[buf];
        const char* bh = (const char*)BsH[buf];
        const char* bl = (const char*)BsL[buf];
        short8 afh[4], afl[4], bfh[4], bfl[4];
#pragma unroll
        for (int m = 0; m < 4; ++m) {
            int o = (wr * 64 + m * 16 + fr) * 64 + fq * 16;
            afh[m] = *(const short8*)(ah + o);
            afl[m] = *(const short8*)(al + o);
        }
#pragma unroll
        for (int n = 0; n < 4; ++n) {
            int o = (wc * 64 + n * 16 + fr) * 64 + fq * 16;
            bfh[n] = *(const short8*)(bh + o);
            bfl[n] = *(const short8*)(bl + o);
        }
#pragma unroll
        for (int m = 0; m < 4; ++m)
#pragma unroll
            for (int n = 0; n < 4; ++n) {
                acc[m][n] = __builtin_amdgcn_mfma_f32_16x16x32_bf16(afl[m], bfh[n], acc[m][n], 0, 0, 0);
                acc[m][n] = __builtin_amdgcn_mfma_f32_16x16x32_bf16(afh[m], bfl[n], acc[m][n], 0, 0, 0);
                acc[m][n] = __builtin_amdgcn_mfma_f32_16x16x32_bf16(afh[m], bfh[n], acc[m][n], 0, 0, 0);
            }
        __syncthreads();
        buf ^= 1;
    }
#pragma unroll
    for (int m = 0; m < 4; ++m) {
#pragma unroll
        for (int i = 0; i < 4; ++i) {
            int row = bm + wr * 64 + m * 16 + fq * 4 + i;
            if (row >= M) continue;
#pragma unroll
            for (int n = 0; n < 4; ++n) {
                int col = bn + wc * 64 + n * 16 + fr;
                C[(size_t)row * 1024 + col] = acc[m][n][i] + bias[col];
            }
        }
    }
}

// ---------- bf16 MFMA GEMM, 2-phase LDS double-buffer (lenient path) ----------
__global__ __launch_bounds__(256) void gemm_bf16(
    const unsigned short* __restrict__ A,    // [Mpad][512] bf16 bits
    const unsigned short* __restrict__ BT,   // [Ncols][512] bf16 bits
    float* __restrict__ C,                   // [M][Ncols]
    const float* __restrict__ bias,          // [Ncols] or null
    int M, int Ncols)
{
    constexpr int K = 512;
    __shared__ unsigned short As[2][128 * 32];
    __shared__ unsigned short Bs[2][128 * 32];
    const int tid = threadIdx.x;
    const int lane = tid & 63;
    const int w = tid >> 6, wr = w >> 1, wc = w & 1;
    const int bm = blockIdx.y * 128, bn = blockIdx.x * 128;
    const int fr = lane & 15, fq = lane >> 4;
    const int srow = tid >> 2;
    const int sbyte = (tid & 3) * 16;
    f32x4 acc[4][4] = {};
    const char* Ab = (const char*)A;
    const char* Bb = (const char*)BT;

    auto stage = [&](int b, int k0) {
        char* AsB = (char*)As[b];
        char* BsB = (char*)Bs[b];
        const char* ga0 = Ab + ((size_t)(bm + srow) * K + k0) * 2 + sbyte;
        const char* ga1 = Ab + ((size_t)(bm + 64 + srow) * K + k0) * 2 + sbyte;
        const char* gb0 = Bb + ((size_t)(bn + srow) * K + k0) * 2 + sbyte;
        const char* gb1 = Bb + ((size_t)(bn + 64 + srow) * K + k0) * 2 + sbyte;
        __builtin_amdgcn_global_load_lds((const __attribute__((address_space(1))) void*)ga0,
            (__attribute__((address_space(3))) void*)(AsB + tid * 16), 16, 0, 0);
        __builtin_amdgcn_global_load_lds((const __attribute__((address_space(1))) void*)ga1,
            (__attribute__((address_space(3))) void*)(AsB + 4096 + tid * 16), 16, 0, 0);
        __builtin_amdgcn_global_load_lds((const __attribute__((address_space(1))) void*)gb0,
            (__attribute__((address_space(3))) void*)(BsB + tid * 16), 16, 0, 0);
        __builtin_amdgcn_global_load_lds((const __attribute__((address_space(1))) void*)gb1,
            (__attribute__((address_space(3))) void*)(BsB + 4096 + tid * 16), 16, 0, 0);
    };

    stage(0, 0);
    __syncthreads();
    int buf = 0;
    for (int t = 0; t < 16; ++t) {
        if (t < 15) stage(buf ^ 1, (t + 1) * 32);
        const char* AsB = (const char*)As[buf];
        const char* BsB = (const char*)Bs[buf];
        short8 af[4], bfv[4];
#pragma unroll
        for (int m = 0; m < 4; ++m)
            af[m] = *(const short8*)(AsB + ((wr * 64 + m * 16 + fr) * 64 + fq * 16));
#pragma unroll
        for (int n = 0; n < 4; ++n)
            bfv[n] = *(const short8*)(BsB + ((wc * 64 + n * 16 + fr) * 64 + fq * 16));
#pragma unroll
        for (int m = 0; m < 4; ++m)
#pragma unroll
            for (int n = 0; n < 4; ++n)
                acc[m][n] = __builtin_amdgcn_mfma_f32_16x16x32_bf16(af[m], bfv[n], acc[m][n], 0, 0, 0);
        __syncthreads();
        buf ^= 1;
    }
#pragma unroll
    for (int m = 0; m < 4; ++m) {
#pragma unroll
        for (int i = 0; i < 4; ++i) {
            int row = bm + wr * 64 + m * 16 + fq * 4 + i;
            if (row >= M) continue;
#pragma unroll
            for (int n = 0; n < 4; ++n) {
                int col = bn + wc * 64 + n * 16 + fr;
                C[(size_t)row * Ncols + col] = acc[m][n][i] + (bias ? bias[col] : 0.f);
            }
        }
    }
}

// ---------- coalesced LDS-tiled transpose + bf16: WT[n][k] = bf16(W[k][n]) ----------
__global__ __launch_bounds__(256) void k_wt2(const float* __restrict__ W, unsigned short* __restrict__ WT) {
    __shared__ float tile[32][33];
    int bx = blockIdx.x, by = blockIdx.y;     // bx: n-tile (0..31), by: k-tile (0..15)
    int tx = threadIdx.x & 31, ty = threadIdx.x >> 5;
#pragma unroll
    for (int i = ty; i < 32; i += 8)
        tile[i][tx] = W[(size_t)(by * 32 + i) * 1024 + bx * 32 + tx];
    __syncthreads();
#pragma unroll
    for (int i = ty; i < 32; i += 8) {
        __hip_bfloat16 b = __float2bfloat16(tile[tx][i]);
        WT[(size_t)(bx * 32 + i) * 512 + by * 32 + tx] = *(unsigned short*)&b;
    }
}

// ---------- pack layer-1 weights: PW[256][1024] = [W1a|W1e|R1a|R1e] ----------
__global__ void k_pack(const float* __restrict__ Wa, const float* __restrict__ We,
                       const float* __restrict__ Ra, const float* __restrict__ Re,
                       const float* __restrict__ ba, const float* __restrict__ be,
                       float* __restrict__ PW, float* __restrict__ Pb) {
    int idx = blockIdx.x * blockDim.x + threadIdx.x;
    if (idx < 256 * 1024) {
        int k = idx >> 10, c = idx & 1023;
        float v;
        if (c < 256) v = Wa[k * 256 + c];
        else if (c < 512) v = We[k * 256 + (c - 256)];
        else if (c < 768) v = Ra[k * 256 + (c - 512)];
        else v = Re[k * 256 + (c - 768)];
        PW[idx] = v;
    } else if (idx < 256 * 1024 + 1024) {
        int c = idx - 256 * 1024;
        Pb[c] = (c < 512) ? 0.f : ((c < 768) ? ba[c - 512] : be[c - 768]);
    }
}

// ---------- tf = leaky_relu(feat[t] @ Wt + bt, 0.01) ----------
__global__ void k_tf(const float* __restrict__ feat, const int* __restrict__ tptr,
                     const float* __restrict__ Wt, const float* __restrict__ bt, float* __restrict__ tf)
{
    int j = threadIdx.x;
    if (j >= 512) return;
    int t = *tptr;
    float acc = 0.f;
    for (int k = 0; k < 256; ++k) acc = fmaf(feat[t * 256 + k], Wt[k * 512 + j], acc);
    acc += bt[j];
    tf[j] = acc >= 0.f ? acc : 0.01f * acc;
}

// ---------- el/er: per (n,h) dot over D (float4) ----------
__global__ void k_el_er(const float* __restrict__ h, int ldh, int hoff,
                        const float* __restrict__ al, const float* __restrict__ ar,
                        float* __restrict__ el, float* __restrict__ er,
                        int ldE, int eoff, int H, int D, int N)
{
    int idx = blockIdx.x * blockDim.x + threadIdx.x;
    if (idx >= N * H) return;
    int n = idx / H, hh = idx - n * H;
    const float* hp = h + (size_t)n * ldh + hoff + hh * D;
    const float* alp = al + hh * D;
    const float* arp = ar + hh * D;
    float sl = 0.f, sr = 0.f;
    for (int d = 0; d < D; d += 4) {
        float4 v = *(const float4*)(hp + d);
        float4 a4 = *(const float4*)(alp + d);
        float4 r4 = *(const float4*)(arp + d);
        sl = fmaf(v.x, a4.x, sl); sl = fmaf(v.y, a4.y, sl); sl = fmaf(v.z, a4.z, sl); sl = fmaf(v.w, a4.w, sl);
        sr = fmaf(v.x, r4.x, sr); sr = fmaf(v.y, r4.y, sr); sr = fmaf(v.z, r4.z, sr); sr = fmaf(v.w, r4.w, sr);
    }
    el[n * ldE + eoff + hh] = sl;
    er[n * ldE + eoff + hh] = sr;
}

// ---------- CSR edge softmax: write normalized alpha into ee[E][H] ----------
__global__ void k_softmax_csr(const float* __restrict__ el, const float* __restrict__ er,
                              const int* __restrict__ rowptr, const int* __restrict__ colidx,
                              const int* __restrict__ src,
                              float* __restrict__ ee, int H, int hshift, int total)
{
    int idx = blockIdx.x * blockDim.x + threadIdx.x;
    if (idx >= total) return;
    int n = idx >> hshift, hh = idx & (H - 1);
    float ern = er[n * H + hh];
    int i0 = rowptr[n], i1 = rowptr[n + 1];
    float mx = -INFINITY;
    for (int i = i0; i < i1; ++i) {
        float v = el[src[colidx[i]] * H + hh] + ern;
        v = v >= 0.f ? v : 0.2f * v;
        mx = fmaxf(mx, v);
    }
    float s = 0.f;
    for (int i = i0; i < i1; ++i) {
        int e = colidx[i];
        float v = el[src[e] * H + hh] + ern;
        v = v >= 0.f ? v : 0.2f * v;
        float ex = expf(v - mx);
        ee[(size_t)e * H + hh] = ex;
        s += ex;
    }
    for (int i = i0; i < i1; ++i) {
        int e = colidx[i];
        ee[(size_t)e * H + hh] /= s;
    }
}

// ---------- CSR aggregation (float4): out4[n,c4] += sum_e alpha[e,hh]*h4[src[e],c4] ----------
__global__ void k_agg_csr4(const float* __restrict__ alpha,
                           const int* __restrict__ rowptr, const int* __restrict__ colidx,
                           const int* __restrict__ src,
                           const float* __restrict__ h, int ldh4, int hoff4,
                           float* __restrict__ out, int ldo4, int ooff4,
                           int H, int dshift4, int hdshift4, int total)
{
    int idx = blockIdx.x * blockDim.x + threadIdx.x;
    if (idx >= total) return;
    int n = idx >> hdshift4, c4 = idx & ((1 << hdshift4) - 1);
    int hh = c4 >> dshift4;
    const float4* h4 = (const float4*)h;
    float4* out4 = (float4*)out;
    float4 acc = out4[(size_t)n * ldo4 + ooff4 + c4];
    int i1 = rowptr[n + 1];
    for (int i = rowptr[n]; i < i1; ++i) {
        int e = colidx[i];
        float a = alpha[(size_t)e * H + hh];
        float4 hv = h4[(size_t)src[e] * ldh4 + hoff4 + c4];
        acc.x = fmaf(a, hv.x, acc.x); acc.y = fmaf(a, hv.y, acc.y);
        acc.z = fmaf(a, hv.z, acc.z); acc.w = fmaf(a, hv.w, acc.w);
    }
    out4[(size_t)n * ldo4 + ooff4 + c4] = acc;
}

// ---------- a2/e2 = lrelu(concat/swap + tf, 0.01); bf16 copy of a2 (float4) ----------
__global__ void k_a2e2(const float* __restrict__ h1o1, const float* __restrict__ tf,
                       float* __restrict__ B, unsigned short* __restrict__ a2bf)
{
    int idx = blockIdx.x * blockDim.x + threadIdx.x;
    if (idx >= NGR * 256) return;
    int n = idx >> 8, c4 = idx & 255;
    int c = c4 << 2;
    const float* o = h1o1 + (size_t)n * 1024 + 512;
    float4 x;
    if (c < 512) x = *(const float4*)(o + c);
    else { int cc = c - 512; x = *(const float4*)(o + ((cc < 256) ? cc + 256 : cc - 256)); }
    float4 t4 = *(const float4*)(tf + (c & 511));
    x.x += t4.x; x.y += t4.y; x.z += t4.z; x.w += t4.w;
    x.x = x.x >= 0.f ? x.x : 0.01f * x.x;
    x.y = x.y >= 0.f ? x.y : 0.01f * x.y;
    x.z = x.z >= 0.f ? x.z : 0.01f * x.z;
    x.w = x.w >= 0.f ? x.w : 0.01f * x.w;
    *(float4*)(B + (size_t)n * 1024 + c) = x;
    if (c < 512) {
        __hip_bfloat16 b0 = __float2bfloat16(x.x), b1 = __float2bfloat16(x.y);
        __hip_bfloat16 b2 = __float2bfloat16(x.z), b3 = __float2bfloat16(x.w);
        ushort4 u4;
        u4.x = *(unsigned short*)&b0; u4.y = *(unsigned short*)&b1;
        u4.z = *(unsigned short*)&b2; u4.w = *(unsigned short*)&b3;
        *(ushort4*)(a2bf + (size_t)n * 512 + c) = u4;
    }
}

// ---------- skinny GEMM: h2e = e2 @ W2e ; e3 = e2 @ R2e + b2e  (N=16 each) ----------
__global__ __launch_bounds__(256) void gemm_e(
    const float* __restrict__ A,    // e2 = a2e2+512, lda=1024
    const float* __restrict__ We, const float* __restrict__ Re, const float* __restrict__ be,
    float* __restrict__ h2e, float* __restrict__ e3, int M)
{
    __shared__ float As[8 * 512];
    int tid = threadIdx.x;
    int m0 = blockIdx.x * 8;
    for (int i = tid; i < 8 * 128; i += 256) {
        int row = i >> 7, c4 = (i & 127) << 2;
        int m = m0 + row;
        float4 v = make_float4(0.f, 0.f, 0.f, 0.f);
        if (m < M) v = *(const float4*)(A + (size_t)m * 1024 + c4);
        *(float4*)(As + row * 512 + c4) = v;
    }
    __syncthreads();
    int r = tid >> 5, j = tid & 31;
    const float* B = (j < 16) ? We : Re;
    int jj = j & 15;
    const float* ar = As + r * 512;
    float acc = 0.f;
#pragma unroll 8
    for (int k = 0; k < 512; ++k) acc = fmaf(ar[k], B[k * 16 + jj], acc);
    int m = m0 + r;
    if (m < M) {
        if (j < 16) h2e[(size_t)m * 16 + jj] = acc;
        else        e3[(size_t)m * 16 + jj] = acc + be[jj];
    }
}

// ---------- attr path (o2a collapsed to mean) ----------
__global__ void k_walpha(const float* __restrict__ ee2a, const int* __restrict__ src,
                         float* __restrict__ walpha, int E)
{
    int i = blockIdx.x * blockDim.x + threadIdx.x;
    if (i >= E * 4) return;
    int e = i >> 2, hh = i & 3;
    atomicAdd(&walpha[src[e] * 4 + hh], ee2a[(size_t)e * 4 + hh]);
}
__global__ __launch_bounds__(256) void k_wmean(const float* __restrict__ h2a,
                                               const float* __restrict__ walpha,
                                               float* __restrict__ partW)
{
    int b = blockIdx.x;
    int t = threadIdx.x;
    float r0 = 0, r1 = 0, r2 = 0, r3 = 0;
    int n0 = b * 40, n1 = min(n0 + 40, NGR);
    for (int n = n0; n < n1; ++n) {
        const float* row = h2a + (size_t)n * 1024;
        const float* wa = walpha + n * 4;
        r0 = fmaf(row[t], wa[0], r0);
        r1 = fmaf(row[t + 256], wa[1], r1);
        r2 = fmaf(row[t + 512], wa[2], r2);
        r3 = fmaf(row[t + 768], wa[3], r3);
    }
    partW[(size_t)b * 1024 + t] = r0;
    partW[(size_t)b * 1024 + t + 256] = r1;
    partW[(size_t)b * 1024 + t + 512] = r2;
    partW[(size_t)b * 1024 + t + 768] = r3;
}
__global__ __launch_bounds__(256) void k_mean_a2(const float* __restrict__ a2e2, float* __restrict__ partA)
{
    int b = blockIdx.x;
    int t = threadIdx.x;
    float s0 = 0, s1 = 0;
    int n0 = b * 80, n1 = min(n0 + 80, NGR);
    for (int n = n0; n < n1; ++n) {
        const float* row = a2e2 + (size_t)n * 1024;
        s0 += row[t]; s1 += row[t + 256];
    }
    partA[(size_t)b * 512 + t] = s0;
    partA[(size_t)b * 512 + t + 256] = s1;
}
__global__ __launch_bounds__(256) void k_gemv_R(const float* __restrict__ partA,
                                                const float* __restrict__ R2a,
                                                const float* __restrict__ b2a,
                                                float* __restrict__ attrR)
{
    __shared__ float am[512];
    __shared__ float red[256];
    int tid = threadIdx.x;
    for (int k = tid; k < 512; k += 256) {
        float s = 0.f;
        for (int b = 0; b < 125; ++b) s += partA[(size_t)b * 512 + k];
        am[k] = s / (float)NGR;
    }
    __syncthreads();
    int c = blockIdx.x * 64 + (tid & 63);
    int ks = (tid >> 6) * 128;
    float s = 0.f;
    for (int k = ks; k < ks + 128; ++k) s = fmaf(am[k], R2a[(size_t)k * 1024 + c], s);
    red[tid] = s;
    __syncthreads();
    if (tid < 64) {
        float v = red[tid] + red[tid + 64] + red[tid + 128] + red[tid + 192];
        attrR[blockIdx.x * 64 + tid] = v + b2a[blockIdx.x * 64 + tid];
    }
}
__global__ void k_attr_fin2(const float* __restrict__ partW, const float* __restrict__ attrR,
                            float* __restrict__ attr)
{
    int c = blockIdx.x * blockDim.x + threadIdx.x;
    if (c >= 1024) return;
    float s = 0.f;
    for (int b = 0; b < 250; ++b) s += partW[(size_t)b * 1024 + c];
    attr[c] = s / (float)NGR + attrR[c];
}

// ---------- node_attr = lrelu(attr,0.01) @ Wo + bo (written twice) ----------
__global__ void k_nattr(const float* __restrict__ attr, const float* __restrict__ Wo,
                        const float* __restrict__ bo, float* __restrict__ out)
{
    int idx = blockIdx.x * blockDim.x + threadIdx.x;
    if (idx >= 16 * 256) return;
    int i = idx >> 8, j = idx & 255;
    float acc = 0.f;
    for (int d = 0; d < 64; ++d) {
        float v = attr[i * 64 + d];
        v = v >= 0.f ? v : 0.01f * v;
        acc = fmaf(v, Wo[d * 256 + j], acc);
    }
    acc += bo[j];
    out[idx] = acc;
    out[4096 + idx] = acc;
}

// ---------- block reductions (1024 threads = 16 waves) ----------
__device__ __forceinline__ float blk_max(float v, float* sh) {
#pragma unroll
    for (int o = 32; o > 0; o >>= 1) v = fmaxf(v, __shfl_xor(v, o, 64));
    if ((threadIdx.x & 63) == 0) sh[threadIdx.x >> 6] = v;
    __syncthreads();
    if (threadIdx.x < 16) {
        float t = sh[threadIdx.x];
#pragma unroll
        for (int o = 8; o > 0; o >>= 1) t = fmaxf(t, __shfl_xor(t, o, 16));
        if (threadIdx.x == 0) sh[0] = t;
    }
    __syncthreads();
    float r = sh[0];
    __syncthreads();
    return r;
}
__device__ __forceinline__ float blk_sum(float v, float* sh) {
#pragma unroll
    for (int o = 32; o > 0; o >>= 1) v += __shfl_xor(v, o, 64);
    if ((threadIdx.x & 63) == 0) sh[threadIdx.x >> 6] = v;
    __syncthreads();
    if (threadIdx.x < 16) {
        float t = sh[threadIdx.x];
#pragma unroll
        for (int o = 8; o > 0; o >>= 1) t += __shfl_xor(t, o, 16);
        if (threadIdx.x == 0) sh[0] = t;
    }
    __syncthreads();
    float r = sh[0];
    __syncthreads();
    return r;
}
__device__ __forceinline__ void blk_argmax(float& v, int& i, float* shf, int* shi) {
#pragma unroll
    for (int o = 32; o > 0; o >>= 1) {
        float ov = __shfl_xor(v, o, 64); int oi = __shfl_xor(i, o, 64);
        if (ov > v || (ov == v && oi < i)) { v = ov; i = oi; }
    }
    if ((threadIdx.x & 63) == 0) { shf[threadIdx.x >> 6] = v; shi[threadIdx.x >> 6] = i; }
    __syncthreads();
    if (threadIdx.x < 16) {
        float tv = shf[threadIdx.x]; int ti = shi[threadIdx.x];
#pragma unroll
        for (int o = 8; o > 0; o >>= 1) {
            float ov = __shfl_xor(tv, o, 16); int oi = __shfl_xor(ti, o, 16);
            if (ov > tv || (ov == tv && oi < ti)) { tv = ov; ti = oi; }
        }
        if (threadIdx.x == 0) { shf[0] = tv; shi[0] = ti; }
    }
    __syncthreads();
    v = shf[0]; i = shi[0];
    __syncthreads();
}

// ---------- gumbel precompute: g[it][r][j], JAX-exact (partitionable threefry) ----------
#define TINYF 1.17549435e-38f
__global__ void k_gumbel(float* __restrict__ gum)
{
    int idx = blockIdx.x * blockDim.x + threadIdx.x;
    if (idx >= 4 * 16 * NGR) return;
    int it = idx / (16 * NGR);
    int f = idx - it * (16 * NGR);     // = r*NGR + j
    u32 fk0, fk1, o0, o1;
    threefry(0u, 42u, 0u, (u32)it, fk0, fk1);   // fold_in(key(42), it)
    threefry(fk0, fk1, 0u, (u32)f, o0, o1);     // partitionable: count=(0,f)
    u32 b = o0 ^ o1;
    float fl = __uint_as_float((b >> 9) | 0x3F800000u) - 1.0f;
    float u = fmaxf(TINYF, fl + TINYF);
    gum[idx] = -logf(-logf(u));
}

// ---------- fused probs softmax + masked-softmax gumbel-argmax sampler ----------
__global__ __launch_bounds__(1024) void k_probs_sample(const float* __restrict__ e3,
                                                       const int* __restrict__ tptr,
                                                       const float* __restrict__ gum,
                                                       float* __restrict__ probs,
                                                       float* __restrict__ out_edges)
{
    __shared__ float col[NGR];
    __shared__ float shf[16];
    __shared__ int shi[16];
    __shared__ int sel[5];
    int r = blockIdx.x, tid = threadIdx.x;
    float mx = -INFINITY;
    for (int n = tid; n < NGR; n += 1024) { float v = e3[n * 16 + r]; col[n] = v; mx = fmaxf(mx, v); }
    __syncthreads();
    float smx = blk_max(mx, shf);
    float sum = 0.f;
    for (int n = tid; n < NGR; n += 1024) sum += expf(col[n] - smx);
    float ssum = blk_sum(sum, shf);
    float pv[10];
#pragma unroll
    for (int w = 0; w < 10; ++w) {
        int j = w * 1024 + tid;
        float p = 0.f;
        if (j < NGR) {
            p = expf(col[j] - smx) / ssum;
            probs[(size_t)r * NGR + j] = p;
        }
        pv[w] = p;
    }
    if (tid == 0) { sel[0] = *tptr; out_edges[r * 5] = (float)sel[0]; }
    __syncthreads();

    for (int it = 0; it < 4; ++it) {
        int nsel = it + 1;
        bool msk[10];
        float vmax = -INFINITY;
#pragma unroll
        for (int w = 0; w < 10; ++w) {
            int j = w * 1024 + tid;
            bool mk = false;
            for (int q = 0; q < nsel; ++q) mk |= (sel[q] == j);
            msk[w] = mk;
            if (j < NGR) {
                float mm = mk ? 0.f : 1.f;
                vmax = fmaxf(vmax, pv[w] * mm - 10000.0f * (1.0f - mm));
            }
        }
        float vm = blk_max(vmax, shf);
        float ex[10];
        float sum2 = 0.f;
#pragma unroll
        for (int w = 0; w < 10; ++w) {
            int j = w * 1024 + tid;
            float mm = msk[w] ? 0.f : 1.f;
            float e = (j < NGR) ? expf((pv[w] - vm) * mm) * mm : 0.f;
            ex[w] = e; sum2 += e;
        }
        float den = blk_sum(sum2, shf) + 1e-8f;
        float best = -INFINITY;
        int bidx = 0x7FFFFFFF;
        const float* g = gum + (size_t)(it * 16 + r) * NGR;
#pragma unroll
        for (int w = 0; w < 10; ++w) {
            int j = w * 1024 + tid;
            if (j < NGR) {
                float lg = logf(fmaxf(ex[w] / den, 1e-30f));
                float sc = g[j] + lg;
                if (sc > best || (sc == best && j < bidx)) { best = sc; bidx = j; }
            }
        }
        blk_argmax(best, bidx, shf, shi);
        if (tid == 0) { sel[it + 1] = bidx; out_edges[r * 5 + it + 1] = (float)bidx; }
        __syncthreads();
    }
}

extern "C" void kernel_launch(void* const* d_in, const int* in_sizes, int n_in,
                              void* d_out, int out_size, void* d_ws, size_t ws_size,
                              hipStream_t stream)
{
    const float* feat = (const float*)d_in[0];
    const int* src = (const int*)d_in[1];
    const int* dst = (const int*)d_in[2];
    const int* tptr = (const int*)d_in[3];
    const float* W1a = (const float*)d_in[4];  const float* al1a = (const float*)d_in[5];
    const float* ar1a = (const float*)d_in[6]; const float* R1a = (const float*)d_in[7];
    const float* b1a = (const float*)d_in[8];
    const float* W1e = (const float*)d_in[9];  const float* al1e = (const float*)d_in[10];
    const float* ar1e = (const float*)d_in[11]; const float* R1e = (const float*)d_in[12];
    const float* b1e = (const float*)d_in[13];
    const float* W2a = (const float*)d_in[14]; const float* al2a = (const float*)d_in[15];
    const float* ar2a = (const float*)d_in[16]; const float* R2a = (const float*)d_in[17];
    const float* b2a = (const float*)d_in[18];
    const float* W2e = (const float*)d_in[19]; const float* al2e = (const float*)d_in[20];
    const float* ar2e = (const float*)d_in[21]; const float* R2e = (const float*)d_in[22];
    const float* b2e = (const float*)d_in[23];
    const float* Wt = (const float*)d_in[24];  const float* bt = (const float*)d_in[25];
    const float* Wo = (const float*)d_in[26];  const float* bo = (const float*)d_in[27];
    const int E = in_sizes[1];
    const int N = NGR;

    float* ws = (float*)d_ws;
    // regionA [N][1024]: phase 1 = h1o1 [h1a|h1e|o1a|o1e]; phase 2 = h2a
    float* regionA = ws;
    size_t off = (size_t)N * 1024;
    auto alloc = [&](size_t n) { float* p = ws + off; off += (n + 3) & ~(size_t)3; return p; };
    float* a2e2 = alloc((size_t)N * 1024);     // [a2(512) | e2(512)]
    float* tf   = alloc(512);
    float* attr = alloc(1024);
    float* attrR = alloc(1024);
    float* partA = alloc(125 * 512);
    float* partW = alloc(250 * 1024);
    float* el1  = alloc((size_t)N * 8);
    float* er1  = alloc((size_t)N * 8);
    float* el2a = alloc((size_t)N * 4);
    float* er2a = alloc((size_t)N * 4);
    float* el2e = alloc(N);
    float* er2e = alloc(N);
    float* h2e  = alloc((size_t)N * 16);
    float* e3   = alloc((size_t)N * 16);
    float* ee1  = alloc((size_t)E * 8);
    float* ee2a = alloc((size_t)E * 4);
    float* ee2e = alloc(E);
    float* packW = alloc(256 * 1024);
    float* packb = alloc(1024);
    float* gum   = alloc((size_t)4 * 16 * NGR);
    unsigned short* a2bf = (unsigned short*)alloc((size_t)10112 * 256);
    unsigned short* WT   = (unsigned short*)alloc((size_t)1024 * 256);
    unsigned short* feathi = (unsigned short*)alloc((size_t)10112 * 128);
    unsigned short* featlo = (unsigned short*)alloc((size_t)10112 * 128);
    unsigned short* WThi = (unsigned short*)alloc((size_t)1024 * 128);
    unsigned short* WTlo = (unsigned short*)alloc((size_t)1024 * 128);
    // ---- zeroed region: walpha (4N floats) + deg (N) + cursor (N) ----
    float* zstart = alloc((size_t)N * 6);
    float* walpha = zstart;
    int* deg    = (int*)(zstart + (size_t)N * 4);
    int* cursor = deg + N;
    int* rowptr = (int*)alloc(N + 1);
    int* colidx = (int*)alloc(E);

    float* out = (float*)d_out;
    float* out_edges = out + 8192;
    float* out_probs = out + 8272;

    dim3 blk(256);

    // zero accumulators + CSR build
    hipMemsetAsync(zstart, 0, (size_t)N * 6 * sizeof(float), stream);
    k_deg<<<(E + 255) / 256, blk, 0, stream>>>(dst, deg, E);
    k_scan<<<1, blk, 0, stream>>>(deg, rowptr, N);
    k_scatter<<<(E + 255) / 256, blk, 0, stream>>>(dst, rowptr, cursor, colidx, E);

    // prep (weights, tf, gumbel, hi/lo splits)
    k_tf<<<1, 512, 0, stream>>>(feat, tptr, Wt, bt, tf);
    k_pack<<<(256 * 1024 + 1024 + 255) / 256, blk, 0, stream>>>(W1a, W1e, R1a, R1e, b1a, b1e, packW, packb);
    k_wt2<<<dim3(32, 16), blk, 0, stream>>>(W2a, WT);
    k_split<<<(N * 64 + 255) / 256, blk, 0, stream>>>(feat, feathi, featlo, N * 64);
    k_wtsplit<<<dim3(32, 8), blk, 0, stream>>>(packW, WThi, WTlo);
    k_gumbel<<<(4 * 16 * NGR + 255) / 256, blk, 0, stream>>>(gum);

    // layer 1 (bf16x3 MFMA emulation of f32, precision-critical): C = [h1a|h1e|o1a|o1e]
    gemm_bf16x3<<<dim3(8, 79), blk, 0, stream>>>(feathi, featlo, WThi, WTlo, regionA, packb, N);
    k_el_er<<<(N * 4 + 255) / 256, blk, 0, stream>>>(regionA, 1024, 0,   al1a, ar1a, el1, er1, 8, 0, 4, 64, N);
    k_el_er<<<(N * 4 + 255) / 256, blk, 0, stream>>>(regionA, 1024, 256, al1e, ar1e, el1, er1, 8, 4, 4, 64, N);
    k_softmax_csr<<<(N * 8 + 255) / 256, blk, 0, stream>>>(el1, er1, rowptr, colidx, src, ee1, 8, 3, N * 8);
    k_agg_csr4<<<(N * 128 + 255) / 256, blk, 0, stream>>>(ee1, rowptr, colidx, src,
                                                          regionA, 256, 0, regionA, 256, 128,
                                                          8, 4, 7, N * 128);
    k_a2e2<<<(N * 256 + 255) / 256, blk, 0, stream>>>(regionA, tf, a2e2, a2bf);

    // mean(a2) path (for collapsed R2a GEMV)
    k_mean_a2<<<125, blk, 0, stream>>>(a2e2, partA);
    k_gemv_R<<<16, blk, 0, stream>>>(partA, R2a, b2a, attrR);

    // layer 2a: only h2a = a2 @ W2a needed per-node (bf16 MFMA, lenient path)
    gemm_bf16<<<dim3(8, 79), blk, 0, stream>>>(a2bf, WT, regionA, nullptr, N, 1024);

    // layer 2e (f32, precision-critical)
    gemm_e<<<(N + 7) / 8, blk, 0, stream>>>(a2e2 + 512, W2e, R2e, b2e, h2e, e3, N);

    k_el_er<<<(N * 4 + 255) / 256, blk, 0, stream>>>(regionA, 1024, 0, al2a, ar2a, el2a, er2a, 4, 0, 4, 256, N);
    k_el_er<<<(N + 255) / 256, blk, 0, stream>>>(h2e, 16, 0, al2e, ar2e, el2e, er2e, 1, 0, 1, 16, N);
    k_softmax_csr<<<(N * 4 + 255) / 256, blk, 0, stream>>>(el2a, er2a, rowptr, colidx, src, ee2a, 4, 2, N * 4);
    k_softmax_csr<<<(N + 255) / 256, blk, 0, stream>>>(el2e, er2e, rowptr, colidx, src, ee2e, 1, 0, N);
    k_agg_csr4<<<(N * 4 + 255) / 256, blk, 0, stream>>>(ee2e, rowptr, colidx, src,
                                                        h2e, 4, 0, e3, 4, 0,
                                                        1, 2, 2, N * 4);

    // attr = mean_n o2a collapsed: agg term via walpha + weighted col-mean of h2a
    k_walpha<<<(E * 4 + 255) / 256, blk, 0, stream>>>(ee2a, src, walpha, E);
    k_wmean<<<250, blk, 0, stream>>>(regionA, walpha, partW);
    k_attr_fin2<<<4, blk, 0, stream>>>(partW, attrR, attr);
    k_nattr<<<16, blk, 0, stream>>>(attr, Wo, bo, out);

    // probs + sampling (bit-exact path)
    k_probs_sample<<<16, 1024, 0, stream>>>(e3, tptr, gum, out_probs, out_edges);
}

// Round 7
// 463.046 us; speedup vs baseline: 3.5977x; 1.0954x over previous
//
#include <hip/hip_runtime.h>
#include <hip/hip_bf16.h>

#define NGR 10000
typedef unsigned int u32;
typedef __attribute__((ext_vector_type(8))) short short8;
typedef __attribute__((ext_vector_type(4))) float f32x4;

// ---------- threefry2x32 (JAX-exact) ----------
__device__ __forceinline__ void threefry(u32 k0, u32 k1, u32 c0, u32 c1, u32& o0, u32& o1) {
    u32 ks2 = k0 ^ k1 ^ 0x1BD11BDAu;
    u32 x0 = c0 + k0, x1 = c1 + k1;
#define TF_R(r) { x0 += x1; x1 = (x1 << r) | (x1 >> (32 - r)); x1 ^= x0; }
    TF_R(13) TF_R(15) TF_R(26) TF_R(6)
    x0 += k1; x1 += ks2 + 1u;
    TF_R(17) TF_R(29) TF_R(16) TF_R(24)
    x0 += ks2; x1 += k0 + 2u;
    TF_R(13) TF_R(15) TF_R(26) TF_R(6)
    x0 += k0; x1 += k1 + 3u;
    TF_R(17) TF_R(29) TF_R(16) TF_R(24)
    x0 += k1; x1 += ks2 + 4u;
    TF_R(13) TF_R(15) TF_R(26) TF_R(6)
    x0 += ks2; x1 += k0 + 5u;
#undef TF_R
    o0 = x0; o1 = x1;
}

// ---------- CSR build ----------
__global__ void k_deg(const int* __restrict__ dst, int* __restrict__ deg, int E) {
    int i = blockIdx.x * blockDim.x + threadIdx.x;
    if (i < E) atomicAdd(&deg[dst[i]], 1);
}
__global__ void k_scan(const int* __restrict__ deg, int* __restrict__ rowptr, int n) {
    __shared__ int sums[256];
    __shared__ int excl[257];
    const int T = 256;
    int t = threadIdx.x;
    int per = (n + T - 1) / T;
    int lo = t * per, hi = min(lo + per, n);
    int s = 0;
    for (int i = lo; i < hi; ++i) s += deg[i];
    sums[t] = s;
    __syncthreads();
    if (t == 0) { int run = 0; for (int i = 0; i < T; ++i) { excl[i] = run; run += sums[i]; } excl[T] = run; }
    __syncthreads();
    int run = excl[t];
    for (int i = lo; i < hi; ++i) { rowptr[i] = run; run += deg[i]; }
    if (t == 0) rowptr[n] = excl[T];
}
__global__ void k_scatter(const int* __restrict__ dst, const int* __restrict__ rowptr,
                          int* __restrict__ cursor, int* __restrict__ colidx, int E) {
    int i = blockIdx.x * blockDim.x + threadIdx.x;
    if (i >= E) return;
    int d = dst[i];
    int pos = atomicAdd(&cursor[d], 1);
    colidx[rowptr[d] + pos] = i;
}

// ---------- split f32 -> (hi, lo) bf16 planes ----------
__global__ void k_split(const float* __restrict__ X, unsigned short* __restrict__ hi,
                        unsigned short* __restrict__ lo, int total4)
{
    int idx = blockIdx.x * blockDim.x + threadIdx.x;
    if (idx >= total4) return;
    float4 v = ((const float4*)X)[idx];
    ushort4 h, l;
    __hip_bfloat16 b; float r;
    b = __float2bfloat16(v.x); h.x = *(unsigned short*)&b; r = v.x - __bfloat162float(b);
    b = __float2bfloat16(r);   l.x = *(unsigned short*)&b;
    b = __float2bfloat16(v.y); h.y = *(unsigned short*)&b; r = v.y - __bfloat162float(b);
    b = __float2bfloat16(r);   l.y = *(unsigned short*)&b;
    b = __float2bfloat16(v.z); h.z = *(unsigned short*)&b; r = v.z - __bfloat162float(b);
    b = __float2bfloat16(r);   l.z = *(unsigned short*)&b;
    b = __float2bfloat16(v.w); h.w = *(unsigned short*)&b; r = v.w - __bfloat162float(b);
    b = __float2bfloat16(r);   l.w = *(unsigned short*)&b;
    ((ushort4*)hi)[idx] = h;
    ((ushort4*)lo)[idx] = l;
}

// ---------- transpose + hi/lo split: BT[n][k] = split(W[k][n]), W=[256][1024] ----------
__global__ __launch_bounds__(256) void k_wtsplit(const float* __restrict__ W,
                                                 unsigned short* __restrict__ BThi,
                                                 unsigned short* __restrict__ BTlo)
{
    __shared__ float tile[32][33];
    int bx = blockIdx.x, by = blockIdx.y;     // bx: n-tile (0..31), by: k-tile (0..7)
    int tx = threadIdx.x & 31, ty = threadIdx.x >> 5;
#pragma unroll
    for (int i = ty; i < 32; i += 8)
        tile[i][tx] = W[(size_t)(by * 32 + i) * 1024 + bx * 32 + tx];
    __syncthreads();
#pragma unroll
    for (int i = ty; i < 32; i += 8) {
        float x = tile[tx][i];
        __hip_bfloat16 b = __float2bfloat16(x);
        float r = x - __bfloat162float(b);
        __hip_bfloat16 bl = __float2bfloat16(r);
        BThi[(size_t)(bx * 32 + i) * 256 + by * 32 + tx] = *(unsigned short*)&b;
        BTlo[(size_t)(bx * 32 + i) * 256 + by * 32 + tx] = *(unsigned short*)&bl;
    }
}

// ---------- bf16x3 MFMA GEMM (f32-emulation): C = A @ BT^T + bias, K=256 ----------
__global__ __launch_bounds__(256) void gemm_bf16x3(
    const unsigned short* __restrict__ Ahi, const unsigned short* __restrict__ Alo,  // [Mpad][256]
    const unsigned short* __restrict__ Bhi, const unsigned short* __restrict__ Blo,  // [1024][256]
    float* __restrict__ C, const float* __restrict__ bias, int M)
{
    constexpr int K = 256;
    __shared__ unsigned short AsH[2][128 * 32];
    __shared__ unsigned short AsL[2][128 * 32];
    __shared__ unsigned short BsH[2][128 * 32];
    __shared__ unsigned short BsL[2][128 * 32];
    const int tid = threadIdx.x;
    const int lane = tid & 63;
    const int w = tid >> 6, wr = w >> 1, wc = w & 1;
    const int bm = blockIdx.y * 128, bn = blockIdx.x * 128;
    const int fr = lane & 15, fq = lane >> 4;
    const int srow = tid >> 2;
    const int sbyte = (tid & 3) * 16;
    f32x4 acc[4][4] = {};

    auto stage = [&](int b, int k0) {
        const char* pA[2] = {(const char*)Ahi, (const char*)Alo};
        const char* pB[2] = {(const char*)Bhi, (const char*)Blo};
        char* dA[2] = {(char*)AsH[b], (char*)AsL[b]};
        char* dB[2] = {(char*)BsH[b], (char*)BsL[b]};
#pragma unroll
        for (int q = 0; q < 2; ++q) {
            const char* ga0 = pA[q] + ((size_t)(bm + srow) * K + k0) * 2 + sbyte;
            const char* ga1 = pA[q] + ((size_t)(bm + 64 + srow) * K + k0) * 2 + sbyte;
            const char* gb0 = pB[q] + ((size_t)(bn + srow) * K + k0) * 2 + sbyte;
            const char* gb1 = pB[q] + ((size_t)(bn + 64 + srow) * K + k0) * 2 + sbyte;
            __builtin_amdgcn_global_load_lds((const __attribute__((address_space(1))) void*)ga0,
                (__attribute__((address_space(3))) void*)(dA[q] + tid * 16), 16, 0, 0);
            __builtin_amdgcn_global_load_lds((const __attribute__((address_space(1))) void*)ga1,
                (__attribute__((address_space(3))) void*)(dA[q] + 4096 + tid * 16), 16, 0, 0);
            __builtin_amdgcn_global_load_lds((const __attribute__((address_space(1))) void*)gb0,
                (__attribute__((address_space(3))) void*)(dB[q] + tid * 16), 16, 0, 0);
            __builtin_amdgcn_global_load_lds((const __attribute__((address_space(1))) void*)gb1,
                (__attribute__((address_space(3))) void*)(dB[q] + 4096 + tid * 16), 16, 0, 0);
        }
    };

    stage(0, 0);
    __syncthreads();
    int buf = 0;
    for (int t = 0; t < 8; ++t) {
        if (t < 7) stage(buf ^ 1, (t + 1) * 32);
        const char* ah = (const char*)AsH[buf];
        const char* al = (const char*)AsL[buf];
        const char* bh = (const char*)BsH[buf];
        const char* bl = (const char*)BsL[buf];
        short8 afh[4], afl[4], bfh[4], bfl[4];
#pragma unroll
        for (int m = 0; m < 4; ++m) {
            int o = (wr * 64 + m * 16 + fr) * 64 + fq * 16;
            afh[m] = *(const short8*)(ah + o);
            afl[m] = *(const short8*)(al + o);
        }
#pragma unroll
        for (int n = 0; n < 4; ++n) {
            int o = (wc * 64 + n * 16 + fr) * 64 + fq * 16;
            bfh[n] = *(const short8*)(bh + o);
            bfl[n] = *(const short8*)(bl + o);
        }
#pragma unroll
        for (int m = 0; m < 4; ++m)
#pragma unroll
            for (int n = 0; n < 4; ++n) {
                acc[m][n] = __builtin_amdgcn_mfma_f32_16x16x32_bf16(afl[m], bfh[n], acc[m][n], 0, 0, 0);
                acc[m][n] = __builtin_amdgcn_mfma_f32_16x16x32_bf16(afh[m], bfl[n], acc[m][n], 0, 0, 0);
                acc[m][n] = __builtin_amdgcn_mfma_f32_16x16x32_bf16(afh[m], bfh[n], acc[m][n], 0, 0, 0);
            }
        __syncthreads();
        buf ^= 1;
    }
#pragma unroll
    for (int m = 0; m < 4; ++m) {
#pragma unroll
        for (int i = 0; i < 4; ++i) {
            int row = bm + wr * 64 + m * 16 + fq * 4 + i;
            if (row >= M) continue;
#pragma unroll
            for (int n = 0; n < 4; ++n) {
                int col = bn + wc * 64 + n * 16 + fr;
                C[(size_t)row * 1024 + col] = acc[m][n][i] + bias[col];
            }
        }
    }
}

// ---------- bf16 MFMA GEMM, 2-phase LDS double-buffer (lenient path) ----------
__global__ __launch_bounds__(256) void gemm_bf16(
    const unsigned short* __restrict__ A,    // [Mpad][512] bf16 bits
    const unsigned short* __restrict__ BT,   // [Ncols][512] bf16 bits
    float* __restrict__ C,                   // [M][Ncols]
    const float* __restrict__ bias,          // [Ncols] or null
    int M, int Ncols)
{
    constexpr int K = 512;
    __shared__ unsigned short As[2][128 * 32];
    __shared__ unsigned short Bs[2][128 * 32];
    const int tid = threadIdx.x;
    const int lane = tid & 63;
    const int w = tid >> 6, wr = w >> 1, wc = w & 1;
    const int bm = blockIdx.y * 128, bn = blockIdx.x * 128;
    const int fr = lane & 15, fq = lane >> 4;
    const int srow = tid >> 2;
    const int sbyte = (tid & 3) * 16;
    f32x4 acc[4][4] = {};
    const char* Ab = (const char*)A;
    const char* Bb = (const char*)BT;

    auto stage = [&](int b, int k0) {
        char* AsB = (char*)As[b];
        char* BsB = (char*)Bs[b];
        const char* ga0 = Ab + ((size_t)(bm + srow) * K + k0) * 2 + sbyte;
        const char* ga1 = Ab + ((size_t)(bm + 64 + srow) * K + k0) * 2 + sbyte;
        const char* gb0 = Bb + ((size_t)(bn + srow) * K + k0) * 2 + sbyte;
        const char* gb1 = Bb + ((size_t)(bn + 64 + srow) * K + k0) * 2 + sbyte;
        __builtin_amdgcn_global_load_lds((const __attribute__((address_space(1))) void*)ga0,
            (__attribute__((address_space(3))) void*)(AsB + tid * 16), 16, 0, 0);
        __builtin_amdgcn_global_load_lds((const __attribute__((address_space(1))) void*)ga1,
            (__attribute__((address_space(3))) void*)(AsB + 4096 + tid * 16), 16, 0, 0);
        __builtin_amdgcn_global_load_lds((const __attribute__((address_space(1))) void*)gb0,
            (__attribute__((address_space(3))) void*)(BsB + tid * 16), 16, 0, 0);
        __builtin_amdgcn_global_load_lds((const __attribute__((address_space(1))) void*)gb1,
            (__attribute__((address_space(3))) void*)(BsB + 4096 + tid * 16), 16, 0, 0);
    };

    stage(0, 0);
    __syncthreads();
    int buf = 0;
    for (int t = 0; t < 16; ++t) {
        if (t < 15) stage(buf ^ 1, (t + 1) * 32);
        const char* AsB = (const char*)As[buf];
        const char* BsB = (const char*)Bs[buf];
        short8 af[4], bfv[4];
#pragma unroll
        for (int m = 0; m < 4; ++m)
            af[m] = *(const short8*)(AsB + ((wr * 64 + m * 16 + fr) * 64 + fq * 16));
#pragma unroll
        for (int n = 0; n < 4; ++n)
            bfv[n] = *(const short8*)(BsB + ((wc * 64 + n * 16 + fr) * 64 + fq * 16));
#pragma unroll
        for (int m = 0; m < 4; ++m)
#pragma unroll
            for (int n = 0; n < 4; ++n)
                acc[m][n] = __builtin_amdgcn_mfma_f32_16x16x32_bf16(af[m], bfv[n], acc[m][n], 0, 0, 0);
        __syncthreads();
        buf ^= 1;
    }
#pragma unroll
    for (int m = 0; m < 4; ++m) {
#pragma unroll
        for (int i = 0; i < 4; ++i) {
            int row = bm + wr * 64 + m * 16 + fq * 4 + i;
            if (row >= M) continue;
#pragma unroll
            for (int n = 0; n < 4; ++n) {
                int col = bn + wc * 64 + n * 16 + fr;
                C[(size_t)row * Ncols + col] = acc[m][n][i] + (bias ? bias[col] : 0.f);
            }
        }
    }
}

// ---------- coalesced LDS-tiled transpose + bf16: WT[n][k] = bf16(W[k][n]) ----------
__global__ __launch_bounds__(256) void k_wt2(const float* __restrict__ W, unsigned short* __restrict__ WT) {
    __shared__ float tile[32][33];
    int bx = blockIdx.x, by = blockIdx.y;
    int tx = threadIdx.x & 31, ty = threadIdx.x >> 5;
#pragma unroll
    for (int i = ty; i < 32; i += 8)
        tile[i][tx] = W[(size_t)(by * 32 + i) * 1024 + bx * 32 + tx];
    __syncthreads();
#pragma unroll
    for (int i = ty; i < 32; i += 8) {
        __hip_bfloat16 b = __float2bfloat16(tile[tx][i]);
        WT[(size_t)(bx * 32 + i) * 512 + by * 32 + tx] = *(unsigned short*)&b;
    }
}

// ---------- pack layer-1 weights: PW[256][1024] = [W1a|W1e|R1a|R1e] ----------
__global__ void k_pack(const float* __restrict__ Wa, const float* __restrict__ We,
                       const float* __restrict__ Ra, const float* __restrict__ Re,
                       const float* __restrict__ ba, const float* __restrict__ be,
                       float* __restrict__ PW, float* __restrict__ Pb) {
    int idx = blockIdx.x * blockDim.x + threadIdx.x;
    if (idx < 256 * 1024) {
        int k = idx >> 10, c = idx & 1023;
        float v;
        if (c < 256) v = Wa[k * 256 + c];
        else if (c < 512) v = We[k * 256 + (c - 256)];
        else if (c < 768) v = Ra[k * 256 + (c - 512)];
        else v = Re[k * 256 + (c - 768)];
        PW[idx] = v;
    } else if (idx < 256 * 1024 + 1024) {
        int c = idx - 256 * 1024;
        Pb[c] = (c < 512) ? 0.f : ((c < 768) ? ba[c - 512] : be[c - 768]);
    }
}

// ---------- tf = leaky_relu(feat[t] @ Wt + bt, 0.01), parallel (8 blocks) ----------
__global__ __launch_bounds__(256) void k_tf_par(const float* __restrict__ feat, const int* __restrict__ tptr,
                                                const float* __restrict__ Wt, const float* __restrict__ bt,
                                                float* __restrict__ tf)
{
    __shared__ float frow[256];
    __shared__ float red[256];
    int tid = threadIdx.x;
    int t = *tptr;
    frow[tid] = feat[t * 256 + tid];
    __syncthreads();
    int j = blockIdx.x * 64 + (tid & 63);
    int ks = (tid >> 6) * 64;
    float s = 0.f;
#pragma unroll 16
    for (int k = ks; k < ks + 64; ++k) s = fmaf(frow[k], Wt[(size_t)k * 512 + j], s);
    red[tid] = s;
    __syncthreads();
    if (tid < 64) {
        float v = red[tid] + red[tid + 64] + red[tid + 128] + red[tid + 192] + bt[j];
        tf[j] = v >= 0.f ? v : 0.01f * v;
    }
}

// ---------- el/er: per (n,h) dot over D (float4) ----------
__global__ void k_el_er(const float* __restrict__ h, int ldh, int hoff,
                        const float* __restrict__ al, const float* __restrict__ ar,
                        float* __restrict__ el, float* __restrict__ er,
                        int ldE, int eoff, int H, int D, int N)
{
    int idx = blockIdx.x * blockDim.x + threadIdx.x;
    if (idx >= N * H) return;
    int n = idx / H, hh = idx - n * H;
    const float* hp = h + (size_t)n * ldh + hoff + hh * D;
    const float* alp = al + hh * D;
    const float* arp = ar + hh * D;
    float sl = 0.f, sr = 0.f;
    for (int d = 0; d < D; d += 4) {
        float4 v = *(const float4*)(hp + d);
        float4 a4 = *(const float4*)(alp + d);
        float4 r4 = *(const float4*)(arp + d);
        sl = fmaf(v.x, a4.x, sl); sl = fmaf(v.y, a4.y, sl); sl = fmaf(v.z, a4.z, sl); sl = fmaf(v.w, a4.w, sl);
        sr = fmaf(v.x, r4.x, sr); sr = fmaf(v.y, r4.y, sr); sr = fmaf(v.z, r4.z, sr); sr = fmaf(v.w, r4.w, sr);
    }
    el[n * ldE + eoff + hh] = sl;
    er[n * ldE + eoff + hh] = sr;
}

// ---------- CSR edge softmax: write normalized alpha into ee[E][H] ----------
__global__ void k_softmax_csr(const float* __restrict__ el, const float* __restrict__ er,
                              const int* __restrict__ rowptr, const int* __restrict__ colidx,
                              const int* __restrict__ src,
                              float* __restrict__ ee, int H, int hshift, int total)
{
    int idx = blockIdx.x * blockDim.x + threadIdx.x;
    if (idx >= total) return;
    int n = idx >> hshift, hh = idx & (H - 1);
    float ern = er[n * H + hh];
    int i0 = rowptr[n], i1 = rowptr[n + 1];
    float mx = -INFINITY;
    for (int i = i0; i < i1; ++i) {
        float v = el[src[colidx[i]] * H + hh] + ern;
        v = v >= 0.f ? v : 0.2f * v;
        mx = fmaxf(mx, v);
    }
    float s = 0.f;
    for (int i = i0; i < i1; ++i) {
        int e = colidx[i];
        float v = el[src[e] * H + hh] + ern;
        v = v >= 0.f ? v : 0.2f * v;
        float ex = expf(v - mx);
        ee[(size_t)e * H + hh] = ex;
        s += ex;
    }
    for (int i = i0; i < i1; ++i) {
        int e = colidx[i];
        ee[(size_t)e * H + hh] /= s;
    }
}

// ---------- CSR aggregation (float4) ----------
__global__ void k_agg_csr4(const float* __restrict__ alpha,
                           const int* __restrict__ rowptr, const int* __restrict__ colidx,
                           const int* __restrict__ src,
                           const float* __restrict__ h, int ldh4, int hoff4,
                           float* __restrict__ out, int ldo4, int ooff4,
                           int H, int dshift4, int hdshift4, int total)
{
    int idx = blockIdx.x * blockDim.x + threadIdx.x;
    if (idx >= total) return;
    int n = idx >> hdshift4, c4 = idx & ((1 << hdshift4) - 1);
    int hh = c4 >> dshift4;
    const float4* h4 = (const float4*)h;
    float4* out4 = (float4*)out;
    float4 acc = out4[(size_t)n * ldo4 + ooff4 + c4];
    int i1 = rowptr[n + 1];
    for (int i = rowptr[n]; i < i1; ++i) {
        int e = colidx[i];
        float a = alpha[(size_t)e * H + hh];
        float4 hv = h4[(size_t)src[e] * ldh4 + hoff4 + c4];
        acc.x = fmaf(a, hv.x, acc.x); acc.y = fmaf(a, hv.y, acc.y);
        acc.z = fmaf(a, hv.z, acc.z); acc.w = fmaf(a, hv.w, acc.w);
    }
    out4[(size_t)n * ldo4 + ooff4 + c4] = acc;
}

// ---------- a2/e2 = lrelu(concat/swap + tf, 0.01); bf16 copy of a2 (float4) ----------
__global__ void k_a2e2(const float* __restrict__ h1o1, const float* __restrict__ tf,
                       float* __restrict__ B, unsigned short* __restrict__ a2bf)
{
    int idx = blockIdx.x * blockDim.x + threadIdx.x;
    if (idx >= NGR * 256) return;
    int n = idx >> 8, c4 = idx & 255;
    int c = c4 << 2;
    const float* o = h1o1 + (size_t)n * 1024 + 512;
    float4 x;
    if (c < 512) x = *(const float4*)(o + c);
    else { int cc = c - 512; x = *(const float4*)(o + ((cc < 256) ? cc + 256 : cc - 256)); }
    float4 t4 = *(const float4*)(tf + (c & 511));
    x.x += t4.x; x.y += t4.y; x.z += t4.z; x.w += t4.w;
    x.x = x.x >= 0.f ? x.x : 0.01f * x.x;
    x.y = x.y >= 0.f ? x.y : 0.01f * x.y;
    x.z = x.z >= 0.f ? x.z : 0.01f * x.z;
    x.w = x.w >= 0.f ? x.w : 0.01f * x.w;
    *(float4*)(B + (size_t)n * 1024 + c) = x;
    if (c < 512) {
        __hip_bfloat16 b0 = __float2bfloat16(x.x), b1 = __float2bfloat16(x.y);
        __hip_bfloat16 b2 = __float2bfloat16(x.z), b3 = __float2bfloat16(x.w);
        ushort4 u4;
        u4.x = *(unsigned short*)&b0; u4.y = *(unsigned short*)&b1;
        u4.z = *(unsigned short*)&b2; u4.w = *(unsigned short*)&b3;
        *(ushort4*)(a2bf + (size_t)n * 512 + c) = u4;
    }
}

// ---------- skinny GEMM: h2e = e2 @ W2e ; e3 = e2 @ R2e + b2e ----------
__global__ __launch_bounds__(256) void gemm_e(
    const float* __restrict__ A,
    const float* __restrict__ We, const float* __restrict__ Re, const float* __restrict__ be,
    float* __restrict__ h2e, float* __restrict__ e3, int M)
{
    __shared__ float As[8 * 512];
    int tid = threadIdx.x;
    int m0 = blockIdx.x * 8;
    for (int i = tid; i < 8 * 128; i += 256) {
        int row = i >> 7, c4 = (i & 127) << 2;
        int m = m0 + row;
        float4 v = make_float4(0.f, 0.f, 0.f, 0.f);
        if (m < M) v = *(const float4*)(A + (size_t)m * 1024 + c4);
        *(float4*)(As + row * 512 + c4) = v;
    }
    __syncthreads();
    int r = tid >> 5, j = tid & 31;
    const float* B = (j < 16) ? We : Re;
    int jj = j & 15;
    const float* ar = As + r * 512;
    float acc0 = 0.f, acc1 = 0.f;
#pragma unroll 8
    for (int k = 0; k < 512; k += 2) {
        acc0 = fmaf(ar[k], B[k * 16 + jj], acc0);
        acc1 = fmaf(ar[k + 1], B[(k + 1) * 16 + jj], acc1);
    }
    float acc = acc0 + acc1;
    int m = m0 + r;
    if (m < M) {
        if (j < 16) h2e[(size_t)m * 16 + jj] = acc;
        else        e3[(size_t)m * 16 + jj] = acc + be[jj];
    }
}

// ---------- attr path (o2a collapsed to mean) ----------
__global__ void k_walpha(const float* __restrict__ ee2a, const int* __restrict__ src,
                         float* __restrict__ walpha, int E)
{
    int i = blockIdx.x * blockDim.x + threadIdx.x;
    if (i >= E * 4) return;
    int e = i >> 2, hh = i & 3;
    atomicAdd(&walpha[src[e] * 4 + hh], ee2a[(size_t)e * 4 + hh]);
}
__global__ __launch_bounds__(256) void k_wmean(const float* __restrict__ h2a,
                                               const float* __restrict__ walpha,
                                               float* __restrict__ partW)
{
    int b = blockIdx.x;
    int t = threadIdx.x;
    float r0 = 0, r1 = 0, r2 = 0, r3 = 0;
    int n0 = b * 40, n1 = min(n0 + 40, NGR);
    for (int n = n0; n < n1; ++n) {
        const float* row = h2a + (size_t)n * 1024;
        const float* wa = walpha + n * 4;
        r0 = fmaf(row[t], wa[0], r0);
        r1 = fmaf(row[t + 256], wa[1], r1);
        r2 = fmaf(row[t + 512], wa[2], r2);
        r3 = fmaf(row[t + 768], wa[3], r3);
    }
    partW[(size_t)b * 1024 + t] = r0;
    partW[(size_t)b * 1024 + t + 256] = r1;
    partW[(size_t)b * 1024 + t + 512] = r2;
    partW[(size_t)b * 1024 + t + 768] = r3;
}
__global__ __launch_bounds__(256) void k_mean_a2(const float* __restrict__ a2e2, float* __restrict__ partA)
{
    int b = blockIdx.x;
    int t = threadIdx.x;
    float s0 = 0, s1 = 0;
    int n0 = b * 80, n1 = min(n0 + 80, NGR);
    for (int n = n0; n < n1; ++n) {
        const float* row = a2e2 + (size_t)n * 1024;
        s0 += row[t]; s1 += row[t + 256];
    }
    partA[(size_t)b * 512 + t] = s0;
    partA[(size_t)b * 512 + t + 256] = s1;
}
// am[k] = (sum_b partA[b][k]) / N   (2 blocks x 256)
__global__ __launch_bounds__(256) void k_am(const float* __restrict__ partA, float* __restrict__ am)
{
    int k = blockIdx.x * 256 + threadIdx.x;
    float s = 0.f;
    for (int b = 0; b < 125; ++b) s += partA[(size_t)b * 512 + k];
    am[k] = s / (float)NGR;
}
// attrR[c] = am @ R2a[:,c] + b2a[c]   (64 blocks x 256: 16 cols/block, 16 k-slices)
__global__ __launch_bounds__(256) void k_gemv2(const float* __restrict__ am,
                                               const float* __restrict__ R2a,
                                               const float* __restrict__ b2a,
                                               float* __restrict__ attrR)
{
    __shared__ float red[256];
    int tid = threadIdx.x;
    int c = blockIdx.x * 16 + (tid & 15);
    int ks = (tid >> 4) * 32;
    float s = 0.f;
#pragma unroll 8
    for (int k = ks; k < ks + 32; ++k) s = fmaf(am[k], R2a[(size_t)k * 1024 + c], s);
    red[tid] = s;
    __syncthreads();
    if (tid < 16) {
        float v = 0.f;
#pragma unroll
        for (int g = 0; g < 16; ++g) v += red[tid + g * 16];
        attrR[blockIdx.x * 16 + tid] = v + b2a[blockIdx.x * 16 + tid];
    }
}
__global__ void k_attr_fin2(const float* __restrict__ partW, const float* __restrict__ attrR,
                            float* __restrict__ attr)
{
    int c = blockIdx.x * blockDim.x + threadIdx.x;
    if (c >= 1024) return;
    float s = 0.f;
    for (int b = 0; b < 250; ++b) s += partW[(size_t)b * 1024 + c];
    attr[c] = s / (float)NGR + attrR[c];
}

// ---------- node_attr = lrelu(attr,0.01) @ Wo + bo (written twice) ----------
__global__ void k_nattr(const float* __restrict__ attr, const float* __restrict__ Wo,
                        const float* __restrict__ bo, float* __restrict__ out)
{
    int idx = blockIdx.x * blockDim.x + threadIdx.x;
    if (idx >= 16 * 256) return;
    int i = idx >> 8, j = idx & 255;
    float acc = 0.f;
    for (int d = 0; d < 64; ++d) {
        float v = attr[i * 64 + d];
        v = v >= 0.f ? v : 0.01f * v;
        acc = fmaf(v, Wo[d * 256 + j], acc);
    }
    acc += bo[j];
    out[idx] = acc;
    out[4096 + idx] = acc;
}

// ---------- block reductions (1024 threads = 16 waves) ----------
__device__ __forceinline__ float blk_max(float v, float* sh) {
#pragma unroll
    for (int o = 32; o > 0; o >>= 1) v = fmaxf(v, __shfl_xor(v, o, 64));
    if ((threadIdx.x & 63) == 0) sh[threadIdx.x >> 6] = v;
    __syncthreads();
    if (threadIdx.x < 16) {
        float t = sh[threadIdx.x];
#pragma unroll
        for (int o = 8; o > 0; o >>= 1) t = fmaxf(t, __shfl_xor(t, o, 16));
        if (threadIdx.x == 0) sh[0] = t;
    }
    __syncthreads();
    float r = sh[0];
    __syncthreads();
    return r;
}
__device__ __forceinline__ float blk_sum(float v, float* sh) {
#pragma unroll
    for (int o = 32; o > 0; o >>= 1) v += __shfl_xor(v, o, 64);
    if ((threadIdx.x & 63) == 0) sh[threadIdx.x >> 6] = v;
    __syncthreads();
    if (threadIdx.x < 16) {
        float t = sh[threadIdx.x];
#pragma unroll
        for (int o = 8; o > 0; o >>= 1) t += __shfl_xor(t, o, 16);
        if (threadIdx.x == 0) sh[0] = t;
    }
    __syncthreads();
    float r = sh[0];
    __syncthreads();
    return r;
}
__device__ __forceinline__ void blk_argmax(float& v, int& i, float* shf, int* shi) {
#pragma unroll
    for (int o = 32; o > 0; o >>= 1) {
        float ov = __shfl_xor(v, o, 64); int oi = __shfl_xor(i, o, 64);
        if (ov > v || (ov == v && oi < i)) { v = ov; i = oi; }
    }
    if ((threadIdx.x & 63) == 0) { shf[threadIdx.x >> 6] = v; shi[threadIdx.x >> 6] = i; }
    __syncthreads();
    if (threadIdx.x < 16) {
        float tv = shf[threadIdx.x]; int ti = shi[threadIdx.x];
#pragma unroll
        for (int o = 8; o > 0; o >>= 1) {
            float ov = __shfl_xor(tv, o, 16); int oi = __shfl_xor(ti, o, 16);
            if (ov > tv || (ov == tv && oi < ti)) { tv = ov; ti = oi; }
        }
        if (threadIdx.x == 0) { shf[0] = tv; shi[0] = ti; }
    }
    __syncthreads();
    v = shf[0]; i = shi[0];
    __syncthreads();
}

// ---------- gumbel precompute: g[it][r][j], JAX-exact (partitionable threefry) ----------
#define TINYF 1.17549435e-38f
__global__ void k_gumbel(float* __restrict__ gum)
{
    int idx = blockIdx.x * blockDim.x + threadIdx.x;
    if (idx >= 4 * 16 * NGR) return;
    int it = idx / (16 * NGR);
    int f = idx - it * (16 * NGR);     // = r*NGR + j
    u32 fk0, fk1, o0, o1;
    threefry(0u, 42u, 0u, (u32)it, fk0, fk1);   // fold_in(key(42), it)
    threefry(fk0, fk1, 0u, (u32)f, o0, o1);     // partitionable: count=(0,f)
    u32 b = o0 ^ o1;
    float fl = __uint_as_float((b >> 9) | 0x3F800000u) - 1.0f;
    float u = fmaxf(TINYF, fl + TINYF);
    gum[idx] = -logf(-logf(u));
}

// ---------- fused probs softmax + masked-softmax gumbel-argmax sampler ----------
__global__ __launch_bounds__(1024) void k_probs_sample(const float* __restrict__ e3,
                                                       const int* __restrict__ tptr,
                                                       const float* __restrict__ gum,
                                                       float* __restrict__ probs,
                                                       float* __restrict__ out_edges)
{
    __shared__ float col[NGR];
    __shared__ float shf[16];
    __shared__ int shi[16];
    __shared__ int sel[5];
    int r = blockIdx.x, tid = threadIdx.x;
    float mx = -INFINITY;
    for (int n = tid; n < NGR; n += 1024) { float v = e3[n * 16 + r]; col[n] = v; mx = fmaxf(mx, v); }
    __syncthreads();
    float smx = blk_max(mx, shf);
    float sum = 0.f;
    for (int n = tid; n < NGR; n += 1024) sum += expf(col[n] - smx);
    float ssum = blk_sum(sum, shf);
    float pv[10];
#pragma unroll
    for (int w = 0; w < 10; ++w) {
        int j = w * 1024 + tid;
        float p = 0.f;
        if (j < NGR) {
            p = expf(col[j] - smx) / ssum;
            probs[(size_t)r * NGR + j] = p;
        }
        pv[w] = p;
    }
    if (tid == 0) { sel[0] = *tptr; out_edges[r * 5] = (float)sel[0]; }
    __syncthreads();

    for (int it = 0; it < 4; ++it) {
        int nsel = it + 1;
        bool msk[10];
        float vmax = -INFINITY;
#pragma unroll
        for (int w = 0; w < 10; ++w) {
            int j = w * 1024 + tid;
            bool mk = false;
            for (int q = 0; q < nsel; ++q) mk |= (sel[q] == j);
            msk[w] = mk;
            if (j < NGR) {
                float mm = mk ? 0.f : 1.f;
                vmax = fmaxf(vmax, pv[w] * mm - 10000.0f * (1.0f - mm));
            }
        }
        float vm = blk_max(vmax, shf);
        float ex[10];
        float sum2 = 0.f;
#pragma unroll
        for (int w = 0; w < 10; ++w) {
            int j = w * 1024 + tid;
            float mm = msk[w] ? 0.f : 1.f;
            float e = (j < NGR) ? expf((pv[w] - vm) * mm) * mm : 0.f;
            ex[w] = e; sum2 += e;
        }
        float den = blk_sum(sum2, shf) + 1e-8f;
        float best = -INFINITY;
        int bidx = 0x7FFFFFFF;
        const float* g = gum + (size_t)(it * 16 + r) * NGR;
#pragma unroll
        for (int w = 0; w < 10; ++w) {
            int j = w * 1024 + tid;
            if (j < NGR) {
                float lg = logf(fmaxf(ex[w] / den, 1e-30f));
                float sc = g[j] + lg;
                if (sc > best || (sc == best && j < bidx)) { best = sc; bidx = j; }
            }
        }
        blk_argmax(best, bidx, shf, shi);
        if (tid == 0) { sel[it + 1] = bidx; out_edges[r * 5 + it + 1] = (float)bidx; }
        __syncthreads();
    }
}

extern "C" void kernel_launch(void* const* d_in, const int* in_sizes, int n_in,
                              void* d_out, int out_size, void* d_ws, size_t ws_size,
                              hipStream_t stream)
{
    const float* feat = (const float*)d_in[0];
    const int* src = (const int*)d_in[1];
    const int* dst = (const int*)d_in[2];
    const int* tptr = (const int*)d_in[3];
    const float* W1a = (const float*)d_in[4];  const float* al1a = (const float*)d_in[5];
    const float* ar1a = (const float*)d_in[6]; const float* R1a = (const float*)d_in[7];
    const float* b1a = (const float*)d_in[8];
    const float* W1e = (const float*)d_in[9];  const float* al1e = (const float*)d_in[10];
    const float* ar1e = (const float*)d_in[11]; const float* R1e = (const float*)d_in[12];
    const float* b1e = (const float*)d_in[13];
    const float* W2a = (const float*)d_in[14]; const float* al2a = (const float*)d_in[15];
    const float* ar2a = (const float*)d_in[16]; const float* R2a = (const float*)d_in[17];
    const float* b2a = (const float*)d_in[18];
    const float* W2e = (const float*)d_in[19]; const float* al2e = (const float*)d_in[20];
    const float* ar2e = (const float*)d_in[21]; const float* R2e = (const float*)d_in[22];
    const float* b2e = (const float*)d_in[23];
    const float* Wt = (const float*)d_in[24];  const float* bt = (const float*)d_in[25];
    const float* Wo = (const float*)d_in[26];  const float* bo = (const float*)d_in[27];
    const int E = in_sizes[1];
    const int N = NGR;

    float* ws = (float*)d_ws;
    float* regionA = ws;
    size_t off = (size_t)N * 1024;
    auto alloc = [&](size_t n) { float* p = ws + off; off += (n + 3) & ~(size_t)3; return p; };
    float* a2e2 = alloc((size_t)N * 1024);
    float* tf   = alloc(512);
    float* attr = alloc(1024);
    float* attrR = alloc(1024);
    float* am_   = alloc(512);
    float* partA = alloc(125 * 512);
    float* partW = alloc(250 * 1024);
    float* el1  = alloc((size_t)N * 8);
    float* er1  = alloc((size_t)N * 8);
    float* el2a = alloc((size_t)N * 4);
    float* er2a = alloc((size_t)N * 4);
    float* el2e = alloc(N);
    float* er2e = alloc(N);
    float* h2e  = alloc((size_t)N * 16);
    float* e3   = alloc((size_t)N * 16);
    float* ee1  = alloc((size_t)E * 8);
    float* ee2a = alloc((size_t)E * 4);
    float* ee2e = alloc(E);
    float* packW = alloc(256 * 1024);
    float* packb = alloc(1024);
    float* gum   = alloc((size_t)4 * 16 * NGR);
    unsigned short* a2bf = (unsigned short*)alloc((size_t)10112 * 256);
    unsigned short* WT   = (unsigned short*)alloc((size_t)1024 * 256);
    unsigned short* feathi = (unsigned short*)alloc((size_t)10112 * 128);
    unsigned short* featlo = (unsigned short*)alloc((size_t)10112 * 128);
    unsigned short* WThi = (unsigned short*)alloc((size_t)1024 * 128);
    unsigned short* WTlo = (unsigned short*)alloc((size_t)1024 * 128);
    float* zstart = alloc((size_t)N * 6);
    float* walpha = zstart;
    int* deg    = (int*)(zstart + (size_t)N * 4);
    int* cursor = deg + N;
    int* rowptr = (int*)alloc(N + 1);
    int* colidx = (int*)alloc(E);

    float* out = (float*)d_out;
    float* out_edges = out + 8192;
    float* out_probs = out + 8272;

    dim3 blk(256);

    // zero accumulators + CSR build
    hipMemsetAsync(zstart, 0, (size_t)N * 6 * sizeof(float), stream);
    k_deg<<<(E + 255) / 256, blk, 0, stream>>>(dst, deg, E);
    k_scan<<<1, blk, 0, stream>>>(deg, rowptr, N);
    k_scatter<<<(E + 255) / 256, blk, 0, stream>>>(dst, rowptr, cursor, colidx, E);

    // prep (weights, tf, gumbel, hi/lo splits)
    k_tf_par<<<8, blk, 0, stream>>>(feat, tptr, Wt, bt, tf);
    k_pack<<<(256 * 1024 + 1024 + 255) / 256, blk, 0, stream>>>(W1a, W1e, R1a, R1e, b1a, b1e, packW, packb);
    k_wt2<<<dim3(32, 16), blk, 0, stream>>>(W2a, WT);
    k_split<<<(N * 64 + 255) / 256, blk, 0, stream>>>(feat, feathi, featlo, N * 64);
    k_wtsplit<<<dim3(32, 8), blk, 0, stream>>>(packW, WThi, WTlo);
    k_gumbel<<<(4 * 16 * NGR + 255) / 256, blk, 0, stream>>>(gum);

    // layer 1 (bf16x3 MFMA emulation of f32, precision-critical): C = [h1a|h1e|o1a|o1e]
    gemm_bf16x3<<<dim3(8, 79), blk, 0, stream>>>(feathi, featlo, WThi, WTlo, regionA, packb, N);
    k_el_er<<<(N * 4 + 255) / 256, blk, 0, stream>>>(regionA, 1024, 0,   al1a, ar1a, el1, er1, 8, 0, 4, 64, N);
    k_el_er<<<(N * 4 + 255) / 256, blk, 0, stream>>>(regionA, 1024, 256, al1e, ar1e, el1, er1, 8, 4, 4, 64, N);
    k_softmax_csr<<<(N * 8 + 255) / 256, blk, 0, stream>>>(el1, er1, rowptr, colidx, src, ee1, 8, 3, N * 8);
    k_agg_csr4<<<(N * 128 + 255) / 256, blk, 0, stream>>>(ee1, rowptr, colidx, src,
                                                          regionA, 256, 0, regionA, 256, 128,
                                                          8, 4, 7, N * 128);
    k_a2e2<<<(N * 256 + 255) / 256, blk, 0, stream>>>(regionA, tf, a2e2, a2bf);

    // mean(a2) path (collapsed R2a GEMV)
    k_mean_a2<<<125, blk, 0, stream>>>(a2e2, partA);
    k_am<<<2, blk, 0, stream>>>(partA, am_);
    k_gemv2<<<64, blk, 0, stream>>>(am_, R2a, b2a, attrR);

    // layer 2a: h2a = a2 @ W2a (bf16 MFMA, lenient path)
    gemm_bf16<<<dim3(8, 79), blk, 0, stream>>>(a2bf, WT, regionA, nullptr, N, 1024);

    // layer 2e (f32, precision-critical)
    gemm_e<<<(N + 7) / 8, blk, 0, stream>>>(a2e2 + 512, W2e, R2e, b2e, h2e, e3, N);

    k_el_er<<<(N * 4 + 255) / 256, blk, 0, stream>>>(regionA, 1024, 0, al2a, ar2a, el2a, er2a, 4, 0, 4, 256, N);
    k_el_er<<<(N + 255) / 256, blk, 0, stream>>>(h2e, 16, 0, al2e, ar2e, el2e, er2e, 1, 0, 1, 16, N);
    k_softmax_csr<<<(N * 4 + 255) / 256, blk, 0, stream>>>(el2a, er2a, rowptr, colidx, src, ee2a, 4, 2, N * 4);
    k_softmax_csr<<<(N + 255) / 256, blk, 0, stream>>>(el2e, er2e, rowptr, colidx, src, ee2e, 1, 0, N);
    k_agg_csr4<<<(N * 4 + 255) / 256, blk, 0, stream>>>(ee2e, rowptr, colidx, src,
                                                        h2e, 4, 0, e3, 4, 0,
                                                        1, 2, 2, N * 4);

    // attr = mean_n o2a collapsed
    k_walpha<<<(E * 4 + 255) / 256, blk, 0, stream>>>(ee2a, src, walpha, E);
    k_wmean<<<250, blk, 0, stream>>>(regionA, walpha, partW);
    k_attr_fin2<<<4, blk, 0, stream>>>(partW, attrR, attr);
    k_nattr<<<16, blk, 0, stream>>>(attr, Wo, bo, out);

    // probs + sampling (bit-exact path)
    k_probs_sample<<<16, 1024, 0, stream>>>(e3, tptr, gum, out_probs, out_edges);
}